// Round 7
// baseline (806.837 us; speedup 1.0000x reference)
//
#include <hip/hip_runtime.h>
#include <math.h>

#define NLIG 16384
#define NPROT 131072
#define NTOT (NLIG + NPROT)
#define NEDGE 2097152
#define NB 256
#define H 64
#define NBUCK 576      // NTOT = 576 * 256
#define BSHIFT 8       // bucket = dst >> 8
#define BCAP 4608      // padded bucket capacity (avg 3641, sd ~60 -> 16 sigma)
#define NCHUNK (NTOT / 16)   // 9216 16-node chunks

typedef short v4s __attribute__((ext_vector_type(4)));
typedef float v4f __attribute__((ext_vector_type(4)));

__device__ __forceinline__ unsigned short f2bf(float f) {
    unsigned int u = __float_as_uint(f);
    u += 0x7fff + ((u >> 16) & 1);   // RNE
    return (unsigned short)(u >> 16);
}
__device__ __forceinline__ float bf2f(unsigned short s) {
    return __uint_as_float(((unsigned int)s) << 16);
}
__device__ __forceinline__ float bflo(unsigned int u) {
    return __uint_as_float(u << 16);
}
__device__ __forceinline__ float bfhi(unsigned int u) {
    return __uint_as_float(u & 0xffff0000u);
}

// ---------------- time embedding MLP ----------------
__global__ void time_mlp_kernel(const float* __restrict__ t,
                                const float* __restrict__ Wt1, const float* __restrict__ bt1,
                                const float* __restrict__ Wt2, const float* __restrict__ bt2,
                                float* __restrict__ t_emb) {
    int b = blockIdx.x;
    int h = threadIdx.x;
    __shared__ float emb_s[H];
    __shared__ float h1_s[H];
    float tv = t[b];
    int i = h & 31;
    float freq = expf((float)i * (-9.2103403719761836f / 31.0f));
    float e = tv * freq;
    emb_s[h] = (h < 32) ? sinf(e) : cosf(e);
    __syncthreads();
    float acc = bt1[h];
    #pragma unroll 8
    for (int k = 0; k < H; k++) acc += emb_s[k] * Wt1[k * H + h];
    float sig = 1.0f / (1.0f + expf(-acc));
    h1_s[h] = acc * sig;
    __syncthreads();
    float acc2 = bt2[h];
    #pragma unroll 8
    for (int k = 0; k < H; k++) acc2 += h1_s[k] * Wt2[k * H + h];
    t_emb[b * H + h] = acc2;
}

// ---------------- weight pre-swizzle into MFMA B-fragment order (bf16) ----------------
__global__ void wswz_kernel(const float* __restrict__ W0, const float* __restrict__ W1,
                            const float* __restrict__ W2, const float* __restrict__ W3,
                            const float* __restrict__ W4, const float* __restrict__ W5,
                            unsigned short* __restrict__ wbuf) {
    const float* Ws[6] = {W0, W1, W2, W3, W4, W5};
    int m = blockIdx.y;
    int t = blockIdx.x * 256 + threadIdx.x;   // 0..4095
    int f = t >> 8, l = (t >> 2) & 63, i = t & 3;
    int kt = f >> 2, ct = f & 3;
    int row = 16 * kt + 4 * (l >> 4) + i;
    int col = 16 * ct + (l & 15);
    wbuf[m * 4096 + t] = f2bf(Ws[m][row * H + col]);
}

// ---------------- node feature init -> bf16-packed x ----------------
__global__ void node_init_kernel(const float* __restrict__ lig_feat,
                                 const float* __restrict__ prot_feat,
                                 const int* __restrict__ lig_batch,
                                 const float* __restrict__ t_emb,
                                 const float* __restrict__ W_lig, const float* __restrict__ b_lig,
                                 const float* __restrict__ W_prot, const float* __restrict__ b_prot,
                                 unsigned int* __restrict__ xb) {
    int node = blockIdx.x * 4 + (threadIdx.x >> 6);
    int h = threadIdx.x & 63;
    if (node >= NTOT) return;
    float acc;
    if (node < NLIG) {
        int b = lig_batch[node];
        acc = b_lig[h] + t_emb[b * H + h];
        #pragma unroll
        for (int k = 0; k < 15; k++)
            acc += lig_feat[node * 15 + k] * W_lig[k * H + h];
    } else {
        int p = node - NLIG;
        acc = b_prot[h];
        #pragma unroll
        for (int k = 0; k < 8; k++)
            acc += prot_feat[p * 8 + k] * W_prot[k * H + h];
    }
    float e0 = __shfl(acc, 2 * (h & 31));
    float e1 = __shfl(acc, 2 * (h & 31) + 1);
    if (h < 32)
        xb[node * 32 + h] = (unsigned int)f2bf(e0) | ((unsigned int)f2bf(e1) << 16);
}

// ---------------- bucketed CSR build (padded buckets: no hist/scan pass) ----------------
// fill: scatter packed (src | dstlow<<18) into per-bucket PADDED regions (b*BCAP).
__global__ __launch_bounds__(1024) void bucket_fill_kernel(const int* __restrict__ edge_index,
                                                           unsigned int* __restrict__ bcursor,
                                                           unsigned int* __restrict__ bucketed) {
    __shared__ unsigned int lh[NBUCK];
    __shared__ unsigned int lcur[NBUCK];
    __shared__ unsigned int gb[NBUCK];
    int tid = threadIdx.x;
    for (int i = tid; i < NBUCK; i += 1024) lh[i] = 0;
    __syncthreads();
    int e0 = blockIdx.x * 8192;
    int src[8], dst[8];
    #pragma unroll
    for (int k = 0; k < 8; k++) {
        src[k] = edge_index[e0 + k * 1024 + tid];
        dst[k] = edge_index[NEDGE + e0 + k * 1024 + tid];
        atomicAdd(&lh[dst[k] >> BSHIFT], 1);
    }
    __syncthreads();
    if (tid < NBUCK) {
        gb[tid] = atomicAdd(&bcursor[tid], lh[tid]);
        lcur[tid] = 0;
    }
    __syncthreads();
    #pragma unroll
    for (int k = 0; k < 8; k++) {
        int b = dst[k] >> BSHIFT;
        unsigned int r = atomicAdd(&lcur[b], 1);
        unsigned int slot = gb[b] + r;
        if (slot < BCAP)
            bucketed[b * BCAP + slot] = (unsigned int)src[k] | ((unsigned int)(dst[k] & 255) << 18);
    }
}

// per-bucket counting sort in LDS -> csr_src + per-node [beg,end)
__global__ __launch_bounds__(512) void bucket_csr_kernel(const unsigned int* __restrict__ bucketed,
                                                         const unsigned int* __restrict__ bcursor,
                                                         int* __restrict__ off,
                                                         int* __restrict__ ends,
                                                         int* __restrict__ csr_src) {
    __shared__ unsigned int stage[BCAP];   // 18 KB packed
    __shared__ unsigned int csr_l[BCAP];   // 18 KB
    __shared__ unsigned int lh[256];
    __shared__ unsigned int lbeg[512];
    __shared__ unsigned int lcur[256];
    int b = blockIdx.x, tid = threadIdx.x;
    unsigned int base = (unsigned int)b * BCAP;
    int cnt = (int)bcursor[b];
    if (cnt > BCAP) cnt = BCAP;   // 16-sigma guard, never triggers
    for (int i = tid; i < 256; i += 512) lh[i] = 0;
    __syncthreads();
    for (int i = tid; i < cnt; i += 512) {
        unsigned int v = bucketed[base + i];
        stage[i] = v;
        atomicAdd(&lh[v >> 18], 1);
    }
    __syncthreads();
    unsigned int own = (tid < 256) ? lh[tid] : 0;
    lbeg[tid] = own;
    __syncthreads();
    for (int d = 1; d < 512; d <<= 1) {
        unsigned int v = (tid >= d) ? lbeg[tid - d] : 0;
        __syncthreads();
        lbeg[tid] += v;
        __syncthreads();
    }
    unsigned int excl = lbeg[tid] - own;
    __syncthreads();
    lbeg[tid] = excl;
    if (tid < 256) {
        lcur[tid] = excl;
        off[b * 256 + tid]  = (int)(base + excl);
        ends[b * 256 + tid] = (int)(base + excl + own);
    }
    __syncthreads();
    for (int i = tid; i < cnt; i += 512) {
        unsigned int v = stage[i];
        unsigned int p = atomicAdd(&lcur[v >> 18], 1);
        csr_l[p] = v & 0x3ffffu;
    }
    __syncthreads();
    for (int i = tid; i < cnt; i += 512)
        csr_src[base + i] = (int)csr_l[i];
}

// ---------------- fused conv: persistent waves + dynamic chunk stealing ----------------
// Grid = 1024 blocks x 512 thr (4 blocks/CU resident). Each wave pulls 16-node
// chunks from a global counter until NCHUNK exhausted -> no dispatch tail.
// All phases (gather, MFMA, epilogue, writeout) are wave-local; the only
// block-wide barrier is the one-time weight-LDS load.
__global__ __launch_bounds__(512, 8) void conv_kernel(const int* __restrict__ off,
                                                      const int* __restrict__ ends,
                                                      const int* __restrict__ csr,
                                                      const unsigned int* __restrict__ xb,
                                                      const unsigned short* __restrict__ wbuf,
                                                      const float* __restrict__ brel,
                                                      unsigned int* __restrict__ xob,
                                                      int* __restrict__ wcnt) {
    __shared__ unsigned int wlds[4096];            // 16 KB: rel frags [0,2048), root [2048,4096)
    __shared__ unsigned short agg_s[128 * 72];     // 18 KB, padded rows; wave w owns rows [16w,16w+16)
    const int tid = threadIdx.x;
    const int w = tid >> 6, l = tid & 63;
    const unsigned int* wsrc = (const unsigned int*)wbuf;
    #pragma unroll
    for (int i = 0; i < 8; i++) wlds[i * 512 + tid] = wsrc[i * 512 + tid];
    __syncthreads();

    const int s = l >> 3, q = l & 7;
    const int lrow = l & 15, g16 = l >> 4, g4 = 4 * (l >> 4);
    float bv[4];
    #pragma unroll
    for (int ct = 0; ct < 4; ct++) bv[ct] = brel[ct * 16 + lrow];

    for (;;) {
        int chunk = 0;
        if (l == 0) chunk = atomicAdd(wcnt, 1);
        chunk = __builtin_amdgcn_readfirstlane(chunk);
        if (chunk >= NCHUNK) break;
        const int node0w = chunk * 16;

        int bvv = (l < 16) ? off[node0w + l] : 0;
        int evv = (l < 16) ? ends[node0w + l] : 0;

        #pragma unroll
        for (int g = 0; g < 2; g++) {
            int beg = __shfl(bvv, g * 8 + s);
            int end = __shfl(evv, g * 8 + s);
            int deg = end - beg;
            float a0 = 0.f, a1 = 0.f, a2 = 0.f, a3 = 0.f;
            float a4 = 0.f, a5 = 0.f, a6 = 0.f, a7 = 0.f;
            for (int j = 0; j < deg; j += 4) {
                int n0 = csr[beg + j];
                int n1 = (j + 1 < deg) ? csr[beg + j + 1] : -1;
                int n2 = (j + 2 < deg) ? csr[beg + j + 2] : -1;
                int n3 = (j + 3 < deg) ? csr[beg + j + 3] : -1;
                {
                    uint4 u = *(const uint4*)&xb[n0 * 32 + q * 4];
                    a0 += bflo(u.x); a1 += bfhi(u.x);
                    a2 += bflo(u.y); a3 += bfhi(u.y);
                    a4 += bflo(u.z); a5 += bfhi(u.z);
                    a6 += bflo(u.w); a7 += bfhi(u.w);
                }
                if (n1 >= 0) {
                    uint4 u = *(const uint4*)&xb[n1 * 32 + q * 4];
                    a0 += bflo(u.x); a1 += bfhi(u.x);
                    a2 += bflo(u.y); a3 += bfhi(u.y);
                    a4 += bflo(u.z); a5 += bfhi(u.z);
                    a6 += bflo(u.w); a7 += bfhi(u.w);
                }
                if (n2 >= 0) {
                    uint4 u = *(const uint4*)&xb[n2 * 32 + q * 4];
                    a0 += bflo(u.x); a1 += bfhi(u.x);
                    a2 += bflo(u.y); a3 += bfhi(u.y);
                    a4 += bflo(u.z); a5 += bfhi(u.z);
                    a6 += bflo(u.w); a7 += bfhi(u.w);
                }
                if (n3 >= 0) {
                    uint4 u = *(const uint4*)&xb[n3 * 32 + q * 4];
                    a0 += bflo(u.x); a1 += bfhi(u.x);
                    a2 += bflo(u.y); a3 += bfhi(u.y);
                    a4 += bflo(u.z); a5 += bfhi(u.z);
                    a6 += bflo(u.w); a7 += bfhi(u.w);
                }
            }
            unsigned int p0 = (unsigned int)f2bf(a0) | ((unsigned int)f2bf(a1) << 16);
            unsigned int p1 = (unsigned int)f2bf(a2) | ((unsigned int)f2bf(a3) << 16);
            unsigned int p2 = (unsigned int)f2bf(a4) | ((unsigned int)f2bf(a5) << 16);
            unsigned int p3 = (unsigned int)f2bf(a6) | ((unsigned int)f2bf(a7) << 16);
            *(uint4*)&agg_s[(w * 16 + g * 8 + s) * 72 + q * 8] = make_uint4(p0, p1, p2, p3);
        }
        __builtin_amdgcn_wave_barrier();   // wave-local LDS ordering fence

        // ---- MFMA phase ----
        v4s ax[4];
        #pragma unroll
        for (int kt = 0; kt < 4; kt++)
            ax[kt] = *(const v4s*)&xb[(node0w + lrow) * 32 + kt * 8 + g16 * 2];
        v4f acc[4];
        #pragma unroll
        for (int ct = 0; ct < 4; ct++) acc[ct] = (v4f){0.f, 0.f, 0.f, 0.f};
        #pragma unroll
        for (int kt = 0; kt < 4; kt++) {
            v4s a_agg = *(const v4s*)&agg_s[(w * 16 + lrow) * 72 + kt * 16 + g4];
            #pragma unroll
            for (int ct = 0; ct < 4; ct++) {
                int f = kt * 4 + ct;
                v4s wr = *(const v4s*)&wlds[f * 128 + l * 2];
                v4s wo = *(const v4s*)&wlds[2048 + f * 128 + l * 2];
                acc[ct] = __builtin_amdgcn_mfma_f32_16x16x16bf16_1k(a_agg, wr, acc[ct], 0, 0, 0);
                acc[ct] = __builtin_amdgcn_mfma_f32_16x16x16bf16_1k(ax[kt], wo, acc[ct], 0, 0, 0);
            }
        }
        __builtin_amdgcn_wave_barrier();

        // ---- epilogue into own agg rows ----
        #pragma unroll
        for (int ct = 0; ct < 4; ct++) {
            #pragma unroll
            for (int r = 0; r < 4; r++)
                agg_s[(w * 16 + g4 + r) * 72 + ct * 16 + lrow] = f2bf(acc[ct][r] + bv[ct]);
        }
        __builtin_amdgcn_wave_barrier();

        // ---- wave-local coalesced writeout: 16 rows x 128 B ----
        {
            int row = l >> 2, qq = l & 3;
            const unsigned int* srcp = (const unsigned int*)&agg_s[(w * 16 + row) * 72 + qq * 16];
            uint4 v0 = *(const uint4*)(srcp);
            uint4 v1 = *(const uint4*)(srcp + 4);
            *(uint4*)&xob[(node0w + row) * 32 + qq * 8] = v0;
            *(uint4*)&xob[(node0w + row) * 32 + qq * 8 + 4] = v1;
        }
        __builtin_amdgcn_wave_barrier();
    }
}

// ---------------- ligand pooling (bf16 x) ----------------
__global__ void pool_kernel(const unsigned int* __restrict__ xb,
                            const int* __restrict__ lig_batch,
                            float* __restrict__ pooled, float* __restrict__ cnt) {
    int node = blockIdx.x * 4 + (threadIdx.x >> 6);
    int h = threadIdx.x & 63;
    if (node >= NLIG) return;
    int b = lig_batch[node];
    unsigned int u = xb[node * 32 + (h >> 1)];
    float v = bf2f((unsigned short)((h & 1) ? (u >> 16) : (u & 0xffffu)));
    unsafeAtomicAdd(&pooled[b * H + h], v);
    if (h == 0) unsafeAtomicAdd(&cnt[b], 1.0f);
}

// ---------------- readout ----------------
__global__ void readout_kernel(const float* __restrict__ pooled, const float* __restrict__ cnt,
                               const float* __restrict__ Wro1, const float* __restrict__ bro1,
                               const float* __restrict__ Wro2, const float* __restrict__ bro2,
                               float* __restrict__ out) {
    __shared__ float pm[4][H];
    int w = threadIdx.x >> 6;
    int h = threadIdx.x & 63;
    int b = blockIdx.x * 4 + w;
    float c = fmaxf(cnt[b], 1.0f);
    pm[w][h] = pooled[b * H + h] / c;
    __syncthreads();
    float acc = bro1[h];
    #pragma unroll 8
    for (int k = 0; k < H; k++) acc += pm[w][k] * Wro1[k * H + h];
    float sig = 1.0f / (1.0f + expf(-acc));
    float s = acc * sig;
    float r = s * Wro2[h];
    #pragma unroll
    for (int off = 32; off; off >>= 1) r += __shfl_down(r, off);
    if (h == 0) out[b] = r + bro2[0];
}

extern "C" void kernel_launch(void* const* d_in, const int* in_sizes, int n_in,
                              void* d_out, int out_size, void* d_ws, size_t ws_size,
                              hipStream_t stream) {
    const float* lig_feat  = (const float*)d_in[1];
    const float* prot_feat = (const float*)d_in[3];
    const float* t         = (const float*)d_in[4];
    const int*   lig_batch = (const int*)d_in[5];
    const int*   edge_index= (const int*)d_in[7];
    const float* W_lig  = (const float*)d_in[8];
    const float* b_lig  = (const float*)d_in[9];
    const float* W_prot = (const float*)d_in[10];
    const float* b_prot = (const float*)d_in[11];
    const float* Wt1 = (const float*)d_in[12];
    const float* bt1 = (const float*)d_in[13];
    const float* Wt2 = (const float*)d_in[14];
    const float* bt2 = (const float*)d_in[15];
    const float* Wrel[3]  = {(const float*)d_in[16], (const float*)d_in[19], (const float*)d_in[22]};
    const float* brel[3]  = {(const float*)d_in[17], (const float*)d_in[20], (const float*)d_in[23]};
    const float* Wroot[3] = {(const float*)d_in[18], (const float*)d_in[21], (const float*)d_in[24]};
    const float* Wro1 = (const float*)d_in[25];
    const float* bro1 = (const float*)d_in[26];
    const float* Wro2 = (const float*)d_in[27];
    const float* bro2 = (const float*)d_in[28];
    float* out = (float*)d_out;

    char* ws = (char*)d_ws;
    int*            off_a   = (int*)(ws);                       // NTOT ints (0.59 MB)
    int*            ends_a  = (int*)(ws + 655360);              // NTOT ints
    unsigned int*   bcursor = (unsigned int*)(ws + 1310720);    // 576 * 4 = 2304 B
    int*            wcnt    = (int*)(ws + 1313024);             // 3 ints
    float*          t_emb   = (float*)(ws + 1376256);
    float*          pooled  = (float*)(ws + 1441792);
    float*          cnt     = (float*)(ws + 1507328);
    unsigned short* wbuf    = (unsigned short*)(ws + 1572864);  // 48 KB
    int*            csr_src = (int*)(ws + 2097152);             // 10.6 MB padded
    unsigned int*   bucketed= (unsigned int*)(ws + 14680064);   // 10.6 MB padded
    unsigned int*   xb0     = (unsigned int*)(ws + 27262976);   // 18 MB
    unsigned int*   xb1     = (unsigned int*)(ws + 46137344);   // 18 MB
    unsigned int*   xbs[2]  = {xb0, xb1};

    time_mlp_kernel<<<NB, H, 0, stream>>>(t, Wt1, bt1, Wt2, bt2, t_emb);
    wswz_kernel<<<dim3(16, 6), 256, 0, stream>>>(Wrel[0], Wroot[0], Wrel[1], Wroot[1],
                                                 Wrel[2], Wroot[2], wbuf);
    node_init_kernel<<<NTOT / 4, 256, 0, stream>>>(lig_feat, prot_feat, lig_batch, t_emb,
                                                   W_lig, b_lig, W_prot, b_prot, xb0);

    // ---- padded-bucket CSR build (zero bcursor + wcnt in one memset) ----
    hipMemsetAsync(bcursor, 0, 2304 + 64, stream);
    bucket_fill_kernel<<<NEDGE / 8192, 1024, 0, stream>>>(edge_index, bcursor, bucketed);
    bucket_csr_kernel<<<NBUCK, 512, 0, stream>>>(bucketed, bcursor, off_a, ends_a, csr_src);

    // ---- 3 fused graph convs (persistent, dynamic chunks) ----
    for (int lyr = 0; lyr < 3; lyr++) {
        unsigned int* cur = xbs[lyr & 1];
        unsigned int* nxt = xbs[(lyr + 1) & 1];
        conv_kernel<<<1024, 512, 0, stream>>>(off_a, ends_a, csr_src, cur,
                                              wbuf + lyr * 8192, brel[lyr], nxt, wcnt + lyr);
    }
    unsigned int* xfin = xbs[1];

    hipMemsetAsync(pooled, 0, (size_t)(NB * H + NB) * sizeof(float), stream);
    pool_kernel<<<NLIG / 4, 256, 0, stream>>>(xfin, lig_batch, pooled, cnt);
    readout_kernel<<<NB / 4, 256, 0, stream>>>(pooled, cnt, Wro1, bro1, Wro2, bro2, out);
}

// Round 8
// 405.482 us; speedup vs baseline: 1.9898x; 1.9898x over previous
//
#include <hip/hip_runtime.h>
#include <math.h>

#define NLIG 16384
#define NPROT 131072
#define NTOT (NLIG + NPROT)
#define NEDGE 2097152
#define NB 256
#define H 64
#define NBUCK 576      // NTOT = 576 * 256
#define BSHIFT 8       // bucket = dst >> 8
#define BCAP 4608      // padded bucket capacity (avg 3641, sd ~60 -> 16 sigma)
#define NCHUNK (NTOT / 16)   // 9216 16-node chunks
#define NSTATIC 8192         // chunks 0..8191 statically owned by the 8192 waves
#define POOLPER 128          // (NCHUNK - NSTATIC) / 8 pool chunks per wave-slot

typedef short v4s __attribute__((ext_vector_type(4)));
typedef float v4f __attribute__((ext_vector_type(4)));

__device__ __forceinline__ unsigned short f2bf(float f) {
    unsigned int u = __float_as_uint(f);
    u += 0x7fff + ((u >> 16) & 1);   // RNE
    return (unsigned short)(u >> 16);
}
__device__ __forceinline__ float bf2f(unsigned short s) {
    return __uint_as_float(((unsigned int)s) << 16);
}
__device__ __forceinline__ float bflo(unsigned int u) {
    return __uint_as_float(u << 16);
}
__device__ __forceinline__ float bfhi(unsigned int u) {
    return __uint_as_float(u & 0xffff0000u);
}

// ---------------- time embedding MLP ----------------
__global__ void time_mlp_kernel(const float* __restrict__ t,
                                const float* __restrict__ Wt1, const float* __restrict__ bt1,
                                const float* __restrict__ Wt2, const float* __restrict__ bt2,
                                float* __restrict__ t_emb) {
    int b = blockIdx.x;
    int h = threadIdx.x;
    __shared__ float emb_s[H];
    __shared__ float h1_s[H];
    float tv = t[b];
    int i = h & 31;
    float freq = expf((float)i * (-9.2103403719761836f / 31.0f));
    float e = tv * freq;
    emb_s[h] = (h < 32) ? sinf(e) : cosf(e);
    __syncthreads();
    float acc = bt1[h];
    #pragma unroll 8
    for (int k = 0; k < H; k++) acc += emb_s[k] * Wt1[k * H + h];
    float sig = 1.0f / (1.0f + expf(-acc));
    h1_s[h] = acc * sig;
    __syncthreads();
    float acc2 = bt2[h];
    #pragma unroll 8
    for (int k = 0; k < H; k++) acc2 += h1_s[k] * Wt2[k * H + h];
    t_emb[b * H + h] = acc2;
}

// ---------------- weight pre-swizzle into MFMA B-fragment order (bf16) ----------------
__global__ void wswz_kernel(const float* __restrict__ W0, const float* __restrict__ W1,
                            const float* __restrict__ W2, const float* __restrict__ W3,
                            const float* __restrict__ W4, const float* __restrict__ W5,
                            unsigned short* __restrict__ wbuf) {
    const float* Ws[6] = {W0, W1, W2, W3, W4, W5};
    int m = blockIdx.y;
    int t = blockIdx.x * 256 + threadIdx.x;   // 0..4095
    int f = t >> 8, l = (t >> 2) & 63, i = t & 3;
    int kt = f >> 2, ct = f & 3;
    int row = 16 * kt + 4 * (l >> 4) + i;
    int col = 16 * ct + (l & 15);
    wbuf[m * 4096 + t] = f2bf(Ws[m][row * H + col]);
}

// ---------------- node feature init -> bf16-packed x ----------------
__global__ void node_init_kernel(const float* __restrict__ lig_feat,
                                 const float* __restrict__ prot_feat,
                                 const int* __restrict__ lig_batch,
                                 const float* __restrict__ t_emb,
                                 const float* __restrict__ W_lig, const float* __restrict__ b_lig,
                                 const float* __restrict__ W_prot, const float* __restrict__ b_prot,
                                 unsigned int* __restrict__ xb) {
    int node = blockIdx.x * 4 + (threadIdx.x >> 6);
    int h = threadIdx.x & 63;
    if (node >= NTOT) return;
    float acc;
    if (node < NLIG) {
        int b = lig_batch[node];
        acc = b_lig[h] + t_emb[b * H + h];
        #pragma unroll
        for (int k = 0; k < 15; k++)
            acc += lig_feat[node * 15 + k] * W_lig[k * H + h];
    } else {
        int p = node - NLIG;
        acc = b_prot[h];
        #pragma unroll
        for (int k = 0; k < 8; k++)
            acc += prot_feat[p * 8 + k] * W_prot[k * H + h];
    }
    float e0 = __shfl(acc, 2 * (h & 31));
    float e1 = __shfl(acc, 2 * (h & 31) + 1);
    if (h < 32)
        xb[node * 32 + h] = (unsigned int)f2bf(e0) | ((unsigned int)f2bf(e1) << 16);
}

// ---------------- bucketed CSR build (padded buckets: no hist/scan pass) ----------------
__global__ __launch_bounds__(1024) void bucket_fill_kernel(const int* __restrict__ edge_index,
                                                           unsigned int* __restrict__ bcursor,
                                                           unsigned int* __restrict__ bucketed) {
    __shared__ unsigned int lh[NBUCK];
    __shared__ unsigned int lcur[NBUCK];
    __shared__ unsigned int gb[NBUCK];
    int tid = threadIdx.x;
    for (int i = tid; i < NBUCK; i += 1024) lh[i] = 0;
    __syncthreads();
    int e0 = blockIdx.x * 8192;
    int src[8], dst[8];
    #pragma unroll
    for (int k = 0; k < 8; k++) {
        src[k] = edge_index[e0 + k * 1024 + tid];
        dst[k] = edge_index[NEDGE + e0 + k * 1024 + tid];
        atomicAdd(&lh[dst[k] >> BSHIFT], 1);
    }
    __syncthreads();
    if (tid < NBUCK) {
        gb[tid] = atomicAdd(&bcursor[tid], lh[tid]);
        lcur[tid] = 0;
    }
    __syncthreads();
    #pragma unroll
    for (int k = 0; k < 8; k++) {
        int b = dst[k] >> BSHIFT;
        unsigned int r = atomicAdd(&lcur[b], 1);
        unsigned int slot = gb[b] + r;
        if (slot < BCAP)
            bucketed[b * BCAP + slot] = (unsigned int)src[k] | ((unsigned int)(dst[k] & 255) << 18);
    }
}

// per-bucket counting sort in LDS -> csr_src + per-node [beg,end)
__global__ __launch_bounds__(512) void bucket_csr_kernel(const unsigned int* __restrict__ bucketed,
                                                         const unsigned int* __restrict__ bcursor,
                                                         int* __restrict__ off,
                                                         int* __restrict__ ends,
                                                         int* __restrict__ csr_src) {
    __shared__ unsigned int stage[BCAP];   // 18 KB packed
    __shared__ unsigned int csr_l[BCAP];   // 18 KB
    __shared__ unsigned int lh[256];
    __shared__ unsigned int lbeg[512];
    __shared__ unsigned int lcur[256];
    int b = blockIdx.x, tid = threadIdx.x;
    unsigned int base = (unsigned int)b * BCAP;
    int cnt = (int)bcursor[b];
    if (cnt > BCAP) cnt = BCAP;   // 16-sigma guard, never triggers
    for (int i = tid; i < 256; i += 512) lh[i] = 0;
    __syncthreads();
    for (int i = tid; i < cnt; i += 512) {
        unsigned int v = bucketed[base + i];
        stage[i] = v;
        atomicAdd(&lh[v >> 18], 1);
    }
    __syncthreads();
    unsigned int own = (tid < 256) ? lh[tid] : 0;
    lbeg[tid] = own;
    __syncthreads();
    for (int d = 1; d < 512; d <<= 1) {
        unsigned int v = (tid >= d) ? lbeg[tid - d] : 0;
        __syncthreads();
        lbeg[tid] += v;
        __syncthreads();
    }
    unsigned int excl = lbeg[tid] - own;
    __syncthreads();
    lbeg[tid] = excl;
    if (tid < 256) {
        lcur[tid] = excl;
        off[b * 256 + tid]  = (int)(base + excl);
        ends[b * 256 + tid] = (int)(base + excl + own);
    }
    __syncthreads();
    for (int i = tid; i < cnt; i += 512) {
        unsigned int v = stage[i];
        unsigned int p = atomicAdd(&lcur[v >> 18], 1);
        csr_l[p] = v & 0x3ffffu;
    }
    __syncthreads();
    for (int i = tid; i < cnt; i += 512)
        csr_src[base + i] = (int)csr_l[i];
}

// ---------------- fused conv: static-first chunks + tiny pipelined pool ----------------
// Grid = exactly 1024 blocks x 512 thr (4 blocks/CU -> 32 waves/CU, full residency).
// Wave gwid statically owns chunk gwid (no atomic). The 1024 remainder chunks sit
// in 8 per-wave-slot pools (256B-spaced counters). The pool grab for the NEXT
// chunk is issued before processing the current one, so its latency (and the
// vmcnt drain its readfirstlane implies) hides under the gather work.
__global__ __launch_bounds__(512, 8) void conv_kernel(const int* __restrict__ off,
                                                      const int* __restrict__ ends,
                                                      const int* __restrict__ csr,
                                                      const unsigned int* __restrict__ xb,
                                                      const unsigned short* __restrict__ wbuf,
                                                      const float* __restrict__ brel,
                                                      unsigned int* __restrict__ xob,
                                                      int* __restrict__ pools) {
    __shared__ unsigned int wlds[4096];            // 16 KB: rel frags [0,2048), root [2048,4096)
    __shared__ unsigned short agg_s[128 * 72];     // 18 KB; wave w owns rows [16w,16w+16)
    const int tid = threadIdx.x;
    const int w = tid >> 6, l = tid & 63;
    const unsigned int* wsrc = (const unsigned int*)wbuf;
    #pragma unroll
    for (int i = 0; i < 8; i++) wlds[i * 512 + tid] = wsrc[i * 512 + tid];

    const int s = l >> 3, q = l & 7;
    const int lrow = l & 15, g16 = l >> 4, g4 = 4 * (l >> 4);

    // first pool grab issued immediately (overlaps wlds load + barrier + first gather)
    int nxt_i = 0;
    if (l == 0) nxt_i = atomicAdd(&pools[w * 64], 1);
    nxt_i = __builtin_amdgcn_readfirstlane(nxt_i);
    int nxt = (nxt_i < POOLPER) ? (NSTATIC + w * POOLPER + nxt_i) : NCHUNK;

    __syncthreads();   // wlds ready

    float bv[4];
    #pragma unroll
    for (int ct = 0; ct < 4; ct++) bv[ct] = brel[ct * 16 + lrow];

    int chunk = blockIdx.x * 8 + w;   // static chunk, 0..8191

    for (;;) {
        const int node0w = chunk * 16;
        int bvv = (l < 16) ? off[node0w + l] : 0;
        int evv = (l < 16) ? ends[node0w + l] : 0;

        #pragma unroll
        for (int g = 0; g < 2; g++) {
            int beg = __shfl(bvv, g * 8 + s);
            int end = __shfl(evv, g * 8 + s);
            int deg = end - beg;
            float a0 = 0.f, a1 = 0.f, a2 = 0.f, a3 = 0.f;
            float a4 = 0.f, a5 = 0.f, a6 = 0.f, a7 = 0.f;
            for (int j = 0; j < deg; j += 8) {
                // 8 csr loads (clamped), then 8 gathers in flight, then masked accumulate
                int dm1 = deg - 1;
                int j0 = j     < dm1 ? j     : dm1;
                int j1 = j + 1 < dm1 ? j + 1 : dm1;
                int j2 = j + 2 < dm1 ? j + 2 : dm1;
                int j3 = j + 3 < dm1 ? j + 3 : dm1;
                int j4 = j + 4 < dm1 ? j + 4 : dm1;
                int j5 = j + 5 < dm1 ? j + 5 : dm1;
                int j6 = j + 6 < dm1 ? j + 6 : dm1;
                int j7 = j + 7 < dm1 ? j + 7 : dm1;
                int n0 = csr[beg + j0];
                int n1 = csr[beg + j1];
                int n2 = csr[beg + j2];
                int n3 = csr[beg + j3];
                int n4 = csr[beg + j4];
                int n5 = csr[beg + j5];
                int n6 = csr[beg + j6];
                int n7 = csr[beg + j7];
                uint4 u0 = *(const uint4*)&xb[n0 * 32 + q * 4];
                uint4 u1 = *(const uint4*)&xb[n1 * 32 + q * 4];
                uint4 u2 = *(const uint4*)&xb[n2 * 32 + q * 4];
                uint4 u3 = *(const uint4*)&xb[n3 * 32 + q * 4];
                uint4 u4 = *(const uint4*)&xb[n4 * 32 + q * 4];
                uint4 u5 = *(const uint4*)&xb[n5 * 32 + q * 4];
                uint4 u6 = *(const uint4*)&xb[n6 * 32 + q * 4];
                uint4 u7 = *(const uint4*)&xb[n7 * 32 + q * 4];
                if (j + 1 >= deg) { u1.x = u1.y = u1.z = u1.w = 0; }
                if (j + 2 >= deg) { u2.x = u2.y = u2.z = u2.w = 0; }
                if (j + 3 >= deg) { u3.x = u3.y = u3.z = u3.w = 0; }
                if (j + 4 >= deg) { u4.x = u4.y = u4.z = u4.w = 0; }
                if (j + 5 >= deg) { u5.x = u5.y = u5.z = u5.w = 0; }
                if (j + 6 >= deg) { u6.x = u6.y = u6.z = u6.w = 0; }
                if (j + 7 >= deg) { u7.x = u7.y = u7.z = u7.w = 0; }
                a0 += bflo(u0.x) + bflo(u1.x) + bflo(u2.x) + bflo(u3.x)
                    + bflo(u4.x) + bflo(u5.x) + bflo(u6.x) + bflo(u7.x);
                a1 += bfhi(u0.x) + bfhi(u1.x) + bfhi(u2.x) + bfhi(u3.x)
                    + bfhi(u4.x) + bfhi(u5.x) + bfhi(u6.x) + bfhi(u7.x);
                a2 += bflo(u0.y) + bflo(u1.y) + bflo(u2.y) + bflo(u3.y)
                    + bflo(u4.y) + bflo(u5.y) + bflo(u6.y) + bflo(u7.y);
                a3 += bfhi(u0.y) + bfhi(u1.y) + bfhi(u2.y) + bfhi(u3.y)
                    + bfhi(u4.y) + bfhi(u5.y) + bfhi(u6.y) + bfhi(u7.y);
                a4 += bflo(u0.z) + bflo(u1.z) + bflo(u2.z) + bflo(u3.z)
                    + bflo(u4.z) + bflo(u5.z) + bflo(u6.z) + bflo(u7.z);
                a5 += bfhi(u0.z) + bfhi(u1.z) + bfhi(u2.z) + bfhi(u3.z)
                    + bfhi(u4.z) + bfhi(u5.z) + bfhi(u6.z) + bfhi(u7.z);
                a6 += bflo(u0.w) + bflo(u1.w) + bflo(u2.w) + bflo(u3.w)
                    + bflo(u4.w) + bflo(u5.w) + bflo(u6.w) + bflo(u7.w);
                a7 += bfhi(u0.w) + bfhi(u1.w) + bfhi(u2.w) + bfhi(u3.w)
                    + bfhi(u4.w) + bfhi(u5.w) + bfhi(u6.w) + bfhi(u7.w);
            }
            unsigned int p0 = (unsigned int)f2bf(a0) | ((unsigned int)f2bf(a1) << 16);
            unsigned int p1 = (unsigned int)f2bf(a2) | ((unsigned int)f2bf(a3) << 16);
            unsigned int p2 = (unsigned int)f2bf(a4) | ((unsigned int)f2bf(a5) << 16);
            unsigned int p3 = (unsigned int)f2bf(a6) | ((unsigned int)f2bf(a7) << 16);
            *(uint4*)&agg_s[(w * 16 + g * 8 + s) * 72 + q * 8] = make_uint4(p0, p1, p2, p3);
        }
        __builtin_amdgcn_wave_barrier();

        // ---- MFMA phase ----
        v4s ax[4];
        #pragma unroll
        for (int kt = 0; kt < 4; kt++)
            ax[kt] = *(const v4s*)&xb[(node0w + lrow) * 32 + kt * 8 + g16 * 2];
        v4f acc[4];
        #pragma unroll
        for (int ct = 0; ct < 4; ct++) acc[ct] = (v4f){0.f, 0.f, 0.f, 0.f};
        #pragma unroll
        for (int kt = 0; kt < 4; kt++) {
            v4s a_agg = *(const v4s*)&agg_s[(w * 16 + lrow) * 72 + kt * 16 + g4];
            #pragma unroll
            for (int ct = 0; ct < 4; ct++) {
                int f = kt * 4 + ct;
                v4s wr = *(const v4s*)&wlds[f * 128 + l * 2];
                v4s wo = *(const v4s*)&wlds[2048 + f * 128 + l * 2];
                acc[ct] = __builtin_amdgcn_mfma_f32_16x16x16bf16_1k(a_agg, wr, acc[ct], 0, 0, 0);
                acc[ct] = __builtin_amdgcn_mfma_f32_16x16x16bf16_1k(ax[kt], wo, acc[ct], 0, 0, 0);
            }
        }
        __builtin_amdgcn_wave_barrier();

        // ---- epilogue into own agg rows ----
        #pragma unroll
        for (int ct = 0; ct < 4; ct++) {
            #pragma unroll
            for (int r = 0; r < 4; r++)
                agg_s[(w * 16 + g4 + r) * 72 + ct * 16 + lrow] = f2bf(acc[ct][r] + bv[ct]);
        }
        __builtin_amdgcn_wave_barrier();

        // ---- wave-local coalesced writeout: 16 rows x 128 B ----
        {
            int row = l >> 2, qq = l & 3;
            const unsigned int* srcp = (const unsigned int*)&agg_s[(w * 16 + row) * 72 + qq * 16];
            uint4 v0 = *(const uint4*)(srcp);
            uint4 v1 = *(const uint4*)(srcp + 4);
            *(uint4*)&xob[(node0w + row) * 32 + qq * 8] = v0;
            *(uint4*)&xob[(node0w + row) * 32 + qq * 8 + 4] = v1;
        }
        __builtin_amdgcn_wave_barrier();

        if (nxt >= NCHUNK) break;
        chunk = nxt;
        // pipelined grab for the chunk after this one
        int ni = 0;
        if (l == 0) ni = atomicAdd(&pools[w * 64], 1);
        ni = __builtin_amdgcn_readfirstlane(ni);
        nxt = (ni < POOLPER) ? (NSTATIC + w * POOLPER + ni) : NCHUNK;
    }
}

// ---------------- ligand pooling (bf16 x) ----------------
__global__ void pool_kernel(const unsigned int* __restrict__ xb,
                            const int* __restrict__ lig_batch,
                            float* __restrict__ pooled, float* __restrict__ cnt) {
    int node = blockIdx.x * 4 + (threadIdx.x >> 6);
    int h = threadIdx.x & 63;
    if (node >= NLIG) return;
    int b = lig_batch[node];
    unsigned int u = xb[node * 32 + (h >> 1)];
    float v = bf2f((unsigned short)((h & 1) ? (u >> 16) : (u & 0xffffu)));
    unsafeAtomicAdd(&pooled[b * H + h], v);
    if (h == 0) unsafeAtomicAdd(&cnt[b], 1.0f);
}

// ---------------- readout ----------------
__global__ void readout_kernel(const float* __restrict__ pooled, const float* __restrict__ cnt,
                               const float* __restrict__ Wro1, const float* __restrict__ bro1,
                               const float* __restrict__ Wro2, const float* __restrict__ bro2,
                               float* __restrict__ out) {
    __shared__ float pm[4][H];
    int w = threadIdx.x >> 6;
    int h = threadIdx.x & 63;
    int b = blockIdx.x * 4 + w;
    float c = fmaxf(cnt[b], 1.0f);
    pm[w][h] = pooled[b * H + h] / c;
    __syncthreads();
    float acc = bro1[h];
    #pragma unroll 8
    for (int k = 0; k < H; k++) acc += pm[w][k] * Wro1[k * H + h];
    float sig = 1.0f / (1.0f + expf(-acc));
    float s = acc * sig;
    float r = s * Wro2[h];
    #pragma unroll
    for (int off = 32; off; off >>= 1) r += __shfl_down(r, off);
    if (h == 0) out[b] = r + bro2[0];
}

extern "C" void kernel_launch(void* const* d_in, const int* in_sizes, int n_in,
                              void* d_out, int out_size, void* d_ws, size_t ws_size,
                              hipStream_t stream) {
    const float* lig_feat  = (const float*)d_in[1];
    const float* prot_feat = (const float*)d_in[3];
    const float* t         = (const float*)d_in[4];
    const int*   lig_batch = (const int*)d_in[5];
    const int*   edge_index= (const int*)d_in[7];
    const float* W_lig  = (const float*)d_in[8];
    const float* b_lig  = (const float*)d_in[9];
    const float* W_prot = (const float*)d_in[10];
    const float* b_prot = (const float*)d_in[11];
    const float* Wt1 = (const float*)d_in[12];
    const float* bt1 = (const float*)d_in[13];
    const float* Wt2 = (const float*)d_in[14];
    const float* bt2 = (const float*)d_in[15];
    const float* Wrel[3]  = {(const float*)d_in[16], (const float*)d_in[19], (const float*)d_in[22]};
    const float* brel[3]  = {(const float*)d_in[17], (const float*)d_in[20], (const float*)d_in[23]};
    const float* Wroot[3] = {(const float*)d_in[18], (const float*)d_in[21], (const float*)d_in[24]};
    const float* Wro1 = (const float*)d_in[25];
    const float* bro1 = (const float*)d_in[26];
    const float* Wro2 = (const float*)d_in[27];
    const float* bro2 = (const float*)d_in[28];
    float* out = (float*)d_out;

    char* ws = (char*)d_ws;
    int*            off_a   = (int*)(ws);                       // NTOT ints
    int*            ends_a  = (int*)(ws + 655360);              // NTOT ints
    unsigned int*   bcursor = (unsigned int*)(ws + 1310720);    // 2304 B
    int*            pools   = (int*)(ws + 1313024);             // 3 layers x 8 x 64 ints = 6144 B
    float*          t_emb   = (float*)(ws + 1376256);
    float*          pooled  = (float*)(ws + 1441792);
    float*          cnt     = (float*)(ws + 1507328);
    unsigned short* wbuf    = (unsigned short*)(ws + 1572864);  // 48 KB
    int*            csr_src = (int*)(ws + 2097152);             // 10.6 MB padded
    unsigned int*   bucketed= (unsigned int*)(ws + 14680064);   // 10.6 MB padded
    unsigned int*   xb0     = (unsigned int*)(ws + 27262976);   // 18 MB
    unsigned int*   xb1     = (unsigned int*)(ws + 46137344);   // 18 MB
    unsigned int*   xbs[2]  = {xb0, xb1};

    time_mlp_kernel<<<NB, H, 0, stream>>>(t, Wt1, bt1, Wt2, bt2, t_emb);
    wswz_kernel<<<dim3(16, 6), 256, 0, stream>>>(Wrel[0], Wroot[0], Wrel[1], Wroot[1],
                                                 Wrel[2], Wroot[2], wbuf);
    node_init_kernel<<<NTOT / 4, 256, 0, stream>>>(lig_feat, prot_feat, lig_batch, t_emb,
                                                   W_lig, b_lig, W_prot, b_prot, xb0);

    // ---- padded-bucket CSR build (zero bcursor + pools in one memset) ----
    hipMemsetAsync(bcursor, 0, 2304 + 6144, stream);
    bucket_fill_kernel<<<NEDGE / 8192, 1024, 0, stream>>>(edge_index, bcursor, bucketed);
    bucket_csr_kernel<<<NBUCK, 512, 0, stream>>>(bucketed, bcursor, off_a, ends_a, csr_src);

    // ---- 3 fused graph convs (static-first + pipelined pool) ----
    for (int lyr = 0; lyr < 3; lyr++) {
        unsigned int* cur = xbs[lyr & 1];
        unsigned int* nxt = xbs[(lyr + 1) & 1];
        conv_kernel<<<1024, 512, 0, stream>>>(off_a, ends_a, csr_src, cur,
                                              wbuf + lyr * 8192, brel[lyr], nxt,
                                              pools + lyr * 512);
    }
    unsigned int* xfin = xbs[1];

    hipMemsetAsync(pooled, 0, (size_t)(NB * H + NB) * sizeof(float), stream);
    pool_kernel<<<NLIG / 4, 256, 0, stream>>>(xfin, lig_batch, pooled, cnt);
    readout_kernel<<<NB / 4, 256, 0, stream>>>(pooled, cnt, Wro1, bro1, Wro2, bro2, out);
}

// Round 9
// 330.137 us; speedup vs baseline: 2.4439x; 1.2282x over previous
//
#include <hip/hip_runtime.h>
#include <math.h>

#define NLIG 16384
#define NPROT 131072
#define NTOT (NLIG + NPROT)
#define NEDGE 2097152
#define NB 256
#define H 64
#define NBUCK 576      // NTOT = 576 * 256
#define BSHIFT 8       // bucket = dst >> 8
#define BCAP 4608      // padded bucket capacity (avg 3641, sd ~60 -> 16 sigma)
#define NCHUNK (NTOT / 16)   // 9216 16-node chunks
#define NSTATIC 8192         // chunks 0..8191 statically owned by the 8192 waves
#define POOLPER 128          // (NCHUNK - NSTATIC) / 8 pool chunks per wave-slot

typedef short v4s __attribute__((ext_vector_type(4)));
typedef float v4f __attribute__((ext_vector_type(4)));

__device__ __forceinline__ unsigned short f2bf(float f) {
    unsigned int u = __float_as_uint(f);
    u += 0x7fff + ((u >> 16) & 1);   // RNE
    return (unsigned short)(u >> 16);
}
__device__ __forceinline__ float bf2f(unsigned short s) {
    return __uint_as_float(((unsigned int)s) << 16);
}
__device__ __forceinline__ float bflo(unsigned int u) {
    return __uint_as_float(u << 16);
}
__device__ __forceinline__ float bfhi(unsigned int u) {
    return __uint_as_float(u & 0xffff0000u);
}

// ---------------- time embedding MLP ----------------
__global__ void time_mlp_kernel(const float* __restrict__ t,
                                const float* __restrict__ Wt1, const float* __restrict__ bt1,
                                const float* __restrict__ Wt2, const float* __restrict__ bt2,
                                float* __restrict__ t_emb) {
    int b = blockIdx.x;
    int h = threadIdx.x;
    __shared__ float emb_s[H];
    __shared__ float h1_s[H];
    float tv = t[b];
    int i = h & 31;
    float freq = expf((float)i * (-9.2103403719761836f / 31.0f));
    float e = tv * freq;
    emb_s[h] = (h < 32) ? sinf(e) : cosf(e);
    __syncthreads();
    float acc = bt1[h];
    #pragma unroll 8
    for (int k = 0; k < H; k++) acc += emb_s[k] * Wt1[k * H + h];
    float sig = 1.0f / (1.0f + expf(-acc));
    h1_s[h] = acc * sig;
    __syncthreads();
    float acc2 = bt2[h];
    #pragma unroll 8
    for (int k = 0; k < H; k++) acc2 += h1_s[k] * Wt2[k * H + h];
    t_emb[b * H + h] = acc2;
}

// ---------------- weight pre-swizzle into MFMA B-fragment order (bf16) ----------------
__global__ void wswz_kernel(const float* __restrict__ W0, const float* __restrict__ W1,
                            const float* __restrict__ W2, const float* __restrict__ W3,
                            const float* __restrict__ W4, const float* __restrict__ W5,
                            unsigned short* __restrict__ wbuf) {
    const float* Ws[6] = {W0, W1, W2, W3, W4, W5};
    int m = blockIdx.y;
    int t = blockIdx.x * 256 + threadIdx.x;   // 0..4095
    int f = t >> 8, l = (t >> 2) & 63, i = t & 3;
    int kt = f >> 2, ct = f & 3;
    int row = 16 * kt + 4 * (l >> 4) + i;
    int col = 16 * ct + (l & 15);
    wbuf[m * 4096 + t] = f2bf(Ws[m][row * H + col]);
}

// ---------------- node feature init -> bf16-packed x ----------------
__global__ void node_init_kernel(const float* __restrict__ lig_feat,
                                 const float* __restrict__ prot_feat,
                                 const int* __restrict__ lig_batch,
                                 const float* __restrict__ t_emb,
                                 const float* __restrict__ W_lig, const float* __restrict__ b_lig,
                                 const float* __restrict__ W_prot, const float* __restrict__ b_prot,
                                 unsigned int* __restrict__ xb) {
    int node = blockIdx.x * 4 + (threadIdx.x >> 6);
    int h = threadIdx.x & 63;
    if (node >= NTOT) return;
    float acc;
    if (node < NLIG) {
        int b = lig_batch[node];
        acc = b_lig[h] + t_emb[b * H + h];
        #pragma unroll
        for (int k = 0; k < 15; k++)
            acc += lig_feat[node * 15 + k] * W_lig[k * H + h];
    } else {
        int p = node - NLIG;
        acc = b_prot[h];
        #pragma unroll
        for (int k = 0; k < 8; k++)
            acc += prot_feat[p * 8 + k] * W_prot[k * H + h];
    }
    float e0 = __shfl(acc, 2 * (h & 31));
    float e1 = __shfl(acc, 2 * (h & 31) + 1);
    if (h < 32)
        xb[node * 32 + h] = (unsigned int)f2bf(e0) | ((unsigned int)f2bf(e1) << 16);
}

// ---------------- bucketed CSR build (padded buckets: no hist/scan pass) ----------------
__global__ __launch_bounds__(1024) void bucket_fill_kernel(const int* __restrict__ edge_index,
                                                           unsigned int* __restrict__ bcursor,
                                                           unsigned int* __restrict__ bucketed) {
    __shared__ unsigned int lh[NBUCK];
    __shared__ unsigned int lcur[NBUCK];
    __shared__ unsigned int gb[NBUCK];
    int tid = threadIdx.x;
    for (int i = tid; i < NBUCK; i += 1024) lh[i] = 0;
    __syncthreads();
    int e0 = blockIdx.x * 8192;
    int src[8], dst[8];
    #pragma unroll
    for (int k = 0; k < 8; k++) {
        src[k] = edge_index[e0 + k * 1024 + tid];
        dst[k] = edge_index[NEDGE + e0 + k * 1024 + tid];
        atomicAdd(&lh[dst[k] >> BSHIFT], 1);
    }
    __syncthreads();
    if (tid < NBUCK) {
        gb[tid] = atomicAdd(&bcursor[tid], lh[tid]);
        lcur[tid] = 0;
    }
    __syncthreads();
    #pragma unroll
    for (int k = 0; k < 8; k++) {
        int b = dst[k] >> BSHIFT;
        unsigned int r = atomicAdd(&lcur[b], 1);
        unsigned int slot = gb[b] + r;
        if (slot < BCAP)
            bucketed[b * BCAP + slot] = (unsigned int)src[k] | ((unsigned int)(dst[k] & 255) << 18);
    }
}

// per-bucket counting sort in LDS -> csr_src + per-node [beg,end)
__global__ __launch_bounds__(512) void bucket_csr_kernel(const unsigned int* __restrict__ bucketed,
                                                         const unsigned int* __restrict__ bcursor,
                                                         int* __restrict__ off,
                                                         int* __restrict__ ends,
                                                         int* __restrict__ csr_src) {
    __shared__ unsigned int stage[BCAP];   // 18 KB packed
    __shared__ unsigned int csr_l[BCAP];   // 18 KB
    __shared__ unsigned int lh[256];
    __shared__ unsigned int lbeg[512];
    __shared__ unsigned int lcur[256];
    int b = blockIdx.x, tid = threadIdx.x;
    unsigned int base = (unsigned int)b * BCAP;
    int cnt = (int)bcursor[b];
    if (cnt > BCAP) cnt = BCAP;   // 16-sigma guard, never triggers
    for (int i = tid; i < 256; i += 512) lh[i] = 0;
    __syncthreads();
    for (int i = tid; i < cnt; i += 512) {
        unsigned int v = bucketed[base + i];
        stage[i] = v;
        atomicAdd(&lh[v >> 18], 1);
    }
    __syncthreads();
    unsigned int own = (tid < 256) ? lh[tid] : 0;
    lbeg[tid] = own;
    __syncthreads();
    for (int d = 1; d < 512; d <<= 1) {
        unsigned int v = (tid >= d) ? lbeg[tid - d] : 0;
        __syncthreads();
        lbeg[tid] += v;
        __syncthreads();
    }
    unsigned int excl = lbeg[tid] - own;
    __syncthreads();
    lbeg[tid] = excl;
    if (tid < 256) {
        lcur[tid] = excl;
        off[b * 256 + tid]  = (int)(base + excl);
        ends[b * 256 + tid] = (int)(base + excl + own);
    }
    __syncthreads();
    for (int i = tid; i < cnt; i += 512) {
        unsigned int v = stage[i];
        unsigned int p = atomicAdd(&lcur[v >> 18], 1);
        csr_l[p] = v & 0x3ffffu;
    }
    __syncthreads();
    for (int i = tid; i < cnt; i += 512)
        csr_src[base + i] = (int)csr_l[i];
}

// ---------------- fused conv: static-first chunks + pipelined pool, 4-deep gather ----------------
// Grid = exactly 1024 blocks x 512 thr (4 blocks/CU, 32 waves/CU full residency).
// Wave gwid statically owns chunk gwid; 1024 remainder chunks in 8 per-wave-slot
// pools, with the grab for the NEXT chunk issued before processing the current
// one (latency + vmcnt drain hidden under gather work).
// Gather is the PROVEN 4-deep unroll (VGPR ~32, no spill — round 8's 8-deep
// unroll spilled: WRITE_SIZE 18->157 MB).
__global__ __launch_bounds__(512, 8) void conv_kernel(const int* __restrict__ off,
                                                      const int* __restrict__ ends,
                                                      const int* __restrict__ csr,
                                                      const unsigned int* __restrict__ xb,
                                                      const unsigned short* __restrict__ wbuf,
                                                      const float* __restrict__ brel,
                                                      unsigned int* __restrict__ xob,
                                                      int* __restrict__ pools) {
    __shared__ unsigned int wlds[4096];            // 16 KB: rel frags [0,2048), root [2048,4096)
    __shared__ unsigned short agg_s[128 * 72];     // 18 KB; wave w owns rows [16w,16w+16)
    const int tid = threadIdx.x;
    const int w = tid >> 6, l = tid & 63;
    const unsigned int* wsrc = (const unsigned int*)wbuf;
    #pragma unroll
    for (int i = 0; i < 8; i++) wlds[i * 512 + tid] = wsrc[i * 512 + tid];

    const int s = l >> 3, q = l & 7;
    const int lrow = l & 15, g16 = l >> 4, g4 = 4 * (l >> 4);

    // first pool grab issued immediately (overlaps wlds load + barrier + first gather)
    int nxt_i = 0;
    if (l == 0) nxt_i = atomicAdd(&pools[w * 64], 1);
    nxt_i = __builtin_amdgcn_readfirstlane(nxt_i);
    int nxt = (nxt_i < POOLPER) ? (NSTATIC + w * POOLPER + nxt_i) : NCHUNK;

    __syncthreads();   // wlds ready

    float bv[4];
    #pragma unroll
    for (int ct = 0; ct < 4; ct++) bv[ct] = brel[ct * 16 + lrow];

    int chunk = blockIdx.x * 8 + w;   // static chunk, 0..8191

    for (;;) {
        const int node0w = chunk * 16;
        int bvv = (l < 16) ? off[node0w + l] : 0;
        int evv = (l < 16) ? ends[node0w + l] : 0;

        #pragma unroll
        for (int g = 0; g < 2; g++) {
            int beg = __shfl(bvv, g * 8 + s);
            int end = __shfl(evv, g * 8 + s);
            int deg = end - beg;
            float a0 = 0.f, a1 = 0.f, a2 = 0.f, a3 = 0.f;
            float a4 = 0.f, a5 = 0.f, a6 = 0.f, a7 = 0.f;
            for (int j = 0; j < deg; j += 4) {
                int n0 = csr[beg + j];
                int n1 = (j + 1 < deg) ? csr[beg + j + 1] : -1;
                int n2 = (j + 2 < deg) ? csr[beg + j + 2] : -1;
                int n3 = (j + 3 < deg) ? csr[beg + j + 3] : -1;
                {
                    uint4 u = *(const uint4*)&xb[n0 * 32 + q * 4];
                    a0 += bflo(u.x); a1 += bfhi(u.x);
                    a2 += bflo(u.y); a3 += bfhi(u.y);
                    a4 += bflo(u.z); a5 += bfhi(u.z);
                    a6 += bflo(u.w); a7 += bfhi(u.w);
                }
                if (n1 >= 0) {
                    uint4 u = *(const uint4*)&xb[n1 * 32 + q * 4];
                    a0 += bflo(u.x); a1 += bfhi(u.x);
                    a2 += bflo(u.y); a3 += bfhi(u.y);
                    a4 += bflo(u.z); a5 += bfhi(u.z);
                    a6 += bflo(u.w); a7 += bfhi(u.w);
                }
                if (n2 >= 0) {
                    uint4 u = *(const uint4*)&xb[n2 * 32 + q * 4];
                    a0 += bflo(u.x); a1 += bfhi(u.x);
                    a2 += bflo(u.y); a3 += bfhi(u.y);
                    a4 += bflo(u.z); a5 += bfhi(u.z);
                    a6 += bflo(u.w); a7 += bfhi(u.w);
                }
                if (n3 >= 0) {
                    uint4 u = *(const uint4*)&xb[n3 * 32 + q * 4];
                    a0 += bflo(u.x); a1 += bfhi(u.x);
                    a2 += bflo(u.y); a3 += bfhi(u.y);
                    a4 += bflo(u.z); a5 += bfhi(u.z);
                    a6 += bflo(u.w); a7 += bfhi(u.w);
                }
            }
            unsigned int p0 = (unsigned int)f2bf(a0) | ((unsigned int)f2bf(a1) << 16);
            unsigned int p1 = (unsigned int)f2bf(a2) | ((unsigned int)f2bf(a3) << 16);
            unsigned int p2 = (unsigned int)f2bf(a4) | ((unsigned int)f2bf(a5) << 16);
            unsigned int p3 = (unsigned int)f2bf(a6) | ((unsigned int)f2bf(a7) << 16);
            *(uint4*)&agg_s[(w * 16 + g * 8 + s) * 72 + q * 8] = make_uint4(p0, p1, p2, p3);
        }
        __builtin_amdgcn_wave_barrier();

        // ---- MFMA phase ----
        v4s ax[4];
        #pragma unroll
        for (int kt = 0; kt < 4; kt++)
            ax[kt] = *(const v4s*)&xb[(node0w + lrow) * 32 + kt * 8 + g16 * 2];
        v4f acc[4];
        #pragma unroll
        for (int ct = 0; ct < 4; ct++) acc[ct] = (v4f){0.f, 0.f, 0.f, 0.f};
        #pragma unroll
        for (int kt = 0; kt < 4; kt++) {
            v4s a_agg = *(const v4s*)&agg_s[(w * 16 + lrow) * 72 + kt * 16 + g4];
            #pragma unroll
            for (int ct = 0; ct < 4; ct++) {
                int f = kt * 4 + ct;
                v4s wr = *(const v4s*)&wlds[f * 128 + l * 2];
                v4s wo = *(const v4s*)&wlds[2048 + f * 128 + l * 2];
                acc[ct] = __builtin_amdgcn_mfma_f32_16x16x16bf16_1k(a_agg, wr, acc[ct], 0, 0, 0);
                acc[ct] = __builtin_amdgcn_mfma_f32_16x16x16bf16_1k(ax[kt], wo, acc[ct], 0, 0, 0);
            }
        }
        __builtin_amdgcn_wave_barrier();

        // ---- epilogue into own agg rows ----
        #pragma unroll
        for (int ct = 0; ct < 4; ct++) {
            #pragma unroll
            for (int r = 0; r < 4; r++)
                agg_s[(w * 16 + g4 + r) * 72 + ct * 16 + lrow] = f2bf(acc[ct][r] + bv[ct]);
        }
        __builtin_amdgcn_wave_barrier();

        // ---- wave-local coalesced writeout: 16 rows x 128 B ----
        {
            int row = l >> 2, qq = l & 3;
            const unsigned int* srcp = (const unsigned int*)&agg_s[(w * 16 + row) * 72 + qq * 16];
            uint4 v0 = *(const uint4*)(srcp);
            uint4 v1 = *(const uint4*)(srcp + 4);
            *(uint4*)&xob[(node0w + row) * 32 + qq * 8] = v0;
            *(uint4*)&xob[(node0w + row) * 32 + qq * 8 + 4] = v1;
        }
        __builtin_amdgcn_wave_barrier();

        if (nxt >= NCHUNK) break;
        chunk = nxt;
        // pipelined grab for the chunk after this one
        int ni = 0;
        if (l == 0) ni = atomicAdd(&pools[w * 64], 1);
        ni = __builtin_amdgcn_readfirstlane(ni);
        nxt = (ni < POOLPER) ? (NSTATIC + w * POOLPER + ni) : NCHUNK;
    }
}

// ---------------- ligand pooling (bf16 x) ----------------
__global__ void pool_kernel(const unsigned int* __restrict__ xb,
                            const int* __restrict__ lig_batch,
                            float* __restrict__ pooled, float* __restrict__ cnt) {
    int node = blockIdx.x * 4 + (threadIdx.x >> 6);
    int h = threadIdx.x & 63;
    if (node >= NLIG) return;
    int b = lig_batch[node];
    unsigned int u = xb[node * 32 + (h >> 1)];
    float v = bf2f((unsigned short)((h & 1) ? (u >> 16) : (u & 0xffffu)));
    unsafeAtomicAdd(&pooled[b * H + h], v);
    if (h == 0) unsafeAtomicAdd(&cnt[b], 1.0f);
}

// ---------------- readout ----------------
__global__ void readout_kernel(const float* __restrict__ pooled, const float* __restrict__ cnt,
                               const float* __restrict__ Wro1, const float* __restrict__ bro1,
                               const float* __restrict__ Wro2, const float* __restrict__ bro2,
                               float* __restrict__ out) {
    __shared__ float pm[4][H];
    int w = threadIdx.x >> 6;
    int h = threadIdx.x & 63;
    int b = blockIdx.x * 4 + w;
    float c = fmaxf(cnt[b], 1.0f);
    pm[w][h] = pooled[b * H + h] / c;
    __syncthreads();
    float acc = bro1[h];
    #pragma unroll 8
    for (int k = 0; k < H; k++) acc += pm[w][k] * Wro1[k * H + h];
    float sig = 1.0f / (1.0f + expf(-acc));
    float s = acc * sig;
    float r = s * Wro2[h];
    #pragma unroll
    for (int off = 32; off; off >>= 1) r += __shfl_down(r, off);
    if (h == 0) out[b] = r + bro2[0];
}

extern "C" void kernel_launch(void* const* d_in, const int* in_sizes, int n_in,
                              void* d_out, int out_size, void* d_ws, size_t ws_size,
                              hipStream_t stream) {
    const float* lig_feat  = (const float*)d_in[1];
    const float* prot_feat = (const float*)d_in[3];
    const float* t         = (const float*)d_in[4];
    const int*   lig_batch = (const int*)d_in[5];
    const int*   edge_index= (const int*)d_in[7];
    const float* W_lig  = (const float*)d_in[8];
    const float* b_lig  = (const float*)d_in[9];
    const float* W_prot = (const float*)d_in[10];
    const float* b_prot = (const float*)d_in[11];
    const float* Wt1 = (const float*)d_in[12];
    const float* bt1 = (const float*)d_in[13];
    const float* Wt2 = (const float*)d_in[14];
    const float* bt2 = (const float*)d_in[15];
    const float* Wrel[3]  = {(const float*)d_in[16], (const float*)d_in[19], (const float*)d_in[22]};
    const float* brel[3]  = {(const float*)d_in[17], (const float*)d_in[20], (const float*)d_in[23]};
    const float* Wroot[3] = {(const float*)d_in[18], (const float*)d_in[21], (const float*)d_in[24]};
    const float* Wro1 = (const float*)d_in[25];
    const float* bro1 = (const float*)d_in[26];
    const float* Wro2 = (const float*)d_in[27];
    const float* bro2 = (const float*)d_in[28];
    float* out = (float*)d_out;

    char* ws = (char*)d_ws;
    int*            off_a   = (int*)(ws);                       // NTOT ints
    int*            ends_a  = (int*)(ws + 655360);              // NTOT ints
    unsigned int*   bcursor = (unsigned int*)(ws + 1310720);    // 2304 B
    int*            pools   = (int*)(ws + 1313024);             // 3 layers x 8 x 64 ints
    float*          t_emb   = (float*)(ws + 1376256);
    float*          pooled  = (float*)(ws + 1441792);
    float*          cnt     = (float*)(ws + 1507328);
    unsigned short* wbuf    = (unsigned short*)(ws + 1572864);  // 48 KB
    int*            csr_src = (int*)(ws + 2097152);             // 10.6 MB padded
    unsigned int*   bucketed= (unsigned int*)(ws + 14680064);   // 10.6 MB padded
    unsigned int*   xb0     = (unsigned int*)(ws + 27262976);   // 18 MB
    unsigned int*   xb1     = (unsigned int*)(ws + 46137344);   // 18 MB
    unsigned int*   xbs[2]  = {xb0, xb1};

    time_mlp_kernel<<<NB, H, 0, stream>>>(t, Wt1, bt1, Wt2, bt2, t_emb);
    wswz_kernel<<<dim3(16, 6), 256, 0, stream>>>(Wrel[0], Wroot[0], Wrel[1], Wroot[1],
                                                 Wrel[2], Wroot[2], wbuf);
    node_init_kernel<<<NTOT / 4, 256, 0, stream>>>(lig_feat, prot_feat, lig_batch, t_emb,
                                                   W_lig, b_lig, W_prot, b_prot, xb0);

    // ---- padded-bucket CSR build (zero bcursor + pools in one memset) ----
    hipMemsetAsync(bcursor, 0, 2304 + 6144, stream);
    bucket_fill_kernel<<<NEDGE / 8192, 1024, 0, stream>>>(edge_index, bcursor, bucketed);
    bucket_csr_kernel<<<NBUCK, 512, 0, stream>>>(bucketed, bcursor, off_a, ends_a, csr_src);

    // ---- 3 fused graph convs (static-first + pipelined pool) ----
    for (int lyr = 0; lyr < 3; lyr++) {
        unsigned int* cur = xbs[lyr & 1];
        unsigned int* nxt = xbs[(lyr + 1) & 1];
        conv_kernel<<<1024, 512, 0, stream>>>(off_a, ends_a, csr_src, cur,
                                              wbuf + lyr * 8192, brel[lyr], nxt,
                                              pools + lyr * 512);
    }
    unsigned int* xfin = xbs[1];

    hipMemsetAsync(pooled, 0, (size_t)(NB * H + NB) * sizeof(float), stream);
    pool_kernel<<<NLIG / 4, 256, 0, stream>>>(xfin, lig_batch, pooled, cnt);
    readout_kernel<<<NB / 4, 256, 0, stream>>>(pooled, cnt, Wro1, bro1, Wro2, bro2, out);
}

// Round 10
// 287.964 us; speedup vs baseline: 2.8019x; 1.1465x over previous
//
#include <hip/hip_runtime.h>
#include <math.h>

#define NLIG 16384
#define NPROT 131072
#define NTOT (NLIG + NPROT)
#define NEDGE 2097152
#define NB 256
#define H 64
#define NBUCK 576      // NTOT = 576 * 256
#define BSHIFT 8       // bucket = dst >> 8
#define BCAP 4608      // padded bucket capacity (avg 3641, sd ~60 -> 16 sigma)
#define NODESPW 18     // 8192 waves x 18 nodes = 147456 = NTOT exactly (no tail)

typedef short v4s __attribute__((ext_vector_type(4)));
typedef float v4f __attribute__((ext_vector_type(4)));

__device__ __forceinline__ unsigned short f2bf(float f) {
    unsigned int u = __float_as_uint(f);
    u += 0x7fff + ((u >> 16) & 1);   // RNE
    return (unsigned short)(u >> 16);
}
__device__ __forceinline__ float bf2f(unsigned short s) {
    return __uint_as_float(((unsigned int)s) << 16);
}
__device__ __forceinline__ float bflo(unsigned int u) {
    return __uint_as_float(u << 16);
}
__device__ __forceinline__ float bfhi(unsigned int u) {
    return __uint_as_float(u & 0xffff0000u);
}

// ---------------- time embedding MLP ----------------
__global__ void time_mlp_kernel(const float* __restrict__ t,
                                const float* __restrict__ Wt1, const float* __restrict__ bt1,
                                const float* __restrict__ Wt2, const float* __restrict__ bt2,
                                float* __restrict__ t_emb) {
    int b = blockIdx.x;
    int h = threadIdx.x;
    __shared__ float emb_s[H];
    __shared__ float h1_s[H];
    float tv = t[b];
    int i = h & 31;
    float freq = expf((float)i * (-9.2103403719761836f / 31.0f));
    float e = tv * freq;
    emb_s[h] = (h < 32) ? sinf(e) : cosf(e);
    __syncthreads();
    float acc = bt1[h];
    #pragma unroll 8
    for (int k = 0; k < H; k++) acc += emb_s[k] * Wt1[k * H + h];
    float sig = 1.0f / (1.0f + expf(-acc));
    h1_s[h] = acc * sig;
    __syncthreads();
    float acc2 = bt2[h];
    #pragma unroll 8
    for (int k = 0; k < H; k++) acc2 += h1_s[k] * Wt2[k * H + h];
    t_emb[b * H + h] = acc2;
}

// ---------------- weight pre-swizzle into MFMA B-fragment order (bf16) ----------------
__global__ void wswz_kernel(const float* __restrict__ W0, const float* __restrict__ W1,
                            const float* __restrict__ W2, const float* __restrict__ W3,
                            const float* __restrict__ W4, const float* __restrict__ W5,
                            unsigned short* __restrict__ wbuf) {
    const float* Ws[6] = {W0, W1, W2, W3, W4, W5};
    int m = blockIdx.y;
    int t = blockIdx.x * 256 + threadIdx.x;   // 0..4095
    int f = t >> 8, l = (t >> 2) & 63, i = t & 3;
    int kt = f >> 2, ct = f & 3;
    int row = 16 * kt + 4 * (l >> 4) + i;
    int col = 16 * ct + (l & 15);
    wbuf[m * 4096 + t] = f2bf(Ws[m][row * H + col]);
}

// ---------------- node feature init -> bf16-packed x ----------------
__global__ void node_init_kernel(const float* __restrict__ lig_feat,
                                 const float* __restrict__ prot_feat,
                                 const int* __restrict__ lig_batch,
                                 const float* __restrict__ t_emb,
                                 const float* __restrict__ W_lig, const float* __restrict__ b_lig,
                                 const float* __restrict__ W_prot, const float* __restrict__ b_prot,
                                 unsigned int* __restrict__ xb) {
    int node = blockIdx.x * 4 + (threadIdx.x >> 6);
    int h = threadIdx.x & 63;
    if (node >= NTOT) return;
    float acc;
    if (node < NLIG) {
        int b = lig_batch[node];
        acc = b_lig[h] + t_emb[b * H + h];
        #pragma unroll
        for (int k = 0; k < 15; k++)
            acc += lig_feat[node * 15 + k] * W_lig[k * H + h];
    } else {
        int p = node - NLIG;
        acc = b_prot[h];
        #pragma unroll
        for (int k = 0; k < 8; k++)
            acc += prot_feat[p * 8 + k] * W_prot[k * H + h];
    }
    float e0 = __shfl(acc, 2 * (h & 31));
    float e1 = __shfl(acc, 2 * (h & 31) + 1);
    if (h < 32)
        xb[node * 32 + h] = (unsigned int)f2bf(e0) | ((unsigned int)f2bf(e1) << 16);
}

// ---------------- bucketed CSR build (padded buckets: no hist/scan pass) ----------------
__global__ __launch_bounds__(1024) void bucket_fill_kernel(const int* __restrict__ edge_index,
                                                           unsigned int* __restrict__ bcursor,
                                                           unsigned int* __restrict__ bucketed) {
    __shared__ unsigned int lh[NBUCK];
    __shared__ unsigned int lcur[NBUCK];
    __shared__ unsigned int gb[NBUCK];
    int tid = threadIdx.x;
    for (int i = tid; i < NBUCK; i += 1024) lh[i] = 0;
    __syncthreads();
    int e0 = blockIdx.x * 8192;
    int src[8], dst[8];
    #pragma unroll
    for (int k = 0; k < 8; k++) {
        src[k] = edge_index[e0 + k * 1024 + tid];
        dst[k] = edge_index[NEDGE + e0 + k * 1024 + tid];
        atomicAdd(&lh[dst[k] >> BSHIFT], 1);
    }
    __syncthreads();
    if (tid < NBUCK) {
        gb[tid] = atomicAdd(&bcursor[tid], lh[tid]);
        lcur[tid] = 0;
    }
    __syncthreads();
    #pragma unroll
    for (int k = 0; k < 8; k++) {
        int b = dst[k] >> BSHIFT;
        unsigned int r = atomicAdd(&lcur[b], 1);
        unsigned int slot = gb[b] + r;
        if (slot < BCAP)
            bucketed[b * BCAP + slot] = (unsigned int)src[k] | ((unsigned int)(dst[k] & 255) << 18);
    }
}

// per-bucket counting sort in LDS -> csr_src + per-node [beg,end)
__global__ __launch_bounds__(512) void bucket_csr_kernel(const unsigned int* __restrict__ bucketed,
                                                         const unsigned int* __restrict__ bcursor,
                                                         int* __restrict__ off,
                                                         int* __restrict__ ends,
                                                         int* __restrict__ csr_src) {
    __shared__ unsigned int stage[BCAP];   // 18 KB packed
    __shared__ unsigned int csr_l[BCAP];   // 18 KB
    __shared__ unsigned int lh[256];
    __shared__ unsigned int lbeg[512];
    __shared__ unsigned int lcur[256];
    int b = blockIdx.x, tid = threadIdx.x;
    unsigned int base = (unsigned int)b * BCAP;
    int cnt = (int)bcursor[b];
    if (cnt > BCAP) cnt = BCAP;   // 16-sigma guard, never triggers
    for (int i = tid; i < 256; i += 512) lh[i] = 0;
    __syncthreads();
    for (int i = tid; i < cnt; i += 512) {
        unsigned int v = bucketed[base + i];
        stage[i] = v;
        atomicAdd(&lh[v >> 18], 1);
    }
    __syncthreads();
    unsigned int own = (tid < 256) ? lh[tid] : 0;
    lbeg[tid] = own;
    __syncthreads();
    for (int d = 1; d < 512; d <<= 1) {
        unsigned int v = (tid >= d) ? lbeg[tid - d] : 0;
        __syncthreads();
        lbeg[tid] += v;
        __syncthreads();
    }
    unsigned int excl = lbeg[tid] - own;
    __syncthreads();
    lbeg[tid] = excl;
    if (tid < 256) {
        lcur[tid] = excl;
        off[b * 256 + tid]  = (int)(base + excl);
        ends[b * 256 + tid] = (int)(base + excl + own);
    }
    __syncthreads();
    for (int i = tid; i < cnt; i += 512) {
        unsigned int v = stage[i];
        unsigned int p = atomicAdd(&lcur[v >> 18], 1);
        csr_l[p] = v & 0x3ffffu;
    }
    __syncthreads();
    for (int i = tid; i < cnt; i += 512)
        csr_src[base + i] = (int)csr_l[i];
}

// ---------------- fused conv: exact static split, 18 nodes/wave, no tail ----------------
// Grid = 1024 blocks x 512 thr = 8192 waves; wave gwid owns nodes
// [gwid*18, gwid*18+18). 8192*18 = NTOT exactly: zero atomics, no second round.
// Gather: 3 slot-groups (8+8+2 nodes); group 2 slots >=2 are masked off.
// MFMA: pass 1 = rows 0..15; pass 2 = rows 16..17 replicated into the A-frag
// (only output rows 0..1 kept — MFMA is ~2% utilized, the extra pass is free).
__global__ __launch_bounds__(512, 8) void conv_kernel(const int* __restrict__ off,
                                                      const int* __restrict__ ends,
                                                      const int* __restrict__ csr,
                                                      const unsigned int* __restrict__ xb,
                                                      const unsigned short* __restrict__ wbuf,
                                                      const float* __restrict__ brel,
                                                      unsigned int* __restrict__ xob) {
    __shared__ unsigned int wlds[4096];              // 16 KB: rel [0,2048), root [2048,4096)
    __shared__ unsigned short agg_s[8 * NODESPW * 72]; // 20.25 KB; wave w owns rows [18w,18w+18)
    const int tid = threadIdx.x;
    const int w = tid >> 6, l = tid & 63;
    const unsigned int* wsrc = (const unsigned int*)wbuf;
    #pragma unroll
    for (int i = 0; i < 8; i++) wlds[i * 512 + tid] = wsrc[i * 512 + tid];

    const int s = l >> 3, q = l & 7;
    const int lrow = l & 15, g16 = l >> 4, g4 = 4 * (l >> 4);
    const int gwid = blockIdx.x * 8 + w;
    const int node0w = gwid * NODESPW;

    int bvv = (l < NODESPW) ? off[node0w + l] : 0;
    int evv = (l < NODESPW) ? ends[node0w + l] : 0;

    __syncthreads();   // wlds ready

    float bv[4];
    #pragma unroll
    for (int ct = 0; ct < 4; ct++) bv[ct] = brel[ct * 16 + lrow];

    // ---- gather: 3 slot-groups ----
    for (int g = 0; g < 3; g++) {
        int nidx = g * 8 + s;                 // node index within the wave's 18
        int beg = __shfl(bvv, nidx);          // lanes >=18 hold 0 -> deg 0 for masked slots
        int end = __shfl(evv, nidx);
        int deg = end - beg;
        float a0 = 0.f, a1 = 0.f, a2 = 0.f, a3 = 0.f;
        float a4 = 0.f, a5 = 0.f, a6 = 0.f, a7 = 0.f;
        for (int j = 0; j < deg; j += 4) {
            int n0 = csr[beg + j];
            int n1 = (j + 1 < deg) ? csr[beg + j + 1] : -1;
            int n2 = (j + 2 < deg) ? csr[beg + j + 2] : -1;
            int n3 = (j + 3 < deg) ? csr[beg + j + 3] : -1;
            {
                uint4 u = *(const uint4*)&xb[n0 * 32 + q * 4];
                a0 += bflo(u.x); a1 += bfhi(u.x);
                a2 += bflo(u.y); a3 += bfhi(u.y);
                a4 += bflo(u.z); a5 += bfhi(u.z);
                a6 += bflo(u.w); a7 += bfhi(u.w);
            }
            if (n1 >= 0) {
                uint4 u = *(const uint4*)&xb[n1 * 32 + q * 4];
                a0 += bflo(u.x); a1 += bfhi(u.x);
                a2 += bflo(u.y); a3 += bfhi(u.y);
                a4 += bflo(u.z); a5 += bfhi(u.z);
                a6 += bflo(u.w); a7 += bfhi(u.w);
            }
            if (n2 >= 0) {
                uint4 u = *(const uint4*)&xb[n2 * 32 + q * 4];
                a0 += bflo(u.x); a1 += bfhi(u.x);
                a2 += bflo(u.y); a3 += bfhi(u.y);
                a4 += bflo(u.z); a5 += bfhi(u.z);
                a6 += bflo(u.w); a7 += bfhi(u.w);
            }
            if (n3 >= 0) {
                uint4 u = *(const uint4*)&xb[n3 * 32 + q * 4];
                a0 += bflo(u.x); a1 += bfhi(u.x);
                a2 += bflo(u.y); a3 += bfhi(u.y);
                a4 += bflo(u.z); a5 += bfhi(u.z);
                a6 += bflo(u.w); a7 += bfhi(u.w);
            }
        }
        if (nidx < NODESPW) {   // group 2, slots >=2 must not store (would alias wave w+1)
            unsigned int p0 = (unsigned int)f2bf(a0) | ((unsigned int)f2bf(a1) << 16);
            unsigned int p1 = (unsigned int)f2bf(a2) | ((unsigned int)f2bf(a3) << 16);
            unsigned int p2 = (unsigned int)f2bf(a4) | ((unsigned int)f2bf(a5) << 16);
            unsigned int p3 = (unsigned int)f2bf(a6) | ((unsigned int)f2bf(a7) << 16);
            *(uint4*)&agg_s[(w * NODESPW + nidx) * 72 + q * 8] = make_uint4(p0, p1, p2, p3);
        }
    }
    __builtin_amdgcn_wave_barrier();

    // ---- MFMA pass 1: rows 0..15 ----
    v4s ax[4];
    #pragma unroll
    for (int kt = 0; kt < 4; kt++)
        ax[kt] = *(const v4s*)&xb[(node0w + lrow) * 32 + kt * 8 + g16 * 2];
    v4f acc[4];
    #pragma unroll
    for (int ct = 0; ct < 4; ct++) acc[ct] = (v4f){0.f, 0.f, 0.f, 0.f};
    #pragma unroll
    for (int kt = 0; kt < 4; kt++) {
        v4s a_agg = *(const v4s*)&agg_s[(w * NODESPW + lrow) * 72 + kt * 16 + g4];
        #pragma unroll
        for (int ct = 0; ct < 4; ct++) {
            int f = kt * 4 + ct;
            v4s wr = *(const v4s*)&wlds[f * 128 + l * 2];
            v4s wo = *(const v4s*)&wlds[2048 + f * 128 + l * 2];
            acc[ct] = __builtin_amdgcn_mfma_f32_16x16x16bf16_1k(a_agg, wr, acc[ct], 0, 0, 0);
            acc[ct] = __builtin_amdgcn_mfma_f32_16x16x16bf16_1k(ax[kt], wo, acc[ct], 0, 0, 0);
        }
    }
    // ---- MFMA pass 2: rows 16..17 (A rows replicated; keep output rows 0..1) ----
    const int r2row = 16 + (lrow & 1);
    v4s ax2[4];
    #pragma unroll
    for (int kt = 0; kt < 4; kt++)
        ax2[kt] = *(const v4s*)&xb[(node0w + r2row) * 32 + kt * 8 + g16 * 2];
    v4f acc2[4];
    #pragma unroll
    for (int ct = 0; ct < 4; ct++) acc2[ct] = (v4f){0.f, 0.f, 0.f, 0.f};
    #pragma unroll
    for (int kt = 0; kt < 4; kt++) {
        v4s a_agg2 = *(const v4s*)&agg_s[(w * NODESPW + r2row) * 72 + kt * 16 + g4];
        #pragma unroll
        for (int ct = 0; ct < 4; ct++) {
            int f = kt * 4 + ct;
            v4s wr = *(const v4s*)&wlds[f * 128 + l * 2];
            v4s wo = *(const v4s*)&wlds[2048 + f * 128 + l * 2];
            acc2[ct] = __builtin_amdgcn_mfma_f32_16x16x16bf16_1k(a_agg2, wr, acc2[ct], 0, 0, 0);
            acc2[ct] = __builtin_amdgcn_mfma_f32_16x16x16bf16_1k(ax2[kt], wo, acc2[ct], 0, 0, 0);
        }
    }
    __builtin_amdgcn_wave_barrier();

    // ---- epilogue into own agg rows ----
    #pragma unroll
    for (int ct = 0; ct < 4; ct++) {
        #pragma unroll
        for (int r = 0; r < 4; r++)
            agg_s[(w * NODESPW + g4 + r) * 72 + ct * 16 + lrow] = f2bf(acc[ct][r] + bv[ct]);
    }
    if (g16 == 0) {   // pass-2 valid outputs: D rows 0,1 -> nodes 16,17
        #pragma unroll
        for (int ct = 0; ct < 4; ct++) {
            agg_s[(w * NODESPW + 16) * 72 + ct * 16 + lrow] = f2bf(acc2[ct][0] + bv[ct]);
            agg_s[(w * NODESPW + 17) * 72 + ct * 16 + lrow] = f2bf(acc2[ct][1] + bv[ct]);
        }
    }
    __builtin_amdgcn_wave_barrier();

    // ---- wave-local coalesced writeout: rows 0..15, then rows 16..17 ----
    {
        int row = l >> 2, qq = l & 3;
        const unsigned int* srcp = (const unsigned int*)&agg_s[(w * NODESPW + row) * 72 + qq * 16];
        uint4 v0 = *(const uint4*)(srcp);
        uint4 v1 = *(const uint4*)(srcp + 4);
        *(uint4*)&xob[(node0w + row) * 32 + qq * 8] = v0;
        *(uint4*)&xob[(node0w + row) * 32 + qq * 8 + 4] = v1;
    }
    {
        int row = 16 + (l >> 5), dw = l & 31;
        xob[(node0w + row) * 32 + dw] =
            *(const unsigned int*)&agg_s[(w * NODESPW + row) * 72 + dw * 2];
    }
}

// ---------------- ligand pooling (bf16 x) ----------------
__global__ void pool_kernel(const unsigned int* __restrict__ xb,
                            const int* __restrict__ lig_batch,
                            float* __restrict__ pooled, float* __restrict__ cnt) {
    int node = blockIdx.x * 4 + (threadIdx.x >> 6);
    int h = threadIdx.x & 63;
    if (node >= NLIG) return;
    int b = lig_batch[node];
    unsigned int u = xb[node * 32 + (h >> 1)];
    float v = bf2f((unsigned short)((h & 1) ? (u >> 16) : (u & 0xffffu)));
    unsafeAtomicAdd(&pooled[b * H + h], v);
    if (h == 0) unsafeAtomicAdd(&cnt[b], 1.0f);
}

// ---------------- readout ----------------
__global__ void readout_kernel(const float* __restrict__ pooled, const float* __restrict__ cnt,
                               const float* __restrict__ Wro1, const float* __restrict__ bro1,
                               const float* __restrict__ Wro2, const float* __restrict__ bro2,
                               float* __restrict__ out) {
    __shared__ float pm[4][H];
    int w = threadIdx.x >> 6;
    int h = threadIdx.x & 63;
    int b = blockIdx.x * 4 + w;
    float c = fmaxf(cnt[b], 1.0f);
    pm[w][h] = pooled[b * H + h] / c;
    __syncthreads();
    float acc = bro1[h];
    #pragma unroll 8
    for (int k = 0; k < H; k++) acc += pm[w][k] * Wro1[k * H + h];
    float sig = 1.0f / (1.0f + expf(-acc));
    float s = acc * sig;
    float r = s * Wro2[h];
    #pragma unroll
    for (int off = 32; off; off >>= 1) r += __shfl_down(r, off);
    if (h == 0) out[b] = r + bro2[0];
}

extern "C" void kernel_launch(void* const* d_in, const int* in_sizes, int n_in,
                              void* d_out, int out_size, void* d_ws, size_t ws_size,
                              hipStream_t stream) {
    const float* lig_feat  = (const float*)d_in[1];
    const float* prot_feat = (const float*)d_in[3];
    const float* t         = (const float*)d_in[4];
    const int*   lig_batch = (const int*)d_in[5];
    const int*   edge_index= (const int*)d_in[7];
    const float* W_lig  = (const float*)d_in[8];
    const float* b_lig  = (const float*)d_in[9];
    const float* W_prot = (const float*)d_in[10];
    const float* b_prot = (const float*)d_in[11];
    const float* Wt1 = (const float*)d_in[12];
    const float* bt1 = (const float*)d_in[13];
    const float* Wt2 = (const float*)d_in[14];
    const float* bt2 = (const float*)d_in[15];
    const float* Wrel[3]  = {(const float*)d_in[16], (const float*)d_in[19], (const float*)d_in[22]};
    const float* brel[3]  = {(const float*)d_in[17], (const float*)d_in[20], (const float*)d_in[23]};
    const float* Wroot[3] = {(const float*)d_in[18], (const float*)d_in[21], (const float*)d_in[24]};
    const float* Wro1 = (const float*)d_in[25];
    const float* bro1 = (const float*)d_in[26];
    const float* Wro2 = (const float*)d_in[27];
    const float* bro2 = (const float*)d_in[28];
    float* out = (float*)d_out;

    char* ws = (char*)d_ws;
    int*            off_a   = (int*)(ws);                       // NTOT ints
    int*            ends_a  = (int*)(ws + 655360);              // NTOT ints
    unsigned int*   bcursor = (unsigned int*)(ws + 1310720);    // 2304 B
    float*          t_emb   = (float*)(ws + 1376256);
    float*          pooled  = (float*)(ws + 1441792);
    float*          cnt     = (float*)(ws + 1507328);
    unsigned short* wbuf    = (unsigned short*)(ws + 1572864);  // 48 KB
    int*            csr_src = (int*)(ws + 2097152);             // 10.6 MB padded
    unsigned int*   bucketed= (unsigned int*)(ws + 14680064);   // 10.6 MB padded
    unsigned int*   xb0     = (unsigned int*)(ws + 27262976);   // 18 MB
    unsigned int*   xb1     = (unsigned int*)(ws + 46137344);   // 18 MB
    unsigned int*   xbs[2]  = {xb0, xb1};

    time_mlp_kernel<<<NB, H, 0, stream>>>(t, Wt1, bt1, Wt2, bt2, t_emb);
    wswz_kernel<<<dim3(16, 6), 256, 0, stream>>>(Wrel[0], Wroot[0], Wrel[1], Wroot[1],
                                                 Wrel[2], Wroot[2], wbuf);
    node_init_kernel<<<NTOT / 4, 256, 0, stream>>>(lig_feat, prot_feat, lig_batch, t_emb,
                                                   W_lig, b_lig, W_prot, b_prot, xb0);

    // ---- padded-bucket CSR build ----
    hipMemsetAsync(bcursor, 0, 2304, stream);
    bucket_fill_kernel<<<NEDGE / 8192, 1024, 0, stream>>>(edge_index, bcursor, bucketed);
    bucket_csr_kernel<<<NBUCK, 512, 0, stream>>>(bucketed, bcursor, off_a, ends_a, csr_src);

    // ---- 3 fused graph convs (exact static split, no tail) ----
    for (int lyr = 0; lyr < 3; lyr++) {
        unsigned int* cur = xbs[lyr & 1];
        unsigned int* nxt = xbs[(lyr + 1) & 1];
        conv_kernel<<<1024, 512, 0, stream>>>(off_a, ends_a, csr_src, cur,
                                              wbuf + lyr * 8192, brel[lyr], nxt);
    }
    unsigned int* xfin = xbs[1];

    hipMemsetAsync(pooled, 0, (size_t)(NB * H + NB) * sizeof(float), stream);
    pool_kernel<<<NLIG / 4, 256, 0, stream>>>(xfin, lig_batch, pooled, cnt);
    readout_kernel<<<NB / 4, 256, 0, stream>>>(pooled, cnt, Wro1, bro1, Wro2, bro2, out);
}

// Round 11
// 276.412 us; speedup vs baseline: 2.9190x; 1.0418x over previous
//
#include <hip/hip_runtime.h>
#include <math.h>

#define NLIG 16384
#define NPROT 131072
#define NTOT (NLIG + NPROT)
#define NEDGE 2097152
#define NB 256
#define H 64
#define NBUCK 576      // NTOT = 576 * 256
#define BSHIFT 8       // bucket = dst >> 8
#define BCAP 4608      // padded bucket capacity (avg 3641, sd ~60 -> 16 sigma)
#define NODESPW 18     // 8192 waves x 18 nodes = 147456 = NTOT exactly (no tail)

typedef short v4s __attribute__((ext_vector_type(4)));
typedef float v4f __attribute__((ext_vector_type(4)));

__device__ __forceinline__ unsigned short f2bf(float f) {
    unsigned int u = __float_as_uint(f);
    u += 0x7fff + ((u >> 16) & 1);   // RNE
    return (unsigned short)(u >> 16);
}
__device__ __forceinline__ float bf2f(unsigned short s) {
    return __uint_as_float(((unsigned int)s) << 16);
}
__device__ __forceinline__ float bflo(unsigned int u) {
    return __uint_as_float(u << 16);
}
__device__ __forceinline__ float bfhi(unsigned int u) {
    return __uint_as_float(u & 0xffff0000u);
}

// ---------------- time embedding MLP ----------------
__global__ void time_mlp_kernel(const float* __restrict__ t,
                                const float* __restrict__ Wt1, const float* __restrict__ bt1,
                                const float* __restrict__ Wt2, const float* __restrict__ bt2,
                                float* __restrict__ t_emb) {
    int b = blockIdx.x;
    int h = threadIdx.x;
    __shared__ float emb_s[H];
    __shared__ float h1_s[H];
    float tv = t[b];
    int i = h & 31;
    float freq = expf((float)i * (-9.2103403719761836f / 31.0f));
    float e = tv * freq;
    emb_s[h] = (h < 32) ? sinf(e) : cosf(e);
    __syncthreads();
    float acc = bt1[h];
    #pragma unroll 8
    for (int k = 0; k < H; k++) acc += emb_s[k] * Wt1[k * H + h];
    float sig = 1.0f / (1.0f + expf(-acc));
    h1_s[h] = acc * sig;
    __syncthreads();
    float acc2 = bt2[h];
    #pragma unroll 8
    for (int k = 0; k < H; k++) acc2 += h1_s[k] * Wt2[k * H + h];
    t_emb[b * H + h] = acc2;
}

// ---------------- weight pre-swizzle into MFMA B-fragment order (bf16) ----------------
__global__ void wswz_kernel(const float* __restrict__ W0, const float* __restrict__ W1,
                            const float* __restrict__ W2, const float* __restrict__ W3,
                            const float* __restrict__ W4, const float* __restrict__ W5,
                            unsigned short* __restrict__ wbuf) {
    const float* Ws[6] = {W0, W1, W2, W3, W4, W5};
    int m = blockIdx.y;
    int t = blockIdx.x * 256 + threadIdx.x;   // 0..4095
    int f = t >> 8, l = (t >> 2) & 63, i = t & 3;
    int kt = f >> 2, ct = f & 3;
    int row = 16 * kt + 4 * (l >> 4) + i;
    int col = 16 * ct + (l & 15);
    wbuf[m * 4096 + t] = f2bf(Ws[m][row * H + col]);
}

// ---------------- node feature init -> bf16-packed x ----------------
__global__ void node_init_kernel(const float* __restrict__ lig_feat,
                                 const float* __restrict__ prot_feat,
                                 const int* __restrict__ lig_batch,
                                 const float* __restrict__ t_emb,
                                 const float* __restrict__ W_lig, const float* __restrict__ b_lig,
                                 const float* __restrict__ W_prot, const float* __restrict__ b_prot,
                                 unsigned int* __restrict__ xb) {
    int node = blockIdx.x * 4 + (threadIdx.x >> 6);
    int h = threadIdx.x & 63;
    if (node >= NTOT) return;
    float acc;
    if (node < NLIG) {
        int b = lig_batch[node];
        acc = b_lig[h] + t_emb[b * H + h];
        #pragma unroll
        for (int k = 0; k < 15; k++)
            acc += lig_feat[node * 15 + k] * W_lig[k * H + h];
    } else {
        int p = node - NLIG;
        acc = b_prot[h];
        #pragma unroll
        for (int k = 0; k < 8; k++)
            acc += prot_feat[p * 8 + k] * W_prot[k * H + h];
    }
    float e0 = __shfl(acc, 2 * (h & 31));
    float e1 = __shfl(acc, 2 * (h & 31) + 1);
    if (h < 32)
        xb[node * 32 + h] = (unsigned int)f2bf(e0) | ((unsigned int)f2bf(e1) << 16);
}

// ---------------- bucketed CSR build (padded buckets: no hist/scan pass) ----------------
__global__ __launch_bounds__(1024) void bucket_fill_kernel(const int* __restrict__ edge_index,
                                                           unsigned int* __restrict__ bcursor,
                                                           unsigned int* __restrict__ bucketed) {
    __shared__ unsigned int lh[NBUCK];
    __shared__ unsigned int lcur[NBUCK];
    __shared__ unsigned int gb[NBUCK];
    int tid = threadIdx.x;
    for (int i = tid; i < NBUCK; i += 1024) lh[i] = 0;
    __syncthreads();
    int e0 = blockIdx.x * 8192;
    int src[8], dst[8];
    #pragma unroll
    for (int k = 0; k < 8; k++) {
        src[k] = edge_index[e0 + k * 1024 + tid];
        dst[k] = edge_index[NEDGE + e0 + k * 1024 + tid];
        atomicAdd(&lh[dst[k] >> BSHIFT], 1);
    }
    __syncthreads();
    if (tid < NBUCK) {
        gb[tid] = atomicAdd(&bcursor[tid], lh[tid]);
        lcur[tid] = 0;
    }
    __syncthreads();
    #pragma unroll
    for (int k = 0; k < 8; k++) {
        int b = dst[k] >> BSHIFT;
        unsigned int r = atomicAdd(&lcur[b], 1);
        unsigned int slot = gb[b] + r;
        if (slot < BCAP)
            bucketed[b * BCAP + slot] = (unsigned int)src[k] | ((unsigned int)(dst[k] & 255) << 18);
    }
}

// per-bucket counting sort in LDS -> csr_src + per-node [beg,end)
__global__ __launch_bounds__(512) void bucket_csr_kernel(const unsigned int* __restrict__ bucketed,
                                                         const unsigned int* __restrict__ bcursor,
                                                         int* __restrict__ off,
                                                         int* __restrict__ ends,
                                                         int* __restrict__ csr_src) {
    __shared__ unsigned int stage[BCAP];   // 18 KB packed
    __shared__ unsigned int csr_l[BCAP];   // 18 KB
    __shared__ unsigned int lh[256];
    __shared__ unsigned int lbeg[512];
    __shared__ unsigned int lcur[256];
    int b = blockIdx.x, tid = threadIdx.x;
    unsigned int base = (unsigned int)b * BCAP;
    int cnt = (int)bcursor[b];
    if (cnt > BCAP) cnt = BCAP;   // 16-sigma guard, never triggers
    for (int i = tid; i < 256; i += 512) lh[i] = 0;
    __syncthreads();
    for (int i = tid; i < cnt; i += 512) {
        unsigned int v = bucketed[base + i];
        stage[i] = v;
        atomicAdd(&lh[v >> 18], 1);
    }
    __syncthreads();
    unsigned int own = (tid < 256) ? lh[tid] : 0;
    lbeg[tid] = own;
    __syncthreads();
    for (int d = 1; d < 512; d <<= 1) {
        unsigned int v = (tid >= d) ? lbeg[tid - d] : 0;
        __syncthreads();
        lbeg[tid] += v;
        __syncthreads();
    }
    unsigned int excl = lbeg[tid] - own;
    __syncthreads();
    lbeg[tid] = excl;
    if (tid < 256) {
        lcur[tid] = excl;
        off[b * 256 + tid]  = (int)(base + excl);
        ends[b * 256 + tid] = (int)(base + excl + own);
    }
    __syncthreads();
    for (int i = tid; i < cnt; i += 512) {
        unsigned int v = stage[i];
        unsigned int p = atomicAdd(&lcur[v >> 18], 1);
        csr_l[p] = v & 0x3ffffu;
    }
    __syncthreads();
    for (int i = tid; i < cnt; i += 512)
        csr_src[base + i] = (int)csr_l[i];
}

// accumulate one 16B quad of a neighbor row
#define ACC8(u)                                   \
    do {                                          \
        a0 += bflo((u).x); a1 += bfhi((u).x);     \
        a2 += bflo((u).y); a3 += bfhi((u).y);     \
        a4 += bflo((u).z); a5 += bfhi((u).z);     \
        a6 += bflo((u).w); a7 += bfhi((u).w);     \
    } while (0)

// ---------------- fused conv: exact static split + pipelined index blocks ----------------
// Grid = 1024 blocks x 512 thr = 8192 waves; wave gwid owns nodes
// [gwid*18, gwid*18+18). Gather: slot s = node, q = feature quad. Slot's 8
// lanes load 8 csr indices in ONE coalesced 32B access; indices distributed
// in-register via shfl; the NEXT index block is issued before processing the
// current one, so gathers stream without a csr->gather serial gate.
__global__ __launch_bounds__(512, 8) void conv_kernel(const int* __restrict__ off,
                                                      const int* __restrict__ ends,
                                                      const int* __restrict__ csr,
                                                      const unsigned int* __restrict__ xb,
                                                      const unsigned short* __restrict__ wbuf,
                                                      const float* __restrict__ brel,
                                                      unsigned int* __restrict__ xob) {
    __shared__ unsigned int wlds[4096];                // 16 KB
    __shared__ unsigned short agg_s[8 * NODESPW * 72]; // 20.25 KB
    const int tid = threadIdx.x;
    const int w = tid >> 6, l = tid & 63;
    const unsigned int* wsrc = (const unsigned int*)wbuf;
    #pragma unroll
    for (int i = 0; i < 8; i++) wlds[i * 512 + tid] = wsrc[i * 512 + tid];

    const int s = l >> 3, q = l & 7;
    const int lrow = l & 15, g16 = l >> 4, g4 = 4 * (l >> 4);
    const int gwid = blockIdx.x * 8 + w;
    const int node0w = gwid * NODESPW;

    int bvv = (l < NODESPW) ? off[node0w + l] : 0;
    int evv = (l < NODESPW) ? ends[node0w + l] : 0;

    // per-slot (beg,deg) for the 3 groups + first index blocks issued up-front
    int b0 = __shfl(bvv, s),      d0 = __shfl(evv, s) - b0;
    int b1 = __shfl(bvv, 8 + s),  d1 = __shfl(evv, 8 + s) - b1;
    int b2 = __shfl(bvv, 16 + s), d2 = __shfl(evv, 16 + s) - b2;
    int id0 = (q < d0) ? csr[b0 + q] : -1;
    int id1 = (q < d1) ? csr[b1 + q] : -1;
    int id2 = (q < d2) ? csr[b2 + q] : -1;

    __syncthreads();   // wlds ready

    float bv[4];
    #pragma unroll
    for (int ct = 0; ct < 4; ct++) bv[ct] = brel[ct * 16 + lrow];

#define DO_GROUP(BEG, DEG, IDFIRST, NIDX)                                       \
    {                                                                           \
        int idcur = (IDFIRST);                                                  \
        float a0 = 0.f, a1 = 0.f, a2 = 0.f, a3 = 0.f;                           \
        float a4 = 0.f, a5 = 0.f, a6 = 0.f, a7 = 0.f;                           \
        for (int jb = 0; jb < (DEG); jb += 8) {                                 \
            int idnxt = (jb + 8 + q < (DEG)) ? csr[(BEG) + jb + 8 + q] : -1;    \
            int n0 = __shfl(idcur, s * 8 + 0);                                  \
            int n1 = __shfl(idcur, s * 8 + 1);                                  \
            int n2 = __shfl(idcur, s * 8 + 2);                                  \
            int n3 = __shfl(idcur, s * 8 + 3);                                  \
            { uint4 u = *(const uint4*)&xb[n0 * 32 + q * 4]; ACC8(u); }         \
            if (n1 >= 0) { uint4 u = *(const uint4*)&xb[n1 * 32 + q * 4]; ACC8(u); } \
            if (n2 >= 0) { uint4 u = *(const uint4*)&xb[n2 * 32 + q * 4]; ACC8(u); } \
            if (n3 >= 0) { uint4 u = *(const uint4*)&xb[n3 * 32 + q * 4]; ACC8(u); } \
            int n4 = __shfl(idcur, s * 8 + 4);                                  \
            int n5 = __shfl(idcur, s * 8 + 5);                                  \
            int n6 = __shfl(idcur, s * 8 + 6);                                  \
            int n7 = __shfl(idcur, s * 8 + 7);                                  \
            if (n4 >= 0) { uint4 u = *(const uint4*)&xb[n4 * 32 + q * 4]; ACC8(u); } \
            if (n5 >= 0) { uint4 u = *(const uint4*)&xb[n5 * 32 + q * 4]; ACC8(u); } \
            if (n6 >= 0) { uint4 u = *(const uint4*)&xb[n6 * 32 + q * 4]; ACC8(u); } \
            if (n7 >= 0) { uint4 u = *(const uint4*)&xb[n7 * 32 + q * 4]; ACC8(u); } \
            idcur = idnxt;                                                      \
        }                                                                       \
        if ((NIDX) < NODESPW) {                                                 \
            unsigned int p0 = (unsigned int)f2bf(a0) | ((unsigned int)f2bf(a1) << 16); \
            unsigned int p1 = (unsigned int)f2bf(a2) | ((unsigned int)f2bf(a3) << 16); \
            unsigned int p2 = (unsigned int)f2bf(a4) | ((unsigned int)f2bf(a5) << 16); \
            unsigned int p3 = (unsigned int)f2bf(a6) | ((unsigned int)f2bf(a7) << 16); \
            *(uint4*)&agg_s[(w * NODESPW + (NIDX)) * 72 + q * 8] =              \
                make_uint4(p0, p1, p2, p3);                                     \
        }                                                                       \
    }

    DO_GROUP(b0, d0, id0, s)
    DO_GROUP(b1, d1, id1, 8 + s)
    DO_GROUP(b2, d2, id2, 16 + s)
#undef DO_GROUP

    __builtin_amdgcn_wave_barrier();

    // ---- MFMA pass 1: rows 0..15 ----
    v4s ax[4];
    #pragma unroll
    for (int kt = 0; kt < 4; kt++)
        ax[kt] = *(const v4s*)&xb[(node0w + lrow) * 32 + kt * 8 + g16 * 2];
    v4f acc[4];
    #pragma unroll
    for (int ct = 0; ct < 4; ct++) acc[ct] = (v4f){0.f, 0.f, 0.f, 0.f};
    #pragma unroll
    for (int kt = 0; kt < 4; kt++) {
        v4s a_agg = *(const v4s*)&agg_s[(w * NODESPW + lrow) * 72 + kt * 16 + g4];
        #pragma unroll
        for (int ct = 0; ct < 4; ct++) {
            int f = kt * 4 + ct;
            v4s wr = *(const v4s*)&wlds[f * 128 + l * 2];
            v4s wo = *(const v4s*)&wlds[2048 + f * 128 + l * 2];
            acc[ct] = __builtin_amdgcn_mfma_f32_16x16x16bf16_1k(a_agg, wr, acc[ct], 0, 0, 0);
            acc[ct] = __builtin_amdgcn_mfma_f32_16x16x16bf16_1k(ax[kt], wo, acc[ct], 0, 0, 0);
        }
    }
    // ---- MFMA pass 2: rows 16..17 (A rows replicated; keep output rows 0..1) ----
    const int r2row = 16 + (lrow & 1);
    v4s ax2[4];
    #pragma unroll
    for (int kt = 0; kt < 4; kt++)
        ax2[kt] = *(const v4s*)&xb[(node0w + r2row) * 32 + kt * 8 + g16 * 2];
    v4f acc2[4];
    #pragma unroll
    for (int ct = 0; ct < 4; ct++) acc2[ct] = (v4f){0.f, 0.f, 0.f, 0.f};
    #pragma unroll
    for (int kt = 0; kt < 4; kt++) {
        v4s a_agg2 = *(const v4s*)&agg_s[(w * NODESPW + r2row) * 72 + kt * 16 + g4];
        #pragma unroll
        for (int ct = 0; ct < 4; ct++) {
            int f = kt * 4 + ct;
            v4s wr = *(const v4s*)&wlds[f * 128 + l * 2];
            v4s wo = *(const v4s*)&wlds[2048 + f * 128 + l * 2];
            acc2[ct] = __builtin_amdgcn_mfma_f32_16x16x16bf16_1k(a_agg2, wr, acc2[ct], 0, 0, 0);
            acc2[ct] = __builtin_amdgcn_mfma_f32_16x16x16bf16_1k(ax2[kt], wo, acc2[ct], 0, 0, 0);
        }
    }
    __builtin_amdgcn_wave_barrier();

    // ---- epilogue into own agg rows ----
    #pragma unroll
    for (int ct = 0; ct < 4; ct++) {
        #pragma unroll
        for (int r = 0; r < 4; r++)
            agg_s[(w * NODESPW + g4 + r) * 72 + ct * 16 + lrow] = f2bf(acc[ct][r] + bv[ct]);
    }
    if (g16 == 0) {   // pass-2 valid outputs: D rows 0,1 -> nodes 16,17
        #pragma unroll
        for (int ct = 0; ct < 4; ct++) {
            agg_s[(w * NODESPW + 16) * 72 + ct * 16 + lrow] = f2bf(acc2[ct][0] + bv[ct]);
            agg_s[(w * NODESPW + 17) * 72 + ct * 16 + lrow] = f2bf(acc2[ct][1] + bv[ct]);
        }
    }
    __builtin_amdgcn_wave_barrier();

    // ---- wave-local coalesced writeout: rows 0..15, then rows 16..17 ----
    {
        int row = l >> 2, qq = l & 3;
        const unsigned int* srcp = (const unsigned int*)&agg_s[(w * NODESPW + row) * 72 + qq * 16];
        uint4 v0 = *(const uint4*)(srcp);
        uint4 v1 = *(const uint4*)(srcp + 4);
        *(uint4*)&xob[(node0w + row) * 32 + qq * 8] = v0;
        *(uint4*)&xob[(node0w + row) * 32 + qq * 8 + 4] = v1;
    }
    {
        int row = 16 + (l >> 5), dw = l & 31;
        xob[(node0w + row) * 32 + dw] =
            *(const unsigned int*)&agg_s[(w * NODESPW + row) * 72 + dw * 2];
    }
}

// ---------------- ligand pooling (bf16 x) ----------------
__global__ void pool_kernel(const unsigned int* __restrict__ xb,
                            const int* __restrict__ lig_batch,
                            float* __restrict__ pooled, float* __restrict__ cnt) {
    int node = blockIdx.x * 4 + (threadIdx.x >> 6);
    int h = threadIdx.x & 63;
    if (node >= NLIG) return;
    int b = lig_batch[node];
    unsigned int u = xb[node * 32 + (h >> 1)];
    float v = bf2f((unsigned short)((h & 1) ? (u >> 16) : (u & 0xffffu)));
    unsafeAtomicAdd(&pooled[b * H + h], v);
    if (h == 0) unsafeAtomicAdd(&cnt[b], 1.0f);
}

// ---------------- readout ----------------
__global__ void readout_kernel(const float* __restrict__ pooled, const float* __restrict__ cnt,
                               const float* __restrict__ Wro1, const float* __restrict__ bro1,
                               const float* __restrict__ Wro2, const float* __restrict__ bro2,
                               float* __restrict__ out) {
    __shared__ float pm[4][H];
    int w = threadIdx.x >> 6;
    int h = threadIdx.x & 63;
    int b = blockIdx.x * 4 + w;
    float c = fmaxf(cnt[b], 1.0f);
    pm[w][h] = pooled[b * H + h] / c;
    __syncthreads();
    float acc = bro1[h];
    #pragma unroll 8
    for (int k = 0; k < H; k++) acc += pm[w][k] * Wro1[k * H + h];
    float sig = 1.0f / (1.0f + expf(-acc));
    float s = acc * sig;
    float r = s * Wro2[h];
    #pragma unroll
    for (int off = 32; off; off >>= 1) r += __shfl_down(r, off);
    if (h == 0) out[b] = r + bro2[0];
}

extern "C" void kernel_launch(void* const* d_in, const int* in_sizes, int n_in,
                              void* d_out, int out_size, void* d_ws, size_t ws_size,
                              hipStream_t stream) {
    const float* lig_feat  = (const float*)d_in[1];
    const float* prot_feat = (const float*)d_in[3];
    const float* t         = (const float*)d_in[4];
    const int*   lig_batch = (const int*)d_in[5];
    const int*   edge_index= (const int*)d_in[7];
    const float* W_lig  = (const float*)d_in[8];
    const float* b_lig  = (const float*)d_in[9];
    const float* W_prot = (const float*)d_in[10];
    const float* b_prot = (const float*)d_in[11];
    const float* Wt1 = (const float*)d_in[12];
    const float* bt1 = (const float*)d_in[13];
    const float* Wt2 = (const float*)d_in[14];
    const float* bt2 = (const float*)d_in[15];
    const float* Wrel[3]  = {(const float*)d_in[16], (const float*)d_in[19], (const float*)d_in[22]};
    const float* brel[3]  = {(const float*)d_in[17], (const float*)d_in[20], (const float*)d_in[23]};
    const float* Wroot[3] = {(const float*)d_in[18], (const float*)d_in[21], (const float*)d_in[24]};
    const float* Wro1 = (const float*)d_in[25];
    const float* bro1 = (const float*)d_in[26];
    const float* Wro2 = (const float*)d_in[27];
    const float* bro2 = (const float*)d_in[28];
    float* out = (float*)d_out;

    char* ws = (char*)d_ws;
    int*            off_a   = (int*)(ws);                       // NTOT ints
    int*            ends_a  = (int*)(ws + 655360);              // NTOT ints
    unsigned int*   bcursor = (unsigned int*)(ws + 1310720);    // 2304 B
    float*          t_emb   = (float*)(ws + 1376256);
    float*          pooled  = (float*)(ws + 1441792);
    float*          cnt     = (float*)(ws + 1507328);
    unsigned short* wbuf    = (unsigned short*)(ws + 1572864);  // 48 KB
    int*            csr_src = (int*)(ws + 2097152);             // 10.6 MB padded
    unsigned int*   bucketed= (unsigned int*)(ws + 14680064);   // 10.6 MB padded
    unsigned int*   xb0     = (unsigned int*)(ws + 27262976);   // 18 MB
    unsigned int*   xb1     = (unsigned int*)(ws + 46137344);   // 18 MB
    unsigned int*   xbs[2]  = {xb0, xb1};

    time_mlp_kernel<<<NB, H, 0, stream>>>(t, Wt1, bt1, Wt2, bt2, t_emb);
    wswz_kernel<<<dim3(16, 6), 256, 0, stream>>>(Wrel[0], Wroot[0], Wrel[1], Wroot[1],
                                                 Wrel[2], Wroot[2], wbuf);
    node_init_kernel<<<NTOT / 4, 256, 0, stream>>>(lig_feat, prot_feat, lig_batch, t_emb,
                                                   W_lig, b_lig, W_prot, b_prot, xb0);

    // ---- padded-bucket CSR build ----
    hipMemsetAsync(bcursor, 0, 2304, stream);
    bucket_fill_kernel<<<NEDGE / 8192, 1024, 0, stream>>>(edge_index, bcursor, bucketed);
    bucket_csr_kernel<<<NBUCK, 512, 0, stream>>>(bucketed, bcursor, off_a, ends_a, csr_src);

    // ---- 3 fused graph convs (exact static split, pipelined index blocks) ----
    for (int lyr = 0; lyr < 3; lyr++) {
        unsigned int* cur = xbs[lyr & 1];
        unsigned int* nxt = xbs[(lyr + 1) & 1];
        conv_kernel<<<1024, 512, 0, stream>>>(off_a, ends_a, csr_src, cur,
                                              wbuf + lyr * 8192, brel[lyr], nxt);
    }
    unsigned int* xfin = xbs[1];

    hipMemsetAsync(pooled, 0, (size_t)(NB * H + NB) * sizeof(float), stream);
    pool_kernel<<<NLIG / 4, 256, 0, stream>>>(xfin, lig_batch, pooled, cnt);
    readout_kernel<<<NB / 4, 256, 0, stream>>>(pooled, cnt, Wro1, bro1, Wro2, bro2, out);
}

// Round 12
// 265.258 us; speedup vs baseline: 3.0417x; 1.0421x over previous
//
#include <hip/hip_runtime.h>
#include <math.h>

#define NLIG 16384
#define NPROT 131072
#define NTOT (NLIG + NPROT)
#define NEDGE 2097152
#define NB 256
#define H 64
#define NBUCK 576      // NTOT = 576 * 256
#define BSHIFT 8       // bucket = dst >> 8
#define BCAP 4608      // padded bucket capacity (avg 3641, sd ~60 -> 16 sigma)
#define NODESPW 24     // 768 blocks x 8 waves x 24 nodes = 147456 = NTOT exactly

typedef short v4s __attribute__((ext_vector_type(4)));
typedef float v4f __attribute__((ext_vector_type(4)));

__device__ __forceinline__ unsigned short f2bf(float f) {
    unsigned int u = __float_as_uint(f);
    u += 0x7fff + ((u >> 16) & 1);   // RNE
    return (unsigned short)(u >> 16);
}
__device__ __forceinline__ float bf2f(unsigned short s) {
    return __uint_as_float(((unsigned int)s) << 16);
}
__device__ __forceinline__ float bflo(unsigned int u) {
    return __uint_as_float(u << 16);
}
__device__ __forceinline__ float bfhi(unsigned int u) {
    return __uint_as_float(u & 0xffff0000u);
}

// ---------------- time embedding MLP ----------------
__global__ void time_mlp_kernel(const float* __restrict__ t,
                                const float* __restrict__ Wt1, const float* __restrict__ bt1,
                                const float* __restrict__ Wt2, const float* __restrict__ bt2,
                                float* __restrict__ t_emb) {
    int b = blockIdx.x;
    int h = threadIdx.x;
    __shared__ float emb_s[H];
    __shared__ float h1_s[H];
    float tv = t[b];
    int i = h & 31;
    float freq = expf((float)i * (-9.2103403719761836f / 31.0f));
    float e = tv * freq;
    emb_s[h] = (h < 32) ? sinf(e) : cosf(e);
    __syncthreads();
    float acc = bt1[h];
    #pragma unroll 8
    for (int k = 0; k < H; k++) acc += emb_s[k] * Wt1[k * H + h];
    float sig = 1.0f / (1.0f + expf(-acc));
    h1_s[h] = acc * sig;
    __syncthreads();
    float acc2 = bt2[h];
    #pragma unroll 8
    for (int k = 0; k < H; k++) acc2 += h1_s[k] * Wt2[k * H + h];
    t_emb[b * H + h] = acc2;
}

// ---------------- weight pre-swizzle into MFMA B-fragment order (bf16) ----------------
__global__ void wswz_kernel(const float* __restrict__ W0, const float* __restrict__ W1,
                            const float* __restrict__ W2, const float* __restrict__ W3,
                            const float* __restrict__ W4, const float* __restrict__ W5,
                            unsigned short* __restrict__ wbuf) {
    const float* Ws[6] = {W0, W1, W2, W3, W4, W5};
    int m = blockIdx.y;
    int t = blockIdx.x * 256 + threadIdx.x;   // 0..4095
    int f = t >> 8, l = (t >> 2) & 63, i = t & 3;
    int kt = f >> 2, ct = f & 3;
    int row = 16 * kt + 4 * (l >> 4) + i;
    int col = 16 * ct + (l & 15);
    wbuf[m * 4096 + t] = f2bf(Ws[m][row * H + col]);
}

// ---------------- node feature init -> bf16-packed x ----------------
__global__ void node_init_kernel(const float* __restrict__ lig_feat,
                                 const float* __restrict__ prot_feat,
                                 const int* __restrict__ lig_batch,
                                 const float* __restrict__ t_emb,
                                 const float* __restrict__ W_lig, const float* __restrict__ b_lig,
                                 const float* __restrict__ W_prot, const float* __restrict__ b_prot,
                                 unsigned int* __restrict__ xb) {
    int node = blockIdx.x * 4 + (threadIdx.x >> 6);
    int h = threadIdx.x & 63;
    if (node >= NTOT) return;
    float acc;
    if (node < NLIG) {
        int b = lig_batch[node];
        acc = b_lig[h] + t_emb[b * H + h];
        #pragma unroll
        for (int k = 0; k < 15; k++)
            acc += lig_feat[node * 15 + k] * W_lig[k * H + h];
    } else {
        int p = node - NLIG;
        acc = b_prot[h];
        #pragma unroll
        for (int k = 0; k < 8; k++)
            acc += prot_feat[p * 8 + k] * W_prot[k * H + h];
    }
    float e0 = __shfl(acc, 2 * (h & 31));
    float e1 = __shfl(acc, 2 * (h & 31) + 1);
    if (h < 32)
        xb[node * 32 + h] = (unsigned int)f2bf(e0) | ((unsigned int)f2bf(e1) << 16);
}

// ---------------- bucketed CSR build (padded buckets: no hist/scan pass) ----------------
__global__ __launch_bounds__(1024) void bucket_fill_kernel(const int* __restrict__ edge_index,
                                                           unsigned int* __restrict__ bcursor,
                                                           unsigned int* __restrict__ bucketed) {
    __shared__ unsigned int lh[NBUCK];
    __shared__ unsigned int lcur[NBUCK];
    __shared__ unsigned int gb[NBUCK];
    int tid = threadIdx.x;
    for (int i = tid; i < NBUCK; i += 1024) lh[i] = 0;
    __syncthreads();
    int e0 = blockIdx.x * 8192;
    int src[8], dst[8];
    #pragma unroll
    for (int k = 0; k < 8; k++) {
        src[k] = edge_index[e0 + k * 1024 + tid];
        dst[k] = edge_index[NEDGE + e0 + k * 1024 + tid];
        atomicAdd(&lh[dst[k] >> BSHIFT], 1);
    }
    __syncthreads();
    if (tid < NBUCK) {
        gb[tid] = atomicAdd(&bcursor[tid], lh[tid]);
        lcur[tid] = 0;
    }
    __syncthreads();
    #pragma unroll
    for (int k = 0; k < 8; k++) {
        int b = dst[k] >> BSHIFT;
        unsigned int r = atomicAdd(&lcur[b], 1);
        unsigned int slot = gb[b] + r;
        if (slot < BCAP)
            bucketed[b * BCAP + slot] = (unsigned int)src[k] | ((unsigned int)(dst[k] & 255) << 18);
    }
}

// per-bucket counting sort in LDS -> csr_src + per-node [beg,end)
__global__ __launch_bounds__(512) void bucket_csr_kernel(const unsigned int* __restrict__ bucketed,
                                                         const unsigned int* __restrict__ bcursor,
                                                         int* __restrict__ off,
                                                         int* __restrict__ ends,
                                                         int* __restrict__ csr_src) {
    __shared__ unsigned int stage[BCAP];   // 18 KB packed
    __shared__ unsigned int csr_l[BCAP];   // 18 KB
    __shared__ unsigned int lh[256];
    __shared__ unsigned int lbeg[512];
    __shared__ unsigned int lcur[256];
    int b = blockIdx.x, tid = threadIdx.x;
    unsigned int base = (unsigned int)b * BCAP;
    int cnt = (int)bcursor[b];
    if (cnt > BCAP) cnt = BCAP;   // 16-sigma guard, never triggers
    for (int i = tid; i < 256; i += 512) lh[i] = 0;
    __syncthreads();
    for (int i = tid; i < cnt; i += 512) {
        unsigned int v = bucketed[base + i];
        stage[i] = v;
        atomicAdd(&lh[v >> 18], 1);
    }
    __syncthreads();
    unsigned int own = (tid < 256) ? lh[tid] : 0;
    lbeg[tid] = own;
    __syncthreads();
    for (int d = 1; d < 512; d <<= 1) {
        unsigned int v = (tid >= d) ? lbeg[tid - d] : 0;
        __syncthreads();
        lbeg[tid] += v;
        __syncthreads();
    }
    unsigned int excl = lbeg[tid] - own;
    __syncthreads();
    lbeg[tid] = excl;
    if (tid < 256) {
        lcur[tid] = excl;
        off[b * 256 + tid]  = (int)(base + excl);
        ends[b * 256 + tid] = (int)(base + excl + own);
    }
    __syncthreads();
    for (int i = tid; i < cnt; i += 512) {
        unsigned int v = stage[i];
        unsigned int p = atomicAdd(&lcur[v >> 18], 1);
        csr_l[p] = v & 0x3ffffu;
    }
    __syncthreads();
    for (int i = tid; i < cnt; i += 512)
        csr_src[base + i] = (int)csr_l[i];
}

// accumulate one 16B quad of a neighbor row
#define ACC8(u)                                   \
    do {                                          \
        a0 += bflo((u).x); a1 += bfhi((u).x);     \
        a2 += bflo((u).y); a3 += bfhi((u).y);     \
        a4 += bflo((u).z); a5 += bfhi((u).z);     \
        a6 += bflo((u).w); a7 += bfhi((u).w);     \
    } while (0)

// ---------------- fused conv: 24 nodes/wave, 8-deep unconditional gather ----------------
// Grid = 768 blocks x 512 thr = 6144 waves; wave gwid owns nodes
// [gwid*24, gwid*24+24) — 6144*24 = NTOT exactly, and 768 = 256 CU x 3 blocks
// (LDS 44KB x 3 = 132KB, VGPR budget 85 at waves/EU=6) -> no dispatch tail.
// Gather: slot s = node (3 full groups of 8), q = feature quad. 8 csr indices
// per slot loaded in one coalesced 32B access + shfl; next block prefetched.
// All 8 row-gathers issued UNCONDITIONALLY (invalid slots clamped to n0,
// zero-masked after) -> 8 vmem ops in flight per lane, no branch-gated issue.
__global__ __launch_bounds__(512, 6) void conv_kernel(const int* __restrict__ off,
                                                      const int* __restrict__ ends,
                                                      const int* __restrict__ csr,
                                                      const unsigned int* __restrict__ xb,
                                                      const unsigned short* __restrict__ wbuf,
                                                      const float* __restrict__ brel,
                                                      unsigned int* __restrict__ xob) {
    __shared__ unsigned int wlds[4096];                // 16 KB
    __shared__ unsigned short agg_s[8 * NODESPW * 72]; // 27 KB
    const int tid = threadIdx.x;
    const int w = tid >> 6, l = tid & 63;
    const unsigned int* wsrc = (const unsigned int*)wbuf;
    #pragma unroll
    for (int i = 0; i < 8; i++) wlds[i * 512 + tid] = wsrc[i * 512 + tid];

    const int s = l >> 3, q = l & 7;
    const int lrow = l & 15, g16 = l >> 4, g4 = 4 * (l >> 4);
    const int gwid = blockIdx.x * 8 + w;
    const int node0w = gwid * NODESPW;

    int bvv = (l < NODESPW) ? off[node0w + l] : 0;
    int evv = (l < NODESPW) ? ends[node0w + l] : 0;

    // per-slot (beg,deg) for the 3 groups + first index blocks issued up-front
    int b0 = __shfl(bvv, s),      d0 = __shfl(evv, s) - b0;
    int b1 = __shfl(bvv, 8 + s),  d1 = __shfl(evv, 8 + s) - b1;
    int b2 = __shfl(bvv, 16 + s), d2 = __shfl(evv, 16 + s) - b2;
    int id0 = (q < d0) ? csr[b0 + q] : -1;
    int id1 = (q < d1) ? csr[b1 + q] : -1;
    int id2 = (q < d2) ? csr[b2 + q] : -1;

    __syncthreads();   // wlds ready

    float bv[4];
    #pragma unroll
    for (int ct = 0; ct < 4; ct++) bv[ct] = brel[ct * 16 + lrow];

#define DO_GROUP(BEG, DEG, IDFIRST, NIDX)                                       \
    {                                                                           \
        int idcur = (IDFIRST);                                                  \
        float a0 = 0.f, a1 = 0.f, a2 = 0.f, a3 = 0.f;                           \
        float a4 = 0.f, a5 = 0.f, a6 = 0.f, a7 = 0.f;                           \
        for (int jb = 0; jb < (DEG); jb += 8) {                                 \
            int idnxt = (jb + 8 + q < (DEG)) ? csr[(BEG) + jb + 8 + q] : -1;    \
            int n0 = __shfl(idcur, s * 8 + 0);                                  \
            int n1 = __shfl(idcur, s * 8 + 1);                                  \
            int n2 = __shfl(idcur, s * 8 + 2);                                  \
            int n3 = __shfl(idcur, s * 8 + 3);                                  \
            int n4 = __shfl(idcur, s * 8 + 4);                                  \
            int n5 = __shfl(idcur, s * 8 + 5);                                  \
            int n6 = __shfl(idcur, s * 8 + 6);                                  \
            int n7 = __shfl(idcur, s * 8 + 7);                                  \
            int c1 = (n1 >= 0) ? n1 : n0;                                       \
            int c2 = (n2 >= 0) ? n2 : n0;                                       \
            int c3 = (n3 >= 0) ? n3 : n0;                                       \
            int c4 = (n4 >= 0) ? n4 : n0;                                       \
            int c5 = (n5 >= 0) ? n5 : n0;                                       \
            int c6 = (n6 >= 0) ? n6 : n0;                                       \
            int c7 = (n7 >= 0) ? n7 : n0;                                       \
            uint4 u0 = *(const uint4*)&xb[n0 * 32 + q * 4];                     \
            uint4 u1 = *(const uint4*)&xb[c1 * 32 + q * 4];                     \
            uint4 u2 = *(const uint4*)&xb[c2 * 32 + q * 4];                     \
            uint4 u3 = *(const uint4*)&xb[c3 * 32 + q * 4];                     \
            uint4 u4 = *(const uint4*)&xb[c4 * 32 + q * 4];                     \
            uint4 u5 = *(const uint4*)&xb[c5 * 32 + q * 4];                     \
            uint4 u6 = *(const uint4*)&xb[c6 * 32 + q * 4];                     \
            uint4 u7 = *(const uint4*)&xb[c7 * 32 + q * 4];                     \
            if (n1 < 0) { u1.x = u1.y = u1.z = u1.w = 0; }                      \
            if (n2 < 0) { u2.x = u2.y = u2.z = u2.w = 0; }                      \
            if (n3 < 0) { u3.x = u3.y = u3.z = u3.w = 0; }                      \
            if (n4 < 0) { u4.x = u4.y = u4.z = u4.w = 0; }                      \
            if (n5 < 0) { u5.x = u5.y = u5.z = u5.w = 0; }                      \
            if (n6 < 0) { u6.x = u6.y = u6.z = u6.w = 0; }                      \
            if (n7 < 0) { u7.x = u7.y = u7.z = u7.w = 0; }                      \
            ACC8(u0); ACC8(u1); ACC8(u2); ACC8(u3);                             \
            ACC8(u4); ACC8(u5); ACC8(u6); ACC8(u7);                             \
            idcur = idnxt;                                                      \
        }                                                                       \
        unsigned int p0 = (unsigned int)f2bf(a0) | ((unsigned int)f2bf(a1) << 16); \
        unsigned int p1 = (unsigned int)f2bf(a2) | ((unsigned int)f2bf(a3) << 16); \
        unsigned int p2 = (unsigned int)f2bf(a4) | ((unsigned int)f2bf(a5) << 16); \
        unsigned int p3 = (unsigned int)f2bf(a6) | ((unsigned int)f2bf(a7) << 16); \
        *(uint4*)&agg_s[(w * NODESPW + (NIDX)) * 72 + q * 8] =                  \
            make_uint4(p0, p1, p2, p3);                                         \
    }

    DO_GROUP(b0, d0, id0, s)
    DO_GROUP(b1, d1, id1, 8 + s)
    DO_GROUP(b2, d2, id2, 16 + s)
#undef DO_GROUP

    __builtin_amdgcn_wave_barrier();

    // ---- MFMA pass 1: rows 0..15 ----
    v4s ax[4];
    #pragma unroll
    for (int kt = 0; kt < 4; kt++)
        ax[kt] = *(const v4s*)&xb[(node0w + lrow) * 32 + kt * 8 + g16 * 2];
    v4f acc[4];
    #pragma unroll
    for (int ct = 0; ct < 4; ct++) acc[ct] = (v4f){0.f, 0.f, 0.f, 0.f};
    #pragma unroll
    for (int kt = 0; kt < 4; kt++) {
        v4s a_agg = *(const v4s*)&agg_s[(w * NODESPW + lrow) * 72 + kt * 16 + g4];
        #pragma unroll
        for (int ct = 0; ct < 4; ct++) {
            int f = kt * 4 + ct;
            v4s wr = *(const v4s*)&wlds[f * 128 + l * 2];
            v4s wo = *(const v4s*)&wlds[2048 + f * 128 + l * 2];
            acc[ct] = __builtin_amdgcn_mfma_f32_16x16x16bf16_1k(a_agg, wr, acc[ct], 0, 0, 0);
            acc[ct] = __builtin_amdgcn_mfma_f32_16x16x16bf16_1k(ax[kt], wo, acc[ct], 0, 0, 0);
        }
    }
    // ---- MFMA pass 2: rows 16..23 (A rows replicated x2; keep D rows 0..7) ----
    const int r2row = 16 + (l & 7);
    v4s ax2[4];
    #pragma unroll
    for (int kt = 0; kt < 4; kt++)
        ax2[kt] = *(const v4s*)&xb[(node0w + r2row) * 32 + kt * 8 + g16 * 2];
    v4f acc2[4];
    #pragma unroll
    for (int ct = 0; ct < 4; ct++) acc2[ct] = (v4f){0.f, 0.f, 0.f, 0.f};
    #pragma unroll
    for (int kt = 0; kt < 4; kt++) {
        v4s a_agg2 = *(const v4s*)&agg_s[(w * NODESPW + r2row) * 72 + kt * 16 + g4];
        #pragma unroll
        for (int ct = 0; ct < 4; ct++) {
            int f = kt * 4 + ct;
            v4s wr = *(const v4s*)&wlds[f * 128 + l * 2];
            v4s wo = *(const v4s*)&wlds[2048 + f * 128 + l * 2];
            acc2[ct] = __builtin_amdgcn_mfma_f32_16x16x16bf16_1k(a_agg2, wr, acc2[ct], 0, 0, 0);
            acc2[ct] = __builtin_amdgcn_mfma_f32_16x16x16bf16_1k(ax2[kt], wo, acc2[ct], 0, 0, 0);
        }
    }
    __builtin_amdgcn_wave_barrier();

    // ---- epilogue into own agg rows ----
    #pragma unroll
    for (int ct = 0; ct < 4; ct++) {
        #pragma unroll
        for (int r = 0; r < 4; r++)
            agg_s[(w * NODESPW + g4 + r) * 72 + ct * 16 + lrow] = f2bf(acc[ct][r] + bv[ct]);
    }
    if (g16 < 2) {   // pass-2 valid D rows 0..7 -> nodes 16..23
        #pragma unroll
        for (int ct = 0; ct < 4; ct++) {
            #pragma unroll
            for (int r = 0; r < 4; r++)
                agg_s[(w * NODESPW + 16 + g4 + r) * 72 + ct * 16 + lrow] =
                    f2bf(acc2[ct][r] + bv[ct]);
        }
    }
    __builtin_amdgcn_wave_barrier();

    // ---- wave-local coalesced writeout: rows 0..15, then rows 16..23 ----
    {
        int row = l >> 2, qq = l & 3;
        const unsigned int* srcp = (const unsigned int*)&agg_s[(w * NODESPW + row) * 72 + qq * 16];
        uint4 v0 = *(const uint4*)(srcp);
        uint4 v1 = *(const uint4*)(srcp + 4);
        *(uint4*)&xob[(node0w + row) * 32 + qq * 8] = v0;
        *(uint4*)&xob[(node0w + row) * 32 + qq * 8 + 4] = v1;
    }
    {
        int row = 16 + (l >> 3), qq = l & 7;
        *(uint4*)&xob[(node0w + row) * 32 + qq * 4] =
            *(const uint4*)&agg_s[(w * NODESPW + row) * 72 + qq * 8];
    }
}

// ---------------- ligand pooling (bf16 x) ----------------
__global__ void pool_kernel(const unsigned int* __restrict__ xb,
                            const int* __restrict__ lig_batch,
                            float* __restrict__ pooled, float* __restrict__ cnt) {
    int node = blockIdx.x * 4 + (threadIdx.x >> 6);
    int h = threadIdx.x & 63;
    if (node >= NLIG) return;
    int b = lig_batch[node];
    unsigned int u = xb[node * 32 + (h >> 1)];
    float v = bf2f((unsigned short)((h & 1) ? (u >> 16) : (u & 0xffffu)));
    unsafeAtomicAdd(&pooled[b * H + h], v);
    if (h == 0) unsafeAtomicAdd(&cnt[b], 1.0f);
}

// ---------------- readout ----------------
__global__ void readout_kernel(const float* __restrict__ pooled, const float* __restrict__ cnt,
                               const float* __restrict__ Wro1, const float* __restrict__ bro1,
                               const float* __restrict__ Wro2, const float* __restrict__ bro2,
                               float* __restrict__ out) {
    __shared__ float pm[4][H];
    int w = threadIdx.x >> 6;
    int h = threadIdx.x & 63;
    int b = blockIdx.x * 4 + w;
    float c = fmaxf(cnt[b], 1.0f);
    pm[w][h] = pooled[b * H + h] / c;
    __syncthreads();
    float acc = bro1[h];
    #pragma unroll 8
    for (int k = 0; k < H; k++) acc += pm[w][k] * Wro1[k * H + h];
    float sig = 1.0f / (1.0f + expf(-acc));
    float s = acc * sig;
    float r = s * Wro2[h];
    #pragma unroll
    for (int off = 32; off; off >>= 1) r += __shfl_down(r, off);
    if (h == 0) out[b] = r + bro2[0];
}

extern "C" void kernel_launch(void* const* d_in, const int* in_sizes, int n_in,
                              void* d_out, int out_size, void* d_ws, size_t ws_size,
                              hipStream_t stream) {
    const float* lig_feat  = (const float*)d_in[1];
    const float* prot_feat = (const float*)d_in[3];
    const float* t         = (const float*)d_in[4];
    const int*   lig_batch = (const int*)d_in[5];
    const int*   edge_index= (const int*)d_in[7];
    const float* W_lig  = (const float*)d_in[8];
    const float* b_lig  = (const float*)d_in[9];
    const float* W_prot = (const float*)d_in[10];
    const float* b_prot = (const float*)d_in[11];
    const float* Wt1 = (const float*)d_in[12];
    const float* bt1 = (const float*)d_in[13];
    const float* Wt2 = (const float*)d_in[14];
    const float* bt2 = (const float*)d_in[15];
    const float* Wrel[3]  = {(const float*)d_in[16], (const float*)d_in[19], (const float*)d_in[22]};
    const float* brel[3]  = {(const float*)d_in[17], (const float*)d_in[20], (const float*)d_in[23]};
    const float* Wroot[3] = {(const float*)d_in[18], (const float*)d_in[21], (const float*)d_in[24]};
    const float* Wro1 = (const float*)d_in[25];
    const float* bro1 = (const float*)d_in[26];
    const float* Wro2 = (const float*)d_in[27];
    const float* bro2 = (const float*)d_in[28];
    float* out = (float*)d_out;

    char* ws = (char*)d_ws;
    int*            off_a   = (int*)(ws);                       // NTOT ints
    int*            ends_a  = (int*)(ws + 655360);              // NTOT ints
    unsigned int*   bcursor = (unsigned int*)(ws + 1310720);    // 2304 B
    float*          t_emb   = (float*)(ws + 1376256);
    float*          pooled  = (float*)(ws + 1441792);
    float*          cnt     = (float*)(ws + 1507328);
    unsigned short* wbuf    = (unsigned short*)(ws + 1572864);  // 48 KB
    int*            csr_src = (int*)(ws + 2097152);             // 10.6 MB padded
    unsigned int*   bucketed= (unsigned int*)(ws + 14680064);   // 10.6 MB padded
    unsigned int*   xb0     = (unsigned int*)(ws + 27262976);   // 18 MB
    unsigned int*   xb1     = (unsigned int*)(ws + 46137344);   // 18 MB
    unsigned int*   xbs[2]  = {xb0, xb1};

    time_mlp_kernel<<<NB, H, 0, stream>>>(t, Wt1, bt1, Wt2, bt2, t_emb);
    wswz_kernel<<<dim3(16, 6), 256, 0, stream>>>(Wrel[0], Wroot[0], Wrel[1], Wroot[1],
                                                 Wrel[2], Wroot[2], wbuf);
    node_init_kernel<<<NTOT / 4, 256, 0, stream>>>(lig_feat, prot_feat, lig_batch, t_emb,
                                                   W_lig, b_lig, W_prot, b_prot, xb0);

    // ---- padded-bucket CSR build ----
    hipMemsetAsync(bcursor, 0, 2304, stream);
    bucket_fill_kernel<<<NEDGE / 8192, 1024, 0, stream>>>(edge_index, bcursor, bucketed);
    bucket_csr_kernel<<<NBUCK, 512, 0, stream>>>(bucketed, bcursor, off_a, ends_a, csr_src);

    // ---- 3 fused graph convs (768 blocks = 3/CU exact; 24 nodes/wave) ----
    for (int lyr = 0; lyr < 3; lyr++) {
        unsigned int* cur = xbs[lyr & 1];
        unsigned int* nxt = xbs[(lyr + 1) & 1];
        conv_kernel<<<768, 512, 0, stream>>>(off_a, ends_a, csr_src, cur,
                                             wbuf + lyr * 8192, brel[lyr], nxt);
    }
    unsigned int* xfin = xbs[1];

    hipMemsetAsync(pooled, 0, (size_t)(NB * H + NB) * sizeof(float), stream);
    pool_kernel<<<NLIG / 4, 256, 0, stream>>>(xfin, lig_batch, pooled, cnt);
    readout_kernel<<<NB / 4, 256, 0, stream>>>(pooled, cnt, Wro1, bro1, Wro2, bro2, out);
}

// Round 13
// 240.315 us; speedup vs baseline: 3.3574x; 1.1038x over previous
//
#include <hip/hip_runtime.h>
#include <math.h>

#define NLIG 16384
#define NPROT 131072
#define NTOT (NLIG + NPROT)
#define NEDGE 2097152
#define NB 256
#define H 64
#define NBUCK 576      // NTOT = 576 * 256
#define BSHIFT 8       // bucket = dst >> 8
#define BCAP 4608      // padded bucket capacity (avg 3641, sd ~60 -> 16 sigma)
#define NODESPW 18     // 8192 waves x 18 nodes = 147456 = NTOT exactly (no tail)

typedef short v4s __attribute__((ext_vector_type(4)));
typedef float v4f __attribute__((ext_vector_type(4)));

__device__ __forceinline__ unsigned short f2bf(float f) {
    unsigned int u = __float_as_uint(f);
    u += 0x7fff + ((u >> 16) & 1);   // RNE
    return (unsigned short)(u >> 16);
}
__device__ __forceinline__ float bf2f(unsigned short s) {
    return __uint_as_float(((unsigned int)s) << 16);
}
__device__ __forceinline__ float bflo(unsigned int u) {
    return __uint_as_float(u << 16);
}
__device__ __forceinline__ float bfhi(unsigned int u) {
    return __uint_as_float(u & 0xffff0000u);
}

// ---------------- time embedding MLP ----------------
__global__ void time_mlp_kernel(const float* __restrict__ t,
                                const float* __restrict__ Wt1, const float* __restrict__ bt1,
                                const float* __restrict__ Wt2, const float* __restrict__ bt2,
                                float* __restrict__ t_emb) {
    int b = blockIdx.x;
    int h = threadIdx.x;
    __shared__ float emb_s[H];
    __shared__ float h1_s[H];
    float tv = t[b];
    int i = h & 31;
    float freq = expf((float)i * (-9.2103403719761836f / 31.0f));
    float e = tv * freq;
    emb_s[h] = (h < 32) ? sinf(e) : cosf(e);
    __syncthreads();
    float acc = bt1[h];
    #pragma unroll 8
    for (int k = 0; k < H; k++) acc += emb_s[k] * Wt1[k * H + h];
    float sig = 1.0f / (1.0f + expf(-acc));
    h1_s[h] = acc * sig;
    __syncthreads();
    float acc2 = bt2[h];
    #pragma unroll 8
    for (int k = 0; k < H; k++) acc2 += h1_s[k] * Wt2[k * H + h];
    t_emb[b * H + h] = acc2;
}

// ---------------- weight pre-swizzle into MFMA B-fragment order (bf16) ----------------
__global__ void wswz_kernel(const float* __restrict__ W0, const float* __restrict__ W1,
                            const float* __restrict__ W2, const float* __restrict__ W3,
                            const float* __restrict__ W4, const float* __restrict__ W5,
                            unsigned short* __restrict__ wbuf) {
    const float* Ws[6] = {W0, W1, W2, W3, W4, W5};
    int m = blockIdx.y;
    int t = blockIdx.x * 256 + threadIdx.x;   // 0..4095
    int f = t >> 8, l = (t >> 2) & 63, i = t & 3;
    int kt = f >> 2, ct = f & 3;
    int row = 16 * kt + 4 * (l >> 4) + i;
    int col = 16 * ct + (l & 15);
    wbuf[m * 4096 + t] = f2bf(Ws[m][row * H + col]);
}

// ---------------- node feature init -> bf16-packed x ----------------
__global__ void node_init_kernel(const float* __restrict__ lig_feat,
                                 const float* __restrict__ prot_feat,
                                 const int* __restrict__ lig_batch,
                                 const float* __restrict__ t_emb,
                                 const float* __restrict__ W_lig, const float* __restrict__ b_lig,
                                 const float* __restrict__ W_prot, const float* __restrict__ b_prot,
                                 unsigned int* __restrict__ xb) {
    int node = blockIdx.x * 4 + (threadIdx.x >> 6);
    int h = threadIdx.x & 63;
    if (node >= NTOT) return;
    float acc;
    if (node < NLIG) {
        int b = lig_batch[node];
        acc = b_lig[h] + t_emb[b * H + h];
        #pragma unroll
        for (int k = 0; k < 15; k++)
            acc += lig_feat[node * 15 + k] * W_lig[k * H + h];
    } else {
        int p = node - NLIG;
        acc = b_prot[h];
        #pragma unroll
        for (int k = 0; k < 8; k++)
            acc += prot_feat[p * 8 + k] * W_prot[k * H + h];
    }
    float e0 = __shfl(acc, 2 * (h & 31));
    float e1 = __shfl(acc, 2 * (h & 31) + 1);
    if (h < 32)
        xb[node * 32 + h] = (unsigned int)f2bf(e0) | ((unsigned int)f2bf(e1) << 16);
}

// ---------------- bucketed CSR build (padded buckets: no hist/scan pass) ----------------
__global__ __launch_bounds__(1024) void bucket_fill_kernel(const int* __restrict__ edge_index,
                                                           unsigned int* __restrict__ bcursor,
                                                           unsigned int* __restrict__ bucketed) {
    __shared__ unsigned int lh[NBUCK];
    __shared__ unsigned int lcur[NBUCK];
    __shared__ unsigned int gb[NBUCK];
    int tid = threadIdx.x;
    for (int i = tid; i < NBUCK; i += 1024) lh[i] = 0;
    __syncthreads();
    int e0 = blockIdx.x * 8192;
    int src[8], dst[8];
    #pragma unroll
    for (int k = 0; k < 8; k++) {
        src[k] = edge_index[e0 + k * 1024 + tid];
        dst[k] = edge_index[NEDGE + e0 + k * 1024 + tid];
        atomicAdd(&lh[dst[k] >> BSHIFT], 1);
    }
    __syncthreads();
    if (tid < NBUCK) {
        gb[tid] = atomicAdd(&bcursor[tid], lh[tid]);
        lcur[tid] = 0;
    }
    __syncthreads();
    #pragma unroll
    for (int k = 0; k < 8; k++) {
        int b = dst[k] >> BSHIFT;
        unsigned int r = atomicAdd(&lcur[b], 1);
        unsigned int slot = gb[b] + r;
        if (slot < BCAP)
            bucketed[b * BCAP + slot] = (unsigned int)src[k] | ((unsigned int)(dst[k] & 255) << 18);
    }
}

// per-bucket counting sort in LDS -> csr_src + per-node [beg,end)
__global__ __launch_bounds__(512) void bucket_csr_kernel(const unsigned int* __restrict__ bucketed,
                                                         const unsigned int* __restrict__ bcursor,
                                                         int* __restrict__ off,
                                                         int* __restrict__ ends,
                                                         int* __restrict__ csr_src) {
    __shared__ unsigned int stage[BCAP];   // 18 KB packed
    __shared__ unsigned int csr_l[BCAP];   // 18 KB
    __shared__ unsigned int lh[256];
    __shared__ unsigned int lbeg[512];
    __shared__ unsigned int lcur[256];
    int b = blockIdx.x, tid = threadIdx.x;
    unsigned int base = (unsigned int)b * BCAP;
    int cnt = (int)bcursor[b];
    if (cnt > BCAP) cnt = BCAP;   // 16-sigma guard, never triggers
    for (int i = tid; i < 256; i += 512) lh[i] = 0;
    __syncthreads();
    for (int i = tid; i < cnt; i += 512) {
        unsigned int v = bucketed[base + i];
        stage[i] = v;
        atomicAdd(&lh[v >> 18], 1);
    }
    __syncthreads();
    unsigned int own = (tid < 256) ? lh[tid] : 0;
    lbeg[tid] = own;
    __syncthreads();
    for (int d = 1; d < 512; d <<= 1) {
        unsigned int v = (tid >= d) ? lbeg[tid - d] : 0;
        __syncthreads();
        lbeg[tid] += v;
        __syncthreads();
    }
    unsigned int excl = lbeg[tid] - own;
    __syncthreads();
    lbeg[tid] = excl;
    if (tid < 256) {
        lcur[tid] = excl;
        off[b * 256 + tid]  = (int)(base + excl);
        ends[b * 256 + tid] = (int)(base + excl + own);
    }
    __syncthreads();
    for (int i = tid; i < cnt; i += 512) {
        unsigned int v = stage[i];
        unsigned int p = atomicAdd(&lcur[v >> 18], 1);
        csr_l[p] = v & 0x3ffffu;
    }
    __syncthreads();
    for (int i = tid; i < cnt; i += 512)
        csr_src[base + i] = (int)csr_l[i];
}

// accumulate one 16B quad of a neighbor row
#define ACC8(u)                                   \
    do {                                          \
        a0 += bflo((u).x); a1 += bfhi((u).x);     \
        a2 += bflo((u).y); a3 += bfhi((u).y);     \
        a4 += bflo((u).z); a5 += bfhi(u.z);       \
        a6 += bflo((u).w); a7 += bfhi((u).w);     \
    } while (0)

// 8-deep unconditional gather over one slot-group; store guarded by NIDX
#define DO_GROUP(BEG, DEG, IDFIRST, NIDX, AGGROW)                               \
    {                                                                           \
        int idcur = (IDFIRST);                                                  \
        float a0 = 0.f, a1 = 0.f, a2 = 0.f, a3 = 0.f;                           \
        float a4 = 0.f, a5 = 0.f, a6 = 0.f, a7 = 0.f;                           \
        for (int jb = 0; jb < (DEG); jb += 8) {                                 \
            int idnxt = (jb + 8 + q < (DEG)) ? csr[(BEG) + jb + 8 + q] : -1;    \
            int n0 = __shfl(idcur, s * 8 + 0);                                  \
            int n1 = __shfl(idcur, s * 8 + 1);                                  \
            int n2 = __shfl(idcur, s * 8 + 2);                                  \
            int n3 = __shfl(idcur, s * 8 + 3);                                  \
            int n4 = __shfl(idcur, s * 8 + 4);                                  \
            int n5 = __shfl(idcur, s * 8 + 5);                                  \
            int n6 = __shfl(idcur, s * 8 + 6);                                  \
            int n7 = __shfl(idcur, s * 8 + 7);                                  \
            int c1 = (n1 >= 0) ? n1 : n0;                                       \
            int c2 = (n2 >= 0) ? n2 : n0;                                       \
            int c3 = (n3 >= 0) ? n3 : n0;                                       \
            int c4 = (n4 >= 0) ? n4 : n0;                                       \
            int c5 = (n5 >= 0) ? n5 : n0;                                       \
            int c6 = (n6 >= 0) ? n6 : n0;                                       \
            int c7 = (n7 >= 0) ? n7 : n0;                                       \
            uint4 u0 = *(const uint4*)&xb[n0 * 32 + q * 4];                     \
            uint4 u1 = *(const uint4*)&xb[c1 * 32 + q * 4];                     \
            uint4 u2 = *(const uint4*)&xb[c2 * 32 + q * 4];                     \
            uint4 u3 = *(const uint4*)&xb[c3 * 32 + q * 4];                     \
            uint4 u4 = *(const uint4*)&xb[c4 * 32 + q * 4];                     \
            uint4 u5 = *(const uint4*)&xb[c5 * 32 + q * 4];                     \
            uint4 u6 = *(const uint4*)&xb[c6 * 32 + q * 4];                     \
            uint4 u7 = *(const uint4*)&xb[c7 * 32 + q * 4];                     \
            if (n1 < 0) { u1.x = u1.y = u1.z = u1.w = 0; }                      \
            if (n2 < 0) { u2.x = u2.y = u2.z = u2.w = 0; }                      \
            if (n3 < 0) { u3.x = u3.y = u3.z = u3.w = 0; }                      \
            if (n4 < 0) { u4.x = u4.y = u4.z = u4.w = 0; }                      \
            if (n5 < 0) { u5.x = u5.y = u5.z = u5.w = 0; }                      \
            if (n6 < 0) { u6.x = u6.y = u6.z = u6.w = 0; }                      \
            if (n7 < 0) { u7.x = u7.y = u7.z = u7.w = 0; }                      \
            ACC8(u0); ACC8(u1); ACC8(u2); ACC8(u3);                             \
            ACC8(u4); ACC8(u5); ACC8(u6); ACC8(u7);                             \
            idcur = idnxt;                                                      \
        }                                                                       \
        if ((NIDX) < NODESPW) {                                                 \
            unsigned int p0 = (unsigned int)f2bf(a0) | ((unsigned int)f2bf(a1) << 16); \
            unsigned int p1 = (unsigned int)f2bf(a2) | ((unsigned int)f2bf(a3) << 16); \
            unsigned int p2 = (unsigned int)f2bf(a4) | ((unsigned int)f2bf(a5) << 16); \
            unsigned int p3 = (unsigned int)f2bf(a6) | ((unsigned int)f2bf(a7) << 16); \
            *(uint4*)&agg_s[(AGGROW) * 72 + q * 8] = make_uint4(p0, p1, p2, p3); \
        }                                                                       \
    }

// ---------------- fused conv (layers 1,2): 18 nodes/wave, 8-deep gather ----------------
// Grid = 1024 blocks x 512 thr = 8192 waves x 18 nodes = NTOT exactly; 4 blocks/CU
// (LDS 36.25KB x 4 = 145KB), VGPR <= 64 at waves/EU=8 (round-12 gather = 40 VGPR).
__global__ __launch_bounds__(512, 8) void conv_kernel(const int* __restrict__ off,
                                                      const int* __restrict__ ends,
                                                      const int* __restrict__ csr,
                                                      const unsigned int* __restrict__ xb,
                                                      const unsigned short* __restrict__ wbuf,
                                                      const float* __restrict__ brel,
                                                      unsigned int* __restrict__ xob) {
    __shared__ unsigned int wlds[4096];                // 16 KB
    __shared__ unsigned short agg_s[8 * NODESPW * 72]; // 20.25 KB
    const int tid = threadIdx.x;
    const int w = tid >> 6, l = tid & 63;
    const unsigned int* wsrc = (const unsigned int*)wbuf;
    #pragma unroll
    for (int i = 0; i < 8; i++) wlds[i * 512 + tid] = wsrc[i * 512 + tid];

    const int s = l >> 3, q = l & 7;
    const int lrow = l & 15, g16 = l >> 4, g4 = 4 * (l >> 4);
    const int gwid = blockIdx.x * 8 + w;
    const int node0w = gwid * NODESPW;

    int bvv = (l < NODESPW) ? off[node0w + l] : 0;
    int evv = (l < NODESPW) ? ends[node0w + l] : 0;

    int b0 = __shfl(bvv, s),      d0 = __shfl(evv, s) - b0;
    int b1 = __shfl(bvv, 8 + s),  d1 = __shfl(evv, 8 + s) - b1;
    int b2 = __shfl(bvv, 16 + s), d2 = __shfl(evv, 16 + s) - b2;
    int id0 = (q < d0) ? csr[b0 + q] : -1;
    int id1 = (q < d1) ? csr[b1 + q] : -1;
    int id2 = (q < d2) ? csr[b2 + q] : -1;

    __syncthreads();   // wlds ready

    float bv[4];
    #pragma unroll
    for (int ct = 0; ct < 4; ct++) bv[ct] = brel[ct * 16 + lrow];

    DO_GROUP(b0, d0, id0, s,      w * NODESPW + s)
    DO_GROUP(b1, d1, id1, 8 + s,  w * NODESPW + 8 + s)
    DO_GROUP(b2, d2, id2, 16 + s, w * NODESPW + 16 + s)

    __builtin_amdgcn_wave_barrier();

    // ---- MFMA pass 1: rows 0..15 ----
    v4s ax[4];
    #pragma unroll
    for (int kt = 0; kt < 4; kt++)
        ax[kt] = *(const v4s*)&xb[(node0w + lrow) * 32 + kt * 8 + g16 * 2];
    v4f acc[4];
    #pragma unroll
    for (int ct = 0; ct < 4; ct++) acc[ct] = (v4f){0.f, 0.f, 0.f, 0.f};
    #pragma unroll
    for (int kt = 0; kt < 4; kt++) {
        v4s a_agg = *(const v4s*)&agg_s[(w * NODESPW + lrow) * 72 + kt * 16 + g4];
        #pragma unroll
        for (int ct = 0; ct < 4; ct++) {
            int f = kt * 4 + ct;
            v4s wr = *(const v4s*)&wlds[f * 128 + l * 2];
            v4s wo = *(const v4s*)&wlds[2048 + f * 128 + l * 2];
            acc[ct] = __builtin_amdgcn_mfma_f32_16x16x16bf16_1k(a_agg, wr, acc[ct], 0, 0, 0);
            acc[ct] = __builtin_amdgcn_mfma_f32_16x16x16bf16_1k(ax[kt], wo, acc[ct], 0, 0, 0);
        }
    }
    // ---- MFMA pass 2: rows 16..17 (A rows replicated; keep D rows 0..1) ----
    const int r2row = 16 + (lrow & 1);
    v4s ax2[4];
    #pragma unroll
    for (int kt = 0; kt < 4; kt++)
        ax2[kt] = *(const v4s*)&xb[(node0w + r2row) * 32 + kt * 8 + g16 * 2];
    v4f acc2[4];
    #pragma unroll
    for (int ct = 0; ct < 4; ct++) acc2[ct] = (v4f){0.f, 0.f, 0.f, 0.f};
    #pragma unroll
    for (int kt = 0; kt < 4; kt++) {
        v4s a_agg2 = *(const v4s*)&agg_s[(w * NODESPW + r2row) * 72 + kt * 16 + g4];
        #pragma unroll
        for (int ct = 0; ct < 4; ct++) {
            int f = kt * 4 + ct;
            v4s wr = *(const v4s*)&wlds[f * 128 + l * 2];
            v4s wo = *(const v4s*)&wlds[2048 + f * 128 + l * 2];
            acc2[ct] = __builtin_amdgcn_mfma_f32_16x16x16bf16_1k(a_agg2, wr, acc2[ct], 0, 0, 0);
            acc2[ct] = __builtin_amdgcn_mfma_f32_16x16x16bf16_1k(ax2[kt], wo, acc2[ct], 0, 0, 0);
        }
    }
    __builtin_amdgcn_wave_barrier();

    // ---- epilogue into own agg rows ----
    #pragma unroll
    for (int ct = 0; ct < 4; ct++) {
        #pragma unroll
        for (int r = 0; r < 4; r++)
            agg_s[(w * NODESPW + g4 + r) * 72 + ct * 16 + lrow] = f2bf(acc[ct][r] + bv[ct]);
    }
    if (g16 == 0) {   // pass-2 valid outputs: D rows 0,1 -> nodes 16,17
        #pragma unroll
        for (int ct = 0; ct < 4; ct++) {
            agg_s[(w * NODESPW + 16) * 72 + ct * 16 + lrow] = f2bf(acc2[ct][0] + bv[ct]);
            agg_s[(w * NODESPW + 17) * 72 + ct * 16 + lrow] = f2bf(acc2[ct][1] + bv[ct]);
        }
    }
    __builtin_amdgcn_wave_barrier();

    // ---- wave-local coalesced writeout: rows 0..15, then rows 16..17 ----
    {
        int row = l >> 2, qq = l & 3;
        const unsigned int* srcp = (const unsigned int*)&agg_s[(w * NODESPW + row) * 72 + qq * 16];
        uint4 v0 = *(const uint4*)(srcp);
        uint4 v1 = *(const uint4*)(srcp + 4);
        *(uint4*)&xob[(node0w + row) * 32 + qq * 8] = v0;
        *(uint4*)&xob[(node0w + row) * 32 + qq * 8 + 4] = v1;
    }
    {
        int row = 16 + (l >> 5), dw = l & 31;
        xob[(node0w + row) * 32 + dw] =
            *(const unsigned int*)&agg_s[(w * NODESPW + row) * 72 + dw * 2];
    }
}

// ---------------- conv layer 3 (ligand rows only) + fused pooling ----------------
// Only x[:NLIG] of conv3's output is used by the reference -> process just the
// 16384 ligand dst nodes (1/9 the work). 8 nodes/wave x 2048 waves (256 blocks).
// Single MFMA pass with rows duplicated (A row = lrow&7); D rows 0..7 valid.
// Epilogue adds f32 outputs directly into pooled[batch] (+1 to cnt) — the
// separate pool kernel and conv3's 18 MB writeout are deleted.
__global__ __launch_bounds__(512, 8) void conv_lig_kernel(const int* __restrict__ off,
                                                          const int* __restrict__ ends,
                                                          const int* __restrict__ csr,
                                                          const unsigned int* __restrict__ xb,
                                                          const unsigned short* __restrict__ wbuf,
                                                          const float* __restrict__ brel,
                                                          const int* __restrict__ lig_batch,
                                                          float* __restrict__ pooled,
                                                          float* __restrict__ cnt) {
    __shared__ unsigned int wlds[4096];          // 16 KB
    __shared__ unsigned short agg_s[8 * 8 * 72]; // 9 KB
    const int tid = threadIdx.x;
    const int w = tid >> 6, l = tid & 63;
    const unsigned int* wsrc = (const unsigned int*)wbuf;
    #pragma unroll
    for (int i = 0; i < 8; i++) wlds[i * 512 + tid] = wsrc[i * 512 + tid];

    const int s = l >> 3, q = l & 7;
    const int lrow = l & 15, g16 = l >> 4, g4 = 4 * (l >> 4);
    const int gwid = blockIdx.x * 8 + w;
    const int node0w = gwid * 8;

    int bvv = (l < 8) ? off[node0w + l] : 0;
    int evv = (l < 8) ? ends[node0w + l] : 0;
    int b0 = __shfl(bvv, s), d0 = __shfl(evv, s) - b0;
    int id0 = (q < d0) ? csr[b0 + q] : -1;

    __syncthreads();   // wlds ready

    float bv[4];
    #pragma unroll
    for (int ct = 0; ct < 4; ct++) bv[ct] = brel[ct * 16 + lrow];

    {
        int idcur = id0;
        float a0 = 0.f, a1 = 0.f, a2 = 0.f, a3 = 0.f;
        float a4 = 0.f, a5 = 0.f, a6 = 0.f, a7 = 0.f;
        for (int jb = 0; jb < d0; jb += 8) {
            int idnxt = (jb + 8 + q < d0) ? csr[b0 + jb + 8 + q] : -1;
            int n0 = __shfl(idcur, s * 8 + 0);
            int n1 = __shfl(idcur, s * 8 + 1);
            int n2 = __shfl(idcur, s * 8 + 2);
            int n3 = __shfl(idcur, s * 8 + 3);
            int n4 = __shfl(idcur, s * 8 + 4);
            int n5 = __shfl(idcur, s * 8 + 5);
            int n6 = __shfl(idcur, s * 8 + 6);
            int n7 = __shfl(idcur, s * 8 + 7);
            int c1 = (n1 >= 0) ? n1 : n0;
            int c2 = (n2 >= 0) ? n2 : n0;
            int c3 = (n3 >= 0) ? n3 : n0;
            int c4 = (n4 >= 0) ? n4 : n0;
            int c5 = (n5 >= 0) ? n5 : n0;
            int c6 = (n6 >= 0) ? n6 : n0;
            int c7 = (n7 >= 0) ? n7 : n0;
            uint4 u0 = *(const uint4*)&xb[n0 * 32 + q * 4];
            uint4 u1 = *(const uint4*)&xb[c1 * 32 + q * 4];
            uint4 u2 = *(const uint4*)&xb[c2 * 32 + q * 4];
            uint4 u3 = *(const uint4*)&xb[c3 * 32 + q * 4];
            uint4 u4 = *(const uint4*)&xb[c4 * 32 + q * 4];
            uint4 u5 = *(const uint4*)&xb[c5 * 32 + q * 4];
            uint4 u6 = *(const uint4*)&xb[c6 * 32 + q * 4];
            uint4 u7 = *(const uint4*)&xb[c7 * 32 + q * 4];
            if (n1 < 0) { u1.x = u1.y = u1.z = u1.w = 0; }
            if (n2 < 0) { u2.x = u2.y = u2.z = u2.w = 0; }
            if (n3 < 0) { u3.x = u3.y = u3.z = u3.w = 0; }
            if (n4 < 0) { u4.x = u4.y = u4.z = u4.w = 0; }
            if (n5 < 0) { u5.x = u5.y = u5.z = u5.w = 0; }
            if (n6 < 0) { u6.x = u6.y = u6.z = u6.w = 0; }
            if (n7 < 0) { u7.x = u7.y = u7.z = u7.w = 0; }
            ACC8(u0); ACC8(u1); ACC8(u2); ACC8(u3);
            ACC8(u4); ACC8(u5); ACC8(u6); ACC8(u7);
            idcur = idnxt;
        }
        unsigned int p0 = (unsigned int)f2bf(a0) | ((unsigned int)f2bf(a1) << 16);
        unsigned int p1 = (unsigned int)f2bf(a2) | ((unsigned int)f2bf(a3) << 16);
        unsigned int p2 = (unsigned int)f2bf(a4) | ((unsigned int)f2bf(a5) << 16);
        unsigned int p3 = (unsigned int)f2bf(a6) | ((unsigned int)f2bf(a7) << 16);
        *(uint4*)&agg_s[(w * 8 + s) * 72 + q * 8] = make_uint4(p0, p1, p2, p3);
    }
    __builtin_amdgcn_wave_barrier();

    // ---- MFMA: A rows duplicated (row = lrow&7) -> D rows 0..7 valid ----
    const int arow = lrow & 7;
    v4s ax[4];
    #pragma unroll
    for (int kt = 0; kt < 4; kt++)
        ax[kt] = *(const v4s*)&xb[(node0w + arow) * 32 + kt * 8 + g16 * 2];
    v4f acc[4];
    #pragma unroll
    for (int ct = 0; ct < 4; ct++) acc[ct] = (v4f){0.f, 0.f, 0.f, 0.f};
    #pragma unroll
    for (int kt = 0; kt < 4; kt++) {
        v4s a_agg = *(const v4s*)&agg_s[(w * 8 + arow) * 72 + kt * 16 + g4];
        #pragma unroll
        for (int ct = 0; ct < 4; ct++) {
            int f = kt * 4 + ct;
            v4s wr = *(const v4s*)&wlds[f * 128 + l * 2];
            v4s wo = *(const v4s*)&wlds[2048 + f * 128 + l * 2];
            acc[ct] = __builtin_amdgcn_mfma_f32_16x16x16bf16_1k(a_agg, wr, acc[ct], 0, 0, 0);
            acc[ct] = __builtin_amdgcn_mfma_f32_16x16x16bf16_1k(ax[kt], wo, acc[ct], 0, 0, 0);
        }
    }

    // ---- fused pooling epilogue (f32 atomics; D rows 0..7 only) ----
    if (g16 < 2) {
        #pragma unroll
        for (int r = 0; r < 4; r++) {
            int node = node0w + g4 + r;
            int bb = lig_batch[node];
            #pragma unroll
            for (int ct = 0; ct < 4; ct++)
                unsafeAtomicAdd(&pooled[bb * H + ct * 16 + lrow], acc[ct][r] + bv[ct]);
            if (lrow == 0) unsafeAtomicAdd(&cnt[bb], 1.0f);
        }
    }
}

// ---------------- readout ----------------
__global__ void readout_kernel(const float* __restrict__ pooled, const float* __restrict__ cnt,
                               const float* __restrict__ Wro1, const float* __restrict__ bro1,
                               const float* __restrict__ Wro2, const float* __restrict__ bro2,
                               float* __restrict__ out) {
    __shared__ float pm[4][H];
    int w = threadIdx.x >> 6;
    int h = threadIdx.x & 63;
    int b = blockIdx.x * 4 + w;
    float c = fmaxf(cnt[b], 1.0f);
    pm[w][h] = pooled[b * H + h] / c;
    __syncthreads();
    float acc = bro1[h];
    #pragma unroll 8
    for (int k = 0; k < H; k++) acc += pm[w][k] * Wro1[k * H + h];
    float sig = 1.0f / (1.0f + expf(-acc));
    float s = acc * sig;
    float r = s * Wro2[h];
    #pragma unroll
    for (int off = 32; off; off >>= 1) r += __shfl_down(r, off);
    if (h == 0) out[b] = r + bro2[0];
}

extern "C" void kernel_launch(void* const* d_in, const int* in_sizes, int n_in,
                              void* d_out, int out_size, void* d_ws, size_t ws_size,
                              hipStream_t stream) {
    const float* lig_feat  = (const float*)d_in[1];
    const float* prot_feat = (const float*)d_in[3];
    const float* t         = (const float*)d_in[4];
    const int*   lig_batch = (const int*)d_in[5];
    const int*   edge_index= (const int*)d_in[7];
    const float* W_lig  = (const float*)d_in[8];
    const float* b_lig  = (const float*)d_in[9];
    const float* W_prot = (const float*)d_in[10];
    const float* b_prot = (const float*)d_in[11];
    const float* Wt1 = (const float*)d_in[12];
    const float* bt1 = (const float*)d_in[13];
    const float* Wt2 = (const float*)d_in[14];
    const float* bt2 = (const float*)d_in[15];
    const float* Wrel[3]  = {(const float*)d_in[16], (const float*)d_in[19], (const float*)d_in[22]};
    const float* brel[3]  = {(const float*)d_in[17], (const float*)d_in[20], (const float*)d_in[23]};
    const float* Wroot[3] = {(const float*)d_in[18], (const float*)d_in[21], (const float*)d_in[24]};
    const float* Wro1 = (const float*)d_in[25];
    const float* bro1 = (const float*)d_in[26];
    const float* Wro2 = (const float*)d_in[27];
    const float* bro2 = (const float*)d_in[28];
    float* out = (float*)d_out;

    char* ws = (char*)d_ws;
    int*            off_a   = (int*)(ws);                       // NTOT ints
    int*            ends_a  = (int*)(ws + 655360);              // NTOT ints
    unsigned int*   bcursor = (unsigned int*)(ws + 1310720);    // 2304 B
    float*          t_emb   = (float*)(ws + 1376256);
    float*          pooled  = (float*)(ws + 1441792);
    float*          cnt     = (float*)(ws + 1507328);
    unsigned short* wbuf    = (unsigned short*)(ws + 1572864);  // 48 KB
    int*            csr_src = (int*)(ws + 2097152);             // 10.6 MB padded
    unsigned int*   bucketed= (unsigned int*)(ws + 14680064);   // 10.6 MB padded
    unsigned int*   xb0     = (unsigned int*)(ws + 27262976);   // 18 MB
    unsigned int*   xb1     = (unsigned int*)(ws + 46137344);   // 18 MB

    time_mlp_kernel<<<NB, H, 0, stream>>>(t, Wt1, bt1, Wt2, bt2, t_emb);
    wswz_kernel<<<dim3(16, 6), 256, 0, stream>>>(Wrel[0], Wroot[0], Wrel[1], Wroot[1],
                                                 Wrel[2], Wroot[2], wbuf);
    node_init_kernel<<<NTOT / 4, 256, 0, stream>>>(lig_feat, prot_feat, lig_batch, t_emb,
                                                   W_lig, b_lig, W_prot, b_prot, xb0);

    // ---- padded-bucket CSR build ----
    hipMemsetAsync(bcursor, 0, 2304, stream);
    bucket_fill_kernel<<<NEDGE / 8192, 1024, 0, stream>>>(edge_index, bcursor, bucketed);
    bucket_csr_kernel<<<NBUCK, 512, 0, stream>>>(bucketed, bcursor, off_a, ends_a, csr_src);

    // zero pooled+cnt (needed by conv_lig's fused pooling)
    hipMemsetAsync(pooled, 0, (size_t)(NB * H + NB) * sizeof(float), stream);

    // ---- conv layers 1,2 (all nodes) ----
    conv_kernel<<<1024, 512, 0, stream>>>(off_a, ends_a, csr_src, xb0,
                                          wbuf, brel[0], xb1);
    conv_kernel<<<1024, 512, 0, stream>>>(off_a, ends_a, csr_src, xb1,
                                          wbuf + 8192, brel[1], xb0);
    // ---- conv layer 3: ligand rows only, fused pooling ----
    conv_lig_kernel<<<NLIG / 64, 512, 0, stream>>>(off_a, ends_a, csr_src, xb0,
                                                   wbuf + 16384, brel[2], lig_batch,
                                                   pooled, cnt);

    readout_kernel<<<NB / 4, 256, 0, stream>>>(pooled, cnt, Wro1, bro1, Wro2, bro2, out);
}

// Round 14
// 219.882 us; speedup vs baseline: 3.6694x; 1.0929x over previous
//
#include <hip/hip_runtime.h>
#include <math.h>

#define NLIG 16384
#define NPROT 131072
#define NTOT (NLIG + NPROT)
#define NEDGE 2097152
#define NB 256
#define H 64
#define NBUCK 576      // NTOT = 576 * 256
#define BSHIFT 8       // bucket = dst >> 8
#define BCAP 4608      // padded bucket capacity (avg 3641, sd ~60 -> 16 sigma)
#define NPW 24         // 768 blocks x 8 waves x 24 nodes = 147456 = NTOT exactly

typedef short v4s __attribute__((ext_vector_type(4)));
typedef float v4f __attribute__((ext_vector_type(4)));

__device__ __forceinline__ unsigned short f2bf(float f) {
    unsigned int u = __float_as_uint(f);
    u += 0x7fff + ((u >> 16) & 1);   // RNE
    return (unsigned short)(u >> 16);
}
__device__ __forceinline__ float bf2f(unsigned short s) {
    return __uint_as_float(((unsigned int)s) << 16);
}
__device__ __forceinline__ float bflo(unsigned int u) {
    return __uint_as_float(u << 16);
}
__device__ __forceinline__ float bfhi(unsigned int u) {
    return __uint_as_float(u & 0xffff0000u);
}

// ---------------- time embedding MLP ----------------
__global__ void time_mlp_kernel(const float* __restrict__ t,
                                const float* __restrict__ Wt1, const float* __restrict__ bt1,
                                const float* __restrict__ Wt2, const float* __restrict__ bt2,
                                float* __restrict__ t_emb) {
    int b = blockIdx.x;
    int h = threadIdx.x;
    __shared__ float emb_s[H];
    __shared__ float h1_s[H];
    float tv = t[b];
    int i = h & 31;
    float freq = expf((float)i * (-9.2103403719761836f / 31.0f));
    float e = tv * freq;
    emb_s[h] = (h < 32) ? sinf(e) : cosf(e);
    __syncthreads();
    float acc = bt1[h];
    #pragma unroll 8
    for (int k = 0; k < H; k++) acc += emb_s[k] * Wt1[k * H + h];
    float sig = 1.0f / (1.0f + expf(-acc));
    h1_s[h] = acc * sig;
    __syncthreads();
    float acc2 = bt2[h];
    #pragma unroll 8
    for (int k = 0; k < H; k++) acc2 += h1_s[k] * Wt2[k * H + h];
    t_emb[b * H + h] = acc2;
}

// ---------------- weight pre-swizzle into MFMA B-fragment order (bf16) ----------------
__global__ void wswz_kernel(const float* __restrict__ W0, const float* __restrict__ W1,
                            const float* __restrict__ W2, const float* __restrict__ W3,
                            const float* __restrict__ W4, const float* __restrict__ W5,
                            unsigned short* __restrict__ wbuf) {
    const float* Ws[6] = {W0, W1, W2, W3, W4, W5};
    int m = blockIdx.y;
    int t = blockIdx.x * 256 + threadIdx.x;   // 0..4095
    int f = t >> 8, l = (t >> 2) & 63, i = t & 3;
    int kt = f >> 2, ct = f & 3;
    int row = 16 * kt + 4 * (l >> 4) + i;
    int col = 16 * ct + (l & 15);
    wbuf[m * 4096 + t] = f2bf(Ws[m][row * H + col]);
}

// ---------------- node feature init -> bf16-packed x ----------------
__global__ void node_init_kernel(const float* __restrict__ lig_feat,
                                 const float* __restrict__ prot_feat,
                                 const int* __restrict__ lig_batch,
                                 const float* __restrict__ t_emb,
                                 const float* __restrict__ W_lig, const float* __restrict__ b_lig,
                                 const float* __restrict__ W_prot, const float* __restrict__ b_prot,
                                 unsigned int* __restrict__ xb) {
    int node = blockIdx.x * 4 + (threadIdx.x >> 6);
    int h = threadIdx.x & 63;
    if (node >= NTOT) return;
    float acc;
    if (node < NLIG) {
        int b = lig_batch[node];
        acc = b_lig[h] + t_emb[b * H + h];
        #pragma unroll
        for (int k = 0; k < 15; k++)
            acc += lig_feat[node * 15 + k] * W_lig[k * H + h];
    } else {
        int p = node - NLIG;
        acc = b_prot[h];
        #pragma unroll
        for (int k = 0; k < 8; k++)
            acc += prot_feat[p * 8 + k] * W_prot[k * H + h];
    }
    float e0 = __shfl(acc, 2 * (h & 31));
    float e1 = __shfl(acc, 2 * (h & 31) + 1);
    if (h < 32)
        xb[node * 32 + h] = (unsigned int)f2bf(e0) | ((unsigned int)f2bf(e1) << 16);
}

// ---------------- bucketed CSR build (padded buckets: no hist/scan pass) ----------------
__global__ __launch_bounds__(1024) void bucket_fill_kernel(const int* __restrict__ edge_index,
                                                           unsigned int* __restrict__ bcursor,
                                                           unsigned int* __restrict__ bucketed) {
    __shared__ unsigned int lh[NBUCK];
    __shared__ unsigned int lcur[NBUCK];
    __shared__ unsigned int gb[NBUCK];
    int tid = threadIdx.x;
    for (int i = tid; i < NBUCK; i += 1024) lh[i] = 0;
    __syncthreads();
    int e0 = blockIdx.x * 8192;
    int src[8], dst[8];
    #pragma unroll
    for (int k = 0; k < 8; k++) {
        src[k] = edge_index[e0 + k * 1024 + tid];
        dst[k] = edge_index[NEDGE + e0 + k * 1024 + tid];
        atomicAdd(&lh[dst[k] >> BSHIFT], 1);
    }
    __syncthreads();
    if (tid < NBUCK) {
        gb[tid] = atomicAdd(&bcursor[tid], lh[tid]);
        lcur[tid] = 0;
    }
    __syncthreads();
    #pragma unroll
    for (int k = 0; k < 8; k++) {
        int b = dst[k] >> BSHIFT;
        unsigned int r = atomicAdd(&lcur[b], 1);
        unsigned int slot = gb[b] + r;
        if (slot < BCAP)
            bucketed[b * BCAP + slot] = (unsigned int)src[k] | ((unsigned int)(dst[k] & 255) << 18);
    }
}

// per-bucket counting sort in LDS -> csr_src + per-node [beg,end)
__global__ __launch_bounds__(512) void bucket_csr_kernel(const unsigned int* __restrict__ bucketed,
                                                         const unsigned int* __restrict__ bcursor,
                                                         int* __restrict__ off,
                                                         int* __restrict__ ends,
                                                         int* __restrict__ csr_src) {
    __shared__ unsigned int stage[BCAP];   // 18 KB packed
    __shared__ unsigned int csr_l[BCAP];   // 18 KB
    __shared__ unsigned int lh[256];
    __shared__ unsigned int lbeg[512];
    __shared__ unsigned int lcur[256];
    int b = blockIdx.x, tid = threadIdx.x;
    unsigned int base = (unsigned int)b * BCAP;
    int cnt = (int)bcursor[b];
    if (cnt > BCAP) cnt = BCAP;   // 16-sigma guard, never triggers
    for (int i = tid; i < 256; i += 512) lh[i] = 0;
    __syncthreads();
    for (int i = tid; i < cnt; i += 512) {
        unsigned int v = bucketed[base + i];
        stage[i] = v;
        atomicAdd(&lh[v >> 18], 1);
    }
    __syncthreads();
    unsigned int own = (tid < 256) ? lh[tid] : 0;
    lbeg[tid] = own;
    __syncthreads();
    for (int d = 1; d < 512; d <<= 1) {
        unsigned int v = (tid >= d) ? lbeg[tid - d] : 0;
        __syncthreads();
        lbeg[tid] += v;
        __syncthreads();
    }
    unsigned int excl = lbeg[tid] - own;
    __syncthreads();
    lbeg[tid] = excl;
    if (tid < 256) {
        lcur[tid] = excl;
        off[b * 256 + tid]  = (int)(base + excl);
        ends[b * 256 + tid] = (int)(base + excl + own);
    }
    __syncthreads();
    for (int i = tid; i < cnt; i += 512) {
        unsigned int v = stage[i];
        unsigned int p = atomicAdd(&lcur[v >> 18], 1);
        csr_l[p] = v & 0x3ffffu;
    }
    __syncthreads();
    for (int i = tid; i < cnt; i += 512)
        csr_src[base + i] = (int)csr_l[i];
}

// accumulate one 16B quad of a neighbor row
#define ACC8(u)                                   \
    do {                                          \
        a0 += bflo((u).x); a1 += bfhi((u).x);     \
        a2 += bflo((u).y); a3 += bfhi((u).y);     \
        a4 += bflo((u).z); a5 += bfhi((u).z);     \
        a6 += bflo((u).w); a7 += bfhi((u).w);     \
    } while (0)

// 8-deep unconditional gather over one slot-group (round-12 proven: VGPR 40,
// no spill at waves/EU=6). Store into agg_s row AGGROW.
#define DO_GROUP(BEG, DEG, IDFIRST, AGGROW)                                     \
    {                                                                           \
        int idcur = (IDFIRST);                                                  \
        float a0 = 0.f, a1 = 0.f, a2 = 0.f, a3 = 0.f;                           \
        float a4 = 0.f, a5 = 0.f, a6 = 0.f, a7 = 0.f;                           \
        for (int jb = 0; jb < (DEG); jb += 8) {                                 \
            int idnxt = (jb + 8 + q < (DEG)) ? csr[(BEG) + jb + 8 + q] : -1;    \
            int n0 = __shfl(idcur, s * 8 + 0);                                  \
            int n1 = __shfl(idcur, s * 8 + 1);                                  \
            int n2 = __shfl(idcur, s * 8 + 2);                                  \
            int n3 = __shfl(idcur, s * 8 + 3);                                  \
            int n4 = __shfl(idcur, s * 8 + 4);                                  \
            int n5 = __shfl(idcur, s * 8 + 5);                                  \
            int n6 = __shfl(idcur, s * 8 + 6);                                  \
            int n7 = __shfl(idcur, s * 8 + 7);                                  \
            int c1 = (n1 >= 0) ? n1 : n0;                                       \
            int c2 = (n2 >= 0) ? n2 : n0;                                       \
            int c3 = (n3 >= 0) ? n3 : n0;                                       \
            int c4 = (n4 >= 0) ? n4 : n0;                                       \
            int c5 = (n5 >= 0) ? n5 : n0;                                       \
            int c6 = (n6 >= 0) ? n6 : n0;                                       \
            int c7 = (n7 >= 0) ? n7 : n0;                                       \
            uint4 u0 = *(const uint4*)&xb[n0 * 32 + q * 4];                     \
            uint4 u1 = *(const uint4*)&xb[c1 * 32 + q * 4];                     \
            uint4 u2 = *(const uint4*)&xb[c2 * 32 + q * 4];                     \
            uint4 u3 = *(const uint4*)&xb[c3 * 32 + q * 4];                     \
            uint4 u4 = *(const uint4*)&xb[c4 * 32 + q * 4];                     \
            uint4 u5 = *(const uint4*)&xb[c5 * 32 + q * 4];                     \
            uint4 u6 = *(const uint4*)&xb[c6 * 32 + q * 4];                     \
            uint4 u7 = *(const uint4*)&xb[c7 * 32 + q * 4];                     \
            if (n1 < 0) { u1.x = u1.y = u1.z = u1.w = 0; }                      \
            if (n2 < 0) { u2.x = u2.y = u2.z = u2.w = 0; }                      \
            if (n3 < 0) { u3.x = u3.y = u3.z = u3.w = 0; }                      \
            if (n4 < 0) { u4.x = u4.y = u4.z = u4.w = 0; }                      \
            if (n5 < 0) { u5.x = u5.y = u5.z = u5.w = 0; }                      \
            if (n6 < 0) { u6.x = u6.y = u6.z = u6.w = 0; }                      \
            if (n7 < 0) { u7.x = u7.y = u7.z = u7.w = 0; }                      \
            ACC8(u0); ACC8(u1); ACC8(u2); ACC8(u3);                             \
            ACC8(u4); ACC8(u5); ACC8(u6); ACC8(u7);                             \
            idcur = idnxt;                                                      \
        }                                                                       \
        unsigned int p0 = (unsigned int)f2bf(a0) | ((unsigned int)f2bf(a1) << 16); \
        unsigned int p1 = (unsigned int)f2bf(a2) | ((unsigned int)f2bf(a3) << 16); \
        unsigned int p2 = (unsigned int)f2bf(a4) | ((unsigned int)f2bf(a5) << 16); \
        unsigned int p3 = (unsigned int)f2bf(a6) | ((unsigned int)f2bf(a7) << 16); \
        *(uint4*)&agg_s[(AGGROW) * 72 + q * 8] = make_uint4(p0, p1, p2, p3);    \
    }

// ---------------- fused conv (layers 1,2): 24 nodes/wave, 8-deep gather ----------------
// ROUND-12 PROVEN CONFIG (52.5 us): 768 blocks x 512 thr = 6144 waves x 24 nodes
// = NTOT exactly; 3 blocks/CU (LDS 43KB x 3), waves/EU=6 -> 85-reg budget fits
// VGPR 40 + 32 AGPR acc with NO SPILL. Round 13's (512,8) cap forced spills
// (WRITE_SIZE 38->75 MB, conv 52.5->69.7 us) — do not tighten the bound.
__global__ __launch_bounds__(512, 6) void conv_kernel(const int* __restrict__ off,
                                                      const int* __restrict__ ends,
                                                      const int* __restrict__ csr,
                                                      const unsigned int* __restrict__ xb,
                                                      const unsigned short* __restrict__ wbuf,
                                                      const float* __restrict__ brel,
                                                      unsigned int* __restrict__ xob) {
    __shared__ unsigned int wlds[4096];            // 16 KB
    __shared__ unsigned short agg_s[8 * NPW * 72]; // 27 KB
    const int tid = threadIdx.x;
    const int w = tid >> 6, l = tid & 63;
    const unsigned int* wsrc = (const unsigned int*)wbuf;
    #pragma unroll
    for (int i = 0; i < 8; i++) wlds[i * 512 + tid] = wsrc[i * 512 + tid];

    const int s = l >> 3, q = l & 7;
    const int lrow = l & 15, g16 = l >> 4, g4 = 4 * (l >> 4);
    const int gwid = blockIdx.x * 8 + w;
    const int node0w = gwid * NPW;

    int bvv = (l < NPW) ? off[node0w + l] : 0;
    int evv = (l < NPW) ? ends[node0w + l] : 0;

    int b0 = __shfl(bvv, s),      d0 = __shfl(evv, s) - b0;
    int b1 = __shfl(bvv, 8 + s),  d1 = __shfl(evv, 8 + s) - b1;
    int b2 = __shfl(bvv, 16 + s), d2 = __shfl(evv, 16 + s) - b2;
    int id0 = (q < d0) ? csr[b0 + q] : -1;
    int id1 = (q < d1) ? csr[b1 + q] : -1;
    int id2 = (q < d2) ? csr[b2 + q] : -1;

    __syncthreads();   // wlds ready

    float bv[4];
    #pragma unroll
    for (int ct = 0; ct < 4; ct++) bv[ct] = brel[ct * 16 + lrow];

    DO_GROUP(b0, d0, id0, w * NPW + s)
    DO_GROUP(b1, d1, id1, w * NPW + 8 + s)
    DO_GROUP(b2, d2, id2, w * NPW + 16 + s)

    __builtin_amdgcn_wave_barrier();

    // ---- MFMA pass 1: rows 0..15 ----
    v4s ax[4];
    #pragma unroll
    for (int kt = 0; kt < 4; kt++)
        ax[kt] = *(const v4s*)&xb[(node0w + lrow) * 32 + kt * 8 + g16 * 2];
    v4f acc[4];
    #pragma unroll
    for (int ct = 0; ct < 4; ct++) acc[ct] = (v4f){0.f, 0.f, 0.f, 0.f};
    #pragma unroll
    for (int kt = 0; kt < 4; kt++) {
        v4s a_agg = *(const v4s*)&agg_s[(w * NPW + lrow) * 72 + kt * 16 + g4];
        #pragma unroll
        for (int ct = 0; ct < 4; ct++) {
            int f = kt * 4 + ct;
            v4s wr = *(const v4s*)&wlds[f * 128 + l * 2];
            v4s wo = *(const v4s*)&wlds[2048 + f * 128 + l * 2];
            acc[ct] = __builtin_amdgcn_mfma_f32_16x16x16bf16_1k(a_agg, wr, acc[ct], 0, 0, 0);
            acc[ct] = __builtin_amdgcn_mfma_f32_16x16x16bf16_1k(ax[kt], wo, acc[ct], 0, 0, 0);
        }
    }
    // ---- MFMA pass 2: rows 16..23 (A rows replicated x2; keep D rows 0..7) ----
    const int r2row = 16 + (l & 7);
    v4s ax2[4];
    #pragma unroll
    for (int kt = 0; kt < 4; kt++)
        ax2[kt] = *(const v4s*)&xb[(node0w + r2row) * 32 + kt * 8 + g16 * 2];
    v4f acc2[4];
    #pragma unroll
    for (int ct = 0; ct < 4; ct++) acc2[ct] = (v4f){0.f, 0.f, 0.f, 0.f};
    #pragma unroll
    for (int kt = 0; kt < 4; kt++) {
        v4s a_agg2 = *(const v4s*)&agg_s[(w * NPW + r2row) * 72 + kt * 16 + g4];
        #pragma unroll
        for (int ct = 0; ct < 4; ct++) {
            int f = kt * 4 + ct;
            v4s wr = *(const v4s*)&wlds[f * 128 + l * 2];
            v4s wo = *(const v4s*)&wlds[2048 + f * 128 + l * 2];
            acc2[ct] = __builtin_amdgcn_mfma_f32_16x16x16bf16_1k(a_agg2, wr, acc2[ct], 0, 0, 0);
            acc2[ct] = __builtin_amdgcn_mfma_f32_16x16x16bf16_1k(ax2[kt], wo, acc2[ct], 0, 0, 0);
        }
    }
    __builtin_amdgcn_wave_barrier();

    // ---- epilogue into own agg rows ----
    #pragma unroll
    for (int ct = 0; ct < 4; ct++) {
        #pragma unroll
        for (int r = 0; r < 4; r++)
            agg_s[(w * NPW + g4 + r) * 72 + ct * 16 + lrow] = f2bf(acc[ct][r] + bv[ct]);
    }
    if (g16 < 2) {   // pass-2 valid D rows 0..7 -> nodes 16..23
        #pragma unroll
        for (int ct = 0; ct < 4; ct++) {
            #pragma unroll
            for (int r = 0; r < 4; r++)
                agg_s[(w * NPW + 16 + g4 + r) * 72 + ct * 16 + lrow] =
                    f2bf(acc2[ct][r] + bv[ct]);
        }
    }
    __builtin_amdgcn_wave_barrier();

    // ---- wave-local coalesced writeout: rows 0..15, then rows 16..23 ----
    {
        int row = l >> 2, qq = l & 3;
        const unsigned int* srcp = (const unsigned int*)&agg_s[(w * NPW + row) * 72 + qq * 16];
        uint4 v0 = *(const uint4*)(srcp);
        uint4 v1 = *(const uint4*)(srcp + 4);
        *(uint4*)&xob[(node0w + row) * 32 + qq * 8] = v0;
        *(uint4*)&xob[(node0w + row) * 32 + qq * 8 + 4] = v1;
    }
    {
        int row = 16 + (l >> 3), qq = l & 7;
        *(uint4*)&xob[(node0w + row) * 32 + qq * 4] =
            *(const uint4*)&agg_s[(w * NPW + row) * 72 + qq * 8];
    }
}

// ---------------- conv layer 3 (ligand rows only) + fused pooling ----------------
// Only x[:NLIG] of conv3's output feeds the pooled readout -> process just the
// 16384 ligand dst nodes (1/9 the work). 8 nodes/wave x 2048 waves (256 blocks).
// Single MFMA pass with A rows duplicated (row = lrow&7); D rows 0..7 valid.
// Epilogue adds f32 outputs directly into pooled[batch] (+1 to cnt).
__global__ __launch_bounds__(512, 6) void conv_lig_kernel(const int* __restrict__ off,
                                                          const int* __restrict__ ends,
                                                          const int* __restrict__ csr,
                                                          const unsigned int* __restrict__ xb,
                                                          const unsigned short* __restrict__ wbuf,
                                                          const float* __restrict__ brel,
                                                          const int* __restrict__ lig_batch,
                                                          float* __restrict__ pooled,
                                                          float* __restrict__ cnt) {
    __shared__ unsigned int wlds[4096];          // 16 KB
    __shared__ unsigned short agg_s[8 * 8 * 72]; // 9 KB
    const int tid = threadIdx.x;
    const int w = tid >> 6, l = tid & 63;
    const unsigned int* wsrc = (const unsigned int*)wbuf;
    #pragma unroll
    for (int i = 0; i < 8; i++) wlds[i * 512 + tid] = wsrc[i * 512 + tid];

    const int s = l >> 3, q = l & 7;
    const int lrow = l & 15, g16 = l >> 4, g4 = 4 * (l >> 4);
    const int gwid = blockIdx.x * 8 + w;
    const int node0w = gwid * 8;

    int bvv = (l < 8) ? off[node0w + l] : 0;
    int evv = (l < 8) ? ends[node0w + l] : 0;
    int b0 = __shfl(bvv, s), d0 = __shfl(evv, s) - b0;
    int id0 = (q < d0) ? csr[b0 + q] : -1;

    __syncthreads();   // wlds ready

    float bv[4];
    #pragma unroll
    for (int ct = 0; ct < 4; ct++) bv[ct] = brel[ct * 16 + lrow];

    DO_GROUP(b0, d0, id0, w * 8 + s)

    __builtin_amdgcn_wave_barrier();

    // ---- MFMA: A rows duplicated (row = lrow&7) -> D rows 0..7 valid ----
    const int arow = lrow & 7;
    v4s ax[4];
    #pragma unroll
    for (int kt = 0; kt < 4; kt++)
        ax[kt] = *(const v4s*)&xb[(node0w + arow) * 32 + kt * 8 + g16 * 2];
    v4f acc[4];
    #pragma unroll
    for (int ct = 0; ct < 4; ct++) acc[ct] = (v4f){0.f, 0.f, 0.f, 0.f};
    #pragma unroll
    for (int kt = 0; kt < 4; kt++) {
        v4s a_agg = *(const v4s*)&agg_s[(w * 8 + arow) * 72 + kt * 16 + g4];
        #pragma unroll
        for (int ct = 0; ct < 4; ct++) {
            int f = kt * 4 + ct;
            v4s wr = *(const v4s*)&wlds[f * 128 + l * 2];
            v4s wo = *(const v4s*)&wlds[2048 + f * 128 + l * 2];
            acc[ct] = __builtin_amdgcn_mfma_f32_16x16x16bf16_1k(a_agg, wr, acc[ct], 0, 0, 0);
            acc[ct] = __builtin_amdgcn_mfma_f32_16x16x16bf16_1k(ax[kt], wo, acc[ct], 0, 0, 0);
        }
    }

    // ---- fused pooling epilogue (f32 atomics; D rows 0..7 only) ----
    if (g16 < 2) {
        #pragma unroll
        for (int r = 0; r < 4; r++) {
            int node = node0w + g4 + r;
            int bb = lig_batch[node];
            #pragma unroll
            for (int ct = 0; ct < 4; ct++)
                unsafeAtomicAdd(&pooled[bb * H + ct * 16 + lrow], acc[ct][r] + bv[ct]);
            if (lrow == 0) unsafeAtomicAdd(&cnt[bb], 1.0f);
        }
    }
}

// ---------------- readout ----------------
__global__ void readout_kernel(const float* __restrict__ pooled, const float* __restrict__ cnt,
                               const float* __restrict__ Wro1, const float* __restrict__ bro1,
                               const float* __restrict__ Wro2, const float* __restrict__ bro2,
                               float* __restrict__ out) {
    __shared__ float pm[4][H];
    int w = threadIdx.x >> 6;
    int h = threadIdx.x & 63;
    int b = blockIdx.x * 4 + w;
    float c = fmaxf(cnt[b], 1.0f);
    pm[w][h] = pooled[b * H + h] / c;
    __syncthreads();
    float acc = bro1[h];
    #pragma unroll 8
    for (int k = 0; k < H; k++) acc += pm[w][k] * Wro1[k * H + h];
    float sig = 1.0f / (1.0f + expf(-acc));
    float s = acc * sig;
    float r = s * Wro2[h];
    #pragma unroll
    for (int off = 32; off; off >>= 1) r += __shfl_down(r, off);
    if (h == 0) out[b] = r + bro2[0];
}

extern "C" void kernel_launch(void* const* d_in, const int* in_sizes, int n_in,
                              void* d_out, int out_size, void* d_ws, size_t ws_size,
                              hipStream_t stream) {
    const float* lig_feat  = (const float*)d_in[1];
    const float* prot_feat = (const float*)d_in[3];
    const float* t         = (const float*)d_in[4];
    const int*   lig_batch = (const int*)d_in[5];
    const int*   edge_index= (const int*)d_in[7];
    const float* W_lig  = (const float*)d_in[8];
    const float* b_lig  = (const float*)d_in[9];
    const float* W_prot = (const float*)d_in[10];
    const float* b_prot = (const float*)d_in[11];
    const float* Wt1 = (const float*)d_in[12];
    const float* bt1 = (const float*)d_in[13];
    const float* Wt2 = (const float*)d_in[14];
    const float* bt2 = (const float*)d_in[15];
    const float* Wrel[3]  = {(const float*)d_in[16], (const float*)d_in[19], (const float*)d_in[22]};
    const float* brel[3]  = {(const float*)d_in[17], (const float*)d_in[20], (const float*)d_in[23]};
    const float* Wroot[3] = {(const float*)d_in[18], (const float*)d_in[21], (const float*)d_in[24]};
    const float* Wro1 = (const float*)d_in[25];
    const float* bro1 = (const float*)d_in[26];
    const float* Wro2 = (const float*)d_in[27];
    const float* bro2 = (const float*)d_in[28];
    float* out = (float*)d_out;

    char* ws = (char*)d_ws;
    int*            off_a   = (int*)(ws);                       // NTOT ints
    int*            ends_a  = (int*)(ws + 655360);              // NTOT ints
    unsigned int*   bcursor = (unsigned int*)(ws + 1310720);    // 2304 B
    float*          t_emb   = (float*)(ws + 1376256);
    float*          pooled  = (float*)(ws + 1441792);
    float*          cnt     = (float*)(ws + 1507328);
    unsigned short* wbuf    = (unsigned short*)(ws + 1572864);  // 48 KB
    int*            csr_src = (int*)(ws + 2097152);             // 10.6 MB padded
    unsigned int*   bucketed= (unsigned int*)(ws + 14680064);   // 10.6 MB padded
    unsigned int*   xb0     = (unsigned int*)(ws + 27262976);   // 18 MB
    unsigned int*   xb1     = (unsigned int*)(ws + 46137344);   // 18 MB

    time_mlp_kernel<<<NB, H, 0, stream>>>(t, Wt1, bt1, Wt2, bt2, t_emb);
    wswz_kernel<<<dim3(16, 6), 256, 0, stream>>>(Wrel[0], Wroot[0], Wrel[1], Wroot[1],
                                                 Wrel[2], Wroot[2], wbuf);
    node_init_kernel<<<NTOT / 4, 256, 0, stream>>>(lig_feat, prot_feat, lig_batch, t_emb,
                                                   W_lig, b_lig, W_prot, b_prot, xb0);

    // ---- padded-bucket CSR build ----
    hipMemsetAsync(bcursor, 0, 2304, stream);
    bucket_fill_kernel<<<NEDGE / 8192, 1024, 0, stream>>>(edge_index, bcursor, bucketed);
    bucket_csr_kernel<<<NBUCK, 512, 0, stream>>>(bucketed, bcursor, off_a, ends_a, csr_src);

    // zero pooled+cnt (needed by conv_lig's fused pooling)
    hipMemsetAsync(pooled, 0, (size_t)(NB * H + NB) * sizeof(float), stream);

    // ---- conv layers 1,2 (all nodes; round-12 proven config) ----
    conv_kernel<<<768, 512, 0, stream>>>(off_a, ends_a, csr_src, xb0,
                                         wbuf, brel[0], xb1);
    conv_kernel<<<768, 512, 0, stream>>>(off_a, ends_a, csr_src, xb1,
                                         wbuf + 8192, brel[1], xb0);
    // ---- conv layer 3: ligand rows only, fused pooling ----
    conv_lig_kernel<<<NLIG / 64, 512, 0, stream>>>(off_a, ends_a, csr_src, xb0,
                                                   wbuf + 16384, brel[2], lig_batch,
                                                   pooled, cnt);

    readout_kernel<<<NB / 4, 256, 0, stream>>>(pooled, cnt, Wro1, bro1, Wro2, bro2, out);
}